// Round 5
// baseline (1109.717 us; speedup 1.0000x reference)
//
#include <hip/hip_runtime.h>
#include <cmath>

#define B_ 32
#define N_ 64
#define H_ 256
#define G3_ 768           // 3*H
#define INTER_ 912        // 2H + 6C + C1
#define KP_ 928           // INTER_ padded to 29*32 for bf16 MFMA GEMM
#define FCIN_ 2992        // 3*INTER + H
#define GRED_ 2736        // 3*INTER (f reductions part of g)

#define PADA 264          // gru1d hA row stride (bf16 elems)
#define PADA2 328         // gru2d unified [h(256)|x(64)] row stride (+8 pad)

typedef __attribute__((ext_vector_type(8))) short short8;
typedef __attribute__((ext_vector_type(4))) short sshort4;
typedef __attribute__((ext_vector_type(4))) float float4v;

#define MFMA __builtin_amdgcn_mfma_f32_16x16x32_bf16

// single-instruction transcendentals: v_exp_f32 is exp2, v_rcp_f32
__device__ __forceinline__ float sigmoid_f(float x) {
    return __builtin_amdgcn_rcpf(1.0f + __builtin_amdgcn_exp2f(-1.44269504f * x));
}
__device__ __forceinline__ float tanh_fast(float x) {
    return 1.0f - 2.0f * __builtin_amdgcn_rcpf(1.0f + __builtin_amdgcn_exp2f(2.88539008f * x));
}
__device__ __forceinline__ unsigned f2bf_bits(float x) {
    unsigned u = __float_as_uint(x);
    return (u + 0x7fffu + ((u >> 16) & 1u)) >> 16;
}
__device__ __forceinline__ short f2bf(float x) { return (short)f2bf_bits(x); }

// ---------------------------------------------------------------------------
// prep: (a) Bfrag   = gru2d weights, fragment-major bf16 (layout verified R2)
//       (b) Bfrag1  = gru1d Whh, same pack (8 kt)
//       (c) Bfrag1W = gru1d Wih (768 x 912), same pack, K zero-padded to 928
//       (d) fc1Wt transpose
// Fragment layout: [kt][ntile(48)][lane(64)][j(8)] bf16; value = W[n][k] with
// n = ntile*16 + (lane&15), k = kt*32 + (lane>>4)*8 + j.
// ---------------------------------------------------------------------------
__global__ __launch_bounds__(256) void prep_kernel(
        const float* __restrict__ Whh2, const float* __restrict__ Wih2,
        const float* __restrict__ Whh1, const float* __restrict__ Wih1,
        const float* __restrict__ fc1W,
        short* __restrict__ Bfrag, short* __restrict__ Bfrag1,
        short* __restrict__ Bfrag1W, float* __restrict__ fc1Wt) {
    int idx = blockIdx.x * 256 + threadIdx.x;
    if (idx < 10 * 48 * 64 * 8) {
        int j = idx & 7, lane = (idx >> 3) & 63, tile = idx >> 9;
        int nt = tile % 48, kt = tile / 48;
        int n = nt * 16 + (lane & 15);
        int kb = (lane >> 4) * 8 + j;
        float v = (kt < 8) ? Whh2[n * 256 + kt * 32 + kb]
                           : Wih2[n * 64 + (kt - 8) * 32 + kb];
        Bfrag[idx] = f2bf(v);
    }
    if (idx < 8 * 48 * 64 * 8) {
        int j = idx & 7, lane = (idx >> 3) & 63, tile = idx >> 9;
        int nt = tile % 48, kt = tile / 48;
        int n = nt * 16 + (lane & 15);
        int k = kt * 32 + (lane >> 4) * 8 + j;
        Bfrag1[idx] = f2bf(Whh1[n * 256 + k]);
    }
    if (idx < 29 * 48 * 64 * 8) {
        int j = idx & 7, lane = (idx >> 3) & 63, tile = idx >> 9;
        int nt = tile % 48, kt = tile / 48;
        int n = nt * 16 + (lane & 15);
        int k = kt * 32 + (lane >> 4) * 8 + j;
        Bfrag1W[idx] = (k < INTER_) ? f2bf(Wih1[n * INTER_ + k]) : (short)0;
    }
    if (idx < FCIN_ * 256) {
        int o = idx & 255, i = idx >> 8;
        fc1Wt[idx] = fc1W[o * FCIN_ + i];
    }
}

// ---------------------------------------------------------------------------
// reduce_states: d[] reductions + x1 copy -> f[:, 0:400]. NT loads.
// ---------------------------------------------------------------------------
__global__ __launch_bounds__(256) void reduce_states_kernel(
        const float* __restrict__ states, const float* __restrict__ x1,
        float* __restrict__ f) {
    const int c = threadIdx.x & 63;
    const int bj = blockIdx.x * 4 + (threadIdx.x >> 6);
    const int b = bj >> 6, j = bj & 63;
    const float* p1 = states + b * 262144 + j * 64 + c;
    const float* p2 = states + b * 262144 + j * 4096 + c;
    float mx1 = -1e30f, mn1 = 1e30f, sm1 = 0.f;
    float mx2 = -1e30f, mn2 = 1e30f, sm2 = 0.f;
    #pragma unroll 8
    for (int n = 0; n < 64; ++n) {
        float v = __builtin_nontemporal_load(p1 + n * 4096);
        mx1 = fmaxf(mx1, v); mn1 = fminf(mn1, v); sm1 += v;
    }
    #pragma unroll 8
    for (int m = 0; m < 64; ++m) {
        float v = __builtin_nontemporal_load(p2 + m * 64);
        mx2 = fmaxf(mx2, v); mn2 = fminf(mn2, v); sm2 += v;
    }
    float* fr = f + bj * INTER_;
    fr[16 + c]  = mx1;  fr[80 + c]  = sm1 * (1.f / 64.f);  fr[144 + c] = mn1;
    fr[208 + c] = mx2;  fr[272 + c] = sm2 * (1.f / 64.f);  fr[336 + c] = mn2;
    if (c < 16) fr[c] = x1[bj * 16 + c];
}

// ---------------------------------------------------------------------------
// gru2d R5: two-group ping-pong. 128 blocks; block g = sd1-group g (A) +
// sd2-group g (B). Per step two barrier-phases:
//   P1(e): MFMA-A(e)  || epi-B(e-1) + x_B^e LDS-write + issue x_A^{e+1}
//   P2(e): MFMA-B(e)  || epi-A(e)   + x_A^{e+1} write + issue x_B^{e+1}
// MFMA of one group and gate-VALU of the other are independent -> both pipes
// fill within each phase; resident weights serve 2x work.
// hA[G] rows = [h(256)|x(64)], single-buffered (reads/writes in alternate
// barrier phases). B residency: kt0-3 regs, kt4-5 LDS, kt6-9 reloaded per
// phase (L2-hot), staggered 2-kt ahead of use.
// epi-B formula identical to R4 (bit-identical accumulation order).
// ---------------------------------------------------------------------------
#define EPI_STEP(P, aR0v, aR1v, aZ0v, aZ1v, aNh0v, aNh1v, aNx0v, aNx1v, hr0, hr1, dst) \
    do {                                                                     \
        const int row_ = q * 4 + (P);                                        \
        float r0_ = sigmoid_f(aR0v[P]);                                      \
        float z0_ = sigmoid_f(aZ0v[P]);                                      \
        float n0_ = tanh_fast(aNx0v[P] + r0_ * aNh0v[P]);                    \
        float h0_ = n0_ + z0_ * (hr0[P] - n0_);                              \
        hr0[P] = h0_;                                                        \
        (dst)[row_ * PADA2 + u0] = f2bf(h0_);                                \
        float r1_ = sigmoid_f(aR1v[P]);                                      \
        float z1_ = sigmoid_f(aZ1v[P]);                                      \
        float n1_ = tanh_fast(aNx1v[P] + r1_ * aNh1v[P]);                    \
        float h1_ = n1_ + z1_ * (hr1[P] - n1_);                              \
        hr1[P] = h1_;                                                        \
        (dst)[row_ * PADA2 + u1] = f2bf(h1_);                                \
    } while (0)

__global__ __launch_bounds__(512, 1) void gru2d_mfma(
        const float* __restrict__ states,
        const int* __restrict__ perm1, const int* __restrict__ perm2,
        const short* __restrict__ Bfrag,
        const float* __restrict__ bih, const float* __restrict__ bhh,
        float* __restrict__ f) {
    __shared__ short hA[2][16 * PADA2];    // [0]=A(sd1), [1]=B(sd2)
    __shared__ short8 Blds[2 * 48 * 64];   // kt 4,5
    __shared__ int perms[2][1024];

    const int tid = threadIdx.x;
    const int lane = tid & 63;
    const int w = tid >> 6;
    const int m = lane & 15;
    const int q = lane >> 4;
    const int sblock = blockIdx.x * 16;

    for (int i = tid; i < 2048; i += 512) {
        int grp = i >> 10, idx = i & 1023;
        int r = idx >> 6, t = idx & 63;
        int qq = (sblock + r) & 63;
        perms[grp][idx] = grp ? perm2[qq * 64 + t] : perm1[qq * 64 + t];
    }
    for (int i = tid; i < 2 * 16 * PADA2; i += 512) ((short*)hA)[i] = 0;
    {
        const uint4* src = (const uint4*)(Bfrag + 4 * 48 * 64 * 8);
        uint4* dst = (uint4*)Blds;
        #pragma unroll
        for (int rep = 0; rep < 12; ++rep)
            dst[tid + rep * 512] = src[tid + rep * 512];
    }

    const short8* Bf8 = (const short8*)Bfrag;
    short8 Bres[24];   // kt 0-3
    #pragma unroll
    for (int kt = 0; kt < 4; ++kt)
        #pragma unroll
        for (int j = 0; j < 6; ++j)
            Bres[kt * 6 + j] = Bf8[(kt * 48 + 8 * j + w) * 64 + lane];

    const int u0 = 16 * w + m;
    const int u1 = 128 + u0;
    const float br0 = bih[u0] + bhh[u0],             br1 = bih[u1] + bhh[u1];
    const float bz0 = bih[256 + u0] + bhh[256 + u0], bz1 = bih[256 + u1] + bhh[256 + u1];
    const float bnx0 = bih[512 + u0], bnx1 = bih[512 + u1];
    const float bnh0 = bhh[512 + u0], bnh1 = bhh[512 + u1];

    // loop-invariant gather geometry: half0 -> row w, half1 -> row w+8, col=lane
    const int s0g = sblock + w,     b0g = s0g >> 6, qq0 = s0g & 63;
    const int s1g = sblock + w + 8, b1g = s1g >> 6, qq1 = s1g & 63;
    const float* baseA0 = states + (size_t)(b0g * 64 + qq0) * 4096 + lane; // +p*64
    const float* baseA1 = states + (size_t)(b1g * 64 + qq1) * 4096 + lane;
    const float* baseB0 = states + (size_t)b0g * 262144 + qq0 * 64 + lane; // +p*4096
    const float* baseB1 = states + (size_t)b1g * 262144 + qq1 * 64 + lane;
    const int w0o = w * PADA2 + 256 + lane;
    const int w1o = (w + 8) * PADA2 + 256 + lane;

    float4v hrA0 = {0,0,0,0}, hrA1 = {0,0,0,0};
    float4v hrB0 = {0,0,0,0}, hrB1 = {0,0,0,0};
    float4v AR0, AR1, AZ0, AZ1, ANh0, ANh1, ANx0, ANx1;
    float4v BR0, BR1, BZ0, BZ1, BNh0, BNh1, BNx0, BNx1;
    float xgA0, xgA1, xgB0 = 0.f, xgB1 = 0.f;

    __syncthreads();
    // prologue: x^0 for both groups
    hA[0][w0o] = f2bf(baseA0[perms[0][w * 64] * 64]);
    hA[0][w1o] = f2bf(baseA1[perms[0][(w + 8) * 64] * 64]);
    hA[1][w0o] = f2bf(baseB0[perms[1][w * 64] * 4096]);
    hA[1][w1o] = f2bf(baseB1[perms[1][(w + 8) * 64] * 4096]);
    __syncthreads();

    #pragma unroll 1
    for (int e = 0; e < 64; ++e) {
        // ================= P1: MFMA-A(e) || epi-B(e-1) =================
        {
            const short* hAc = (const short*)hA[0];
            short* hBd = (short*)hA[1];
            AR0  = (float4v){br0, br0, br0, br0};
            AR1  = (float4v){br1, br1, br1, br1};
            AZ0  = (float4v){bz0, bz0, bz0, bz0};
            AZ1  = (float4v){bz1, bz1, bz1, bz1};
            ANh0 = (float4v){bnh0, bnh0, bnh0, bnh0};
            ANh1 = (float4v){bnh1, bnh1, bnh1, bnh1};
            ANx0 = (float4v){bnx0, bnx0, bnx0, bnx0};
            ANx1 = (float4v){bnx1, bnx1, bnx1, bnx1};
            if (e < 63) {   // issue x_A^{e+1}
                xgA0 = baseA0[perms[0][w * 64 + e + 1] * 64];
                xgA1 = baseA1[perms[0][(w + 8) * 64 + e + 1] * 64];
            }
            short8 bR6[6], bR7[6], bR8[6], bR9[6];
            #pragma unroll
            for (int kt = 0; kt < 10; ++kt) {
                short8 a = *(const short8*)(hAc + m * PADA2 + kt * 32 + q * 8);
                short8 b0, b1, b2, b3, b4, b5;
                if (kt < 4) {
                    b0 = Bres[kt * 6 + 0]; b1 = Bres[kt * 6 + 1];
                    b2 = Bres[kt * 6 + 2]; b3 = Bres[kt * 6 + 3];
                    b4 = Bres[kt * 6 + 4]; b5 = Bres[kt * 6 + 5];
                } else if (kt < 6) {
                    b0 = Blds[((kt - 4) * 48 + 8 * 0 + w) * 64 + lane];
                    b1 = Blds[((kt - 4) * 48 + 8 * 1 + w) * 64 + lane];
                    b2 = Blds[((kt - 4) * 48 + 8 * 2 + w) * 64 + lane];
                    b3 = Blds[((kt - 4) * 48 + 8 * 3 + w) * 64 + lane];
                    b4 = Blds[((kt - 4) * 48 + 8 * 4 + w) * 64 + lane];
                    b5 = Blds[((kt - 4) * 48 + 8 * 5 + w) * 64 + lane];
                } else if (kt == 6) {
                    b0 = bR6[0]; b1 = bR6[1]; b2 = bR6[2];
                    b3 = bR6[3]; b4 = bR6[4]; b5 = bR6[5];
                } else if (kt == 7) {
                    b0 = bR7[0]; b1 = bR7[1]; b2 = bR7[2];
                    b3 = bR7[3]; b4 = bR7[4]; b5 = bR7[5];
                } else if (kt == 8) {
                    b0 = bR8[0]; b1 = bR8[1]; b2 = bR8[2];
                    b3 = bR8[3]; b4 = bR8[4]; b5 = bR8[5];
                } else {
                    b0 = bR9[0]; b1 = bR9[1]; b2 = bR9[2];
                    b3 = bR9[3]; b4 = bR9[4]; b5 = bR9[5];
                }
                AR0 = MFMA(a, b0, AR0, 0, 0, 0);
                AR1 = MFMA(a, b1, AR1, 0, 0, 0);
                AZ0 = MFMA(a, b2, AZ0, 0, 0, 0);
                AZ1 = MFMA(a, b3, AZ1, 0, 0, 0);
                if (kt < 8) {
                    ANh0 = MFMA(a, b4, ANh0, 0, 0, 0);
                    ANh1 = MFMA(a, b5, ANh1, 0, 0, 0);
                } else {
                    ANx0 = MFMA(a, b4, ANx0, 0, 0, 0);
                    ANx1 = MFMA(a, b5, ANx1, 0, 0, 0);
                }
                if (kt == 3) {
                    #pragma unroll
                    for (int j = 0; j < 6; ++j)
                        bR6[j] = Bf8[(6 * 48 + 8 * j + w) * 64 + lane];
                }
                if (kt == 4) {
                    #pragma unroll
                    for (int j = 0; j < 6; ++j)
                        bR7[j] = Bf8[(7 * 48 + 8 * j + w) * 64 + lane];
                }
                if (kt == 5) {
                    #pragma unroll
                    for (int j = 0; j < 6; ++j)
                        bR8[j] = Bf8[(8 * 48 + 8 * j + w) * 64 + lane];
                }
                if (kt == 6) {
                    #pragma unroll
                    for (int j = 0; j < 6; ++j)
                        bR9[j] = Bf8[(9 * 48 + 8 * j + w) * 64 + lane];
                }
                if (kt == 1 && e > 0)
                    EPI_STEP(0, BR0, BR1, BZ0, BZ1, BNh0, BNh1, BNx0, BNx1, hrB0, hrB1, hBd);
                if (kt == 3 && e > 0)
                    EPI_STEP(1, BR0, BR1, BZ0, BZ1, BNh0, BNh1, BNx0, BNx1, hrB0, hrB1, hBd);
                if (kt == 5 && e > 0)
                    EPI_STEP(2, BR0, BR1, BZ0, BZ1, BNh0, BNh1, BNx0, BNx1, hrB0, hrB1, hBd);
                if (kt == 7 && e > 0)
                    EPI_STEP(3, BR0, BR1, BZ0, BZ1, BNh0, BNh1, BNx0, BNx1, hrB0, hrB1, hBd);
            }
            if (e > 0) {    // x_B^e write (loads issued P2(e-1))
                hBd[w0o] = f2bf(xgB0);
                hBd[w1o] = f2bf(xgB1);
            }
        }
        __syncthreads();
        // ================= P2: MFMA-B(e) || epi-A(e) =================
        {
            const short* hBc = (const short*)hA[1];
            short* hAd = (short*)hA[0];
            BR0  = (float4v){br0, br0, br0, br0};
            BR1  = (float4v){br1, br1, br1, br1};
            BZ0  = (float4v){bz0, bz0, bz0, bz0};
            BZ1  = (float4v){bz1, bz1, bz1, bz1};
            BNh0 = (float4v){bnh0, bnh0, bnh0, bnh0};
            BNh1 = (float4v){bnh1, bnh1, bnh1, bnh1};
            BNx0 = (float4v){bnx0, bnx0, bnx0, bnx0};
            BNx1 = (float4v){bnx1, bnx1, bnx1, bnx1};
            if (e < 63) {   // issue x_B^{e+1}
                xgB0 = baseB0[perms[1][w * 64 + e + 1] * 4096];
                xgB1 = baseB1[perms[1][(w + 8) * 64 + e + 1] * 4096];
            }
            short8 bR6[6], bR7[6], bR8[6], bR9[6];
            #pragma unroll
            for (int kt = 0; kt < 10; ++kt) {
                short8 a = *(const short8*)(hBc + m * PADA2 + kt * 32 + q * 8);
                short8 b0, b1, b2, b3, b4, b5;
                if (kt < 4) {
                    b0 = Bres[kt * 6 + 0]; b1 = Bres[kt * 6 + 1];
                    b2 = Bres[kt * 6 + 2]; b3 = Bres[kt * 6 + 3];
                    b4 = Bres[kt * 6 + 4]; b5 = Bres[kt * 6 + 5];
                } else if (kt < 6) {
                    b0 = Blds[((kt - 4) * 48 + 8 * 0 + w) * 64 + lane];
                    b1 = Blds[((kt - 4) * 48 + 8 * 1 + w) * 64 + lane];
                    b2 = Blds[((kt - 4) * 48 + 8 * 2 + w) * 64 + lane];
                    b3 = Blds[((kt - 4) * 48 + 8 * 3 + w) * 64 + lane];
                    b4 = Blds[((kt - 4) * 48 + 8 * 4 + w) * 64 + lane];
                    b5 = Blds[((kt - 4) * 48 + 8 * 5 + w) * 64 + lane];
                } else if (kt == 6) {
                    b0 = bR6[0]; b1 = bR6[1]; b2 = bR6[2];
                    b3 = bR6[3]; b4 = bR6[4]; b5 = bR6[5];
                } else if (kt == 7) {
                    b0 = bR7[0]; b1 = bR7[1]; b2 = bR7[2];
                    b3 = bR7[3]; b4 = bR7[4]; b5 = bR7[5];
                } else if (kt == 8) {
                    b0 = bR8[0]; b1 = bR8[1]; b2 = bR8[2];
                    b3 = bR8[3]; b4 = bR8[4]; b5 = bR8[5];
                } else {
                    b0 = bR9[0]; b1 = bR9[1]; b2 = bR9[2];
                    b3 = bR9[3]; b4 = bR9[4]; b5 = bR9[5];
                }
                BR0 = MFMA(a, b0, BR0, 0, 0, 0);
                BR1 = MFMA(a, b1, BR1, 0, 0, 0);
                BZ0 = MFMA(a, b2, BZ0, 0, 0, 0);
                BZ1 = MFMA(a, b3, BZ1, 0, 0, 0);
                if (kt < 8) {
                    BNh0 = MFMA(a, b4, BNh0, 0, 0, 0);
                    BNh1 = MFMA(a, b5, BNh1, 0, 0, 0);
                } else {
                    BNx0 = MFMA(a, b4, BNx0, 0, 0, 0);
                    BNx1 = MFMA(a, b5, BNx1, 0, 0, 0);
                }
                if (kt == 3) {
                    #pragma unroll
                    for (int j = 0; j < 6; ++j)
                        bR6[j] = Bf8[(6 * 48 + 8 * j + w) * 64 + lane];
                }
                if (kt == 4) {
                    #pragma unroll
                    for (int j = 0; j < 6; ++j)
                        bR7[j] = Bf8[(7 * 48 + 8 * j + w) * 64 + lane];
                }
                if (kt == 5) {
                    #pragma unroll
                    for (int j = 0; j < 6; ++j)
                        bR8[j] = Bf8[(8 * 48 + 8 * j + w) * 64 + lane];
                }
                if (kt == 6) {
                    #pragma unroll
                    for (int j = 0; j < 6; ++j)
                        bR9[j] = Bf8[(9 * 48 + 8 * j + w) * 64 + lane];
                }
                if (kt == 1)
                    EPI_STEP(0, AR0, AR1, AZ0, AZ1, ANh0, ANh1, ANx0, ANx1, hrA0, hrA1, hAd);
                if (kt == 3)
                    EPI_STEP(1, AR0, AR1, AZ0, AZ1, ANh0, ANh1, ANx0, ANx1, hrA0, hrA1, hAd);
                if (kt == 5)
                    EPI_STEP(2, AR0, AR1, AZ0, AZ1, ANh0, ANh1, ANx0, ANx1, hrA0, hrA1, hAd);
                if (kt == 7)
                    EPI_STEP(3, AR0, AR1, AZ0, AZ1, ANh0, ANh1, ANx0, ANx1, hrA0, hrA1, hAd);
            }
            if (e < 63) {   // x_A^{e+1} write (loads issued in P1(e))
                hAd[w0o] = f2bf(xgA0);
                hAd[w1o] = f2bf(xgA1);
            }
        }
        __syncthreads();
    }

    // final epi-B(63) (hA write harmless)
    {
        short* hBd = (short*)hA[1];
        EPI_STEP(0, BR0, BR1, BZ0, BZ1, BNh0, BNh1, BNx0, BNx1, hrB0, hrB1, hBd);
        EPI_STEP(1, BR0, BR1, BZ0, BZ1, BNh0, BNh1, BNx0, BNx1, hrB0, hrB1, hBd);
        EPI_STEP(2, BR0, BR1, BZ0, BZ1, BNh0, BNh1, BNx0, BNx1, hrB0, hrB1, hBd);
        EPI_STEP(3, BR0, BR1, BZ0, BZ1, BNh0, BNh1, BNx0, BNx1, hrB0, hrB1, hBd);
    }

    #pragma unroll
    for (int p = 0; p < 4; ++p) {
        int s = sblock + q * 4 + p;
        f[s * INTER_ + 400 + u0] = hrA0[p];
        f[s * INTER_ + 400 + u1] = hrA1[p];
        f[s * INTER_ + 656 + u0] = hrB0[p];
        f[s * INTER_ + 656 + u1] = hrB1[p];
    }
}

// ---------------------------------------------------------------------------
// convert f (fp32 [2048][912]) -> fbf (bf16 [2048][928], zero-padded K)
// ---------------------------------------------------------------------------
__global__ __launch_bounds__(256) void convert_f_kernel(
        const float* __restrict__ f, short* __restrict__ fbf) {
    int idx = blockIdx.x * 256 + threadIdx.x;
    int row = idx / 232;
    int c4 = (idx - row * 232) * 4;
    if (row >= 2048) return;
    sshort4 o;
    if (c4 < INTER_) {
        float4v v = *(const float4v*)(f + row * INTER_ + c4);
        o[0] = f2bf(v[0]); o[1] = f2bf(v[1]); o[2] = f2bf(v[2]); o[3] = f2bf(v[3]);
    } else {
        o[0] = 0; o[1] = 0; o[2] = 0; o[3] = 0;
    }
    *(sshort4*)(fbf + row * KP_ + c4) = o;
}

// ---------------------------------------------------------------------------
// xw1 = fbf[2048][928] @ Wih1^T (+bih1), bf16 MFMA. Output TRANSPOSED to
// [t][seq][768] so gru1d's per-step reads are step-contiguous.
// ---------------------------------------------------------------------------
__global__ __launch_bounds__(256) void gemm_xw1_mfma(
        const short* __restrict__ fbf, const short* __restrict__ BfragW,
        const float* __restrict__ bih, float* __restrict__ xw) {
    const int tid = threadIdx.x;
    const int lane = tid & 63;
    const int w = tid >> 6;
    const int m = lane & 15;
    const int q = lane >> 4;
    const int tn = blockIdx.x;
    const int tm = blockIdx.y;
    const int rowb = tm * 64 + w * 16;
    const short8* Bf8 = (const short8*)BfragW;

    float4v acc[4];
    #pragma unroll
    for (int nn = 0; nn < 4; ++nn) {
        float b = bih[tn * 64 + nn * 16 + m];
        acc[nn][0] = b; acc[nn][1] = b; acc[nn][2] = b; acc[nn][3] = b;
    }

    const short* arow = fbf + (rowb + m) * KP_;
    short8 a_cur = *(const short8*)(arow + q * 8);
    short8 b_cur[4];
    #pragma unroll
    for (int nn = 0; nn < 4; ++nn)
        b_cur[nn] = Bf8[(tn * 4 + nn) * 64 + lane];

    for (int kt = 0; kt < 29; ++kt) {
        short8 a_nxt = a_cur;
        short8 b_nxt[4];
        if (kt + 1 < 29) {
            a_nxt = *(const short8*)(arow + (kt + 1) * 32 + q * 8);
            #pragma unroll
            for (int nn = 0; nn < 4; ++nn)
                b_nxt[nn] = Bf8[((kt + 1) * 48 + tn * 4 + nn) * 64 + lane];
        }
        #pragma unroll
        for (int nn = 0; nn < 4; ++nn)
            acc[nn] = MFMA(a_cur, b_cur[nn], acc[nn], 0, 0, 0);
        a_cur = a_nxt;
        #pragma unroll
        for (int nn = 0; nn < 4; ++nn) b_cur[nn] = b_nxt[nn];
    }

    #pragma unroll
    for (int p = 0; p < 4; ++p) {
        int row = rowb + q * 4 + p;
        int seq = row >> 6, t = row & 63;
        #pragma unroll
        for (int nn = 0; nn < 4; ++nn)
            xw[(t * 32 + seq) * G3_ + tn * 64 + nn * 16 + m] = acc[nn][p];
    }
}

// ---------------------------------------------------------------------------
// fused: blocks 0-1 = gru1d (2 CUs); blocks 2-33 = f-reductions for tail
// ---------------------------------------------------------------------------
__global__ __launch_bounds__(512, 1) void gru1d_freduce(
        const float* __restrict__ xw, const short* __restrict__ Bfrag1,
        const float* __restrict__ bhh, float* __restrict__ hlast,
        const float* __restrict__ f, float* __restrict__ g) {
    __shared__ short hA[2][16 * PADA];
    __shared__ short8 Blds[2 * 48 * 64];   // kt 6,7

    const int tid = threadIdx.x;

    if (blockIdx.x >= 2) {
        const int b = blockIdx.x - 2;
        for (int i = tid; i < INTER_; i += 512) {
            const float* fp = f + (size_t)(b * 64) * INTER_ + i;
            float mx = -1e30f, mn = 1e30f, sm = 0.f;
            #pragma unroll 8
            for (int t = 0; t < 64; ++t) {
                float v = __builtin_nontemporal_load(fp + t * INTER_);
                mx = fmaxf(mx, v); mn = fminf(mn, v); sm += v;
            }
            g[b * GRED_ + i] = mx;
            g[b * GRED_ + INTER_ + i] = sm * (1.f / 64.f);
            g[b * GRED_ + 2 * INTER_ + i] = mn;
        }
        return;
    }

    const int lane = tid & 63;
    const int w = tid >> 6;
    const int m = lane & 15;
    const int q = lane >> 4;
    const int sblock = blockIdx.x * 16;

    for (int i = tid; i < 16 * PADA; i += 512) hA[0][i] = 0;
    {
        const uint4* src = (const uint4*)(Bfrag1 + 6 * 48 * 64 * 8);
        uint4* dst = (uint4*)Blds;
        #pragma unroll
        for (int rep = 0; rep < 12; ++rep)
            dst[tid + rep * 512] = src[tid + rep * 512];
    }
    const short8* Bf8 = (const short8*)Bfrag1;
    short8 Bres[36];
    #pragma unroll
    for (int kt = 0; kt < 6; ++kt)
        #pragma unroll
        for (int j = 0; j < 6; ++j)
            Bres[kt * 6 + j] = Bf8[(kt * 48 + 8 * j + w) * 64 + lane];

    const int u0 = 16 * w + m;
    const int u1 = 128 + u0;
    const float br0 = bhh[u0],       br1 = bhh[u1];
    const float bz0 = bhh[256 + u0], bz1 = bhh[256 + u1];
    const float bn0 = bhh[512 + u0], bn1 = bhh[512 + u1];

    float4v hreg0 = {0.f, 0.f, 0.f, 0.f}, hreg1 = {0.f, 0.f, 0.f, 0.f};
    __syncthreads();

    for (int t = 0; t < 64; ++t) {
        const short* hAc = hA[t & 1];

        float giR0[4], giR1[4], giZ0[4], giZ1[4], giN0[4], giN1[4];
        #pragma unroll
        for (int p = 0; p < 4; ++p) {
            const float* gr = xw + (size_t)(t * 32 + sblock + q * 4 + p) * G3_;
            giR0[p] = gr[u0];        giR1[p] = gr[u1];
            giZ0[p] = gr[256 + u0];  giZ1[p] = gr[256 + u1];
            giN0[p] = gr[512 + u0];  giN1[p] = gr[512 + u1];
        }

        float4v aR0 = {br0, br0, br0, br0}, aR1 = {br1, br1, br1, br1};
        float4v aZ0 = {bz0, bz0, bz0, bz0}, aZ1 = {bz1, bz1, bz1, bz1};
        float4v aN0 = {bn0, bn0, bn0, bn0}, aN1 = {bn1, bn1, bn1, bn1};

        #pragma unroll
        for (int kt = 0; kt < 6; ++kt) {
            short8 a = *(const short8*)(hAc + m * PADA + kt * 32 + q * 8);
            aR0 = MFMA(a, Bres[kt * 6 + 0], aR0, 0, 0, 0);
            aR1 = MFMA(a, Bres[kt * 6 + 1], aR1, 0, 0, 0);
            aZ0 = MFMA(a, Bres[kt * 6 + 2], aZ0, 0, 0, 0);
            aZ1 = MFMA(a, Bres[kt * 6 + 3], aZ1, 0, 0, 0);
            aN0 = MFMA(a, Bres[kt * 6 + 4], aN0, 0, 0, 0);
            aN1 = MFMA(a, Bres[kt * 6 + 5], aN1, 0, 0, 0);
        }
        #pragma unroll
        for (int kt = 0; kt < 2; ++kt) {
            short8 a = *(const short8*)(hAc + m * PADA + (6 + kt) * 32 + q * 8);
            short8 b0 = Blds[(kt * 48 + 8 * 0 + w) * 64 + lane];
            short8 b1 = Blds[(kt * 48 + 8 * 1 + w) * 64 + lane];
            short8 b2 = Blds[(kt * 48 + 8 * 2 + w) * 64 + lane];
            short8 b3 = Blds[(kt * 48 + 8 * 3 + w) * 64 + lane];
            short8 b4 = Blds[(kt * 48 + 8 * 4 + w) * 64 + lane];
            short8 b5 = Blds[(kt * 48 + 8 * 5 + w) * 64 + lane];
            aR0 = MFMA(a, b0, aR0, 0, 0, 0);
            aR1 = MFMA(a, b1, aR1, 0, 0, 0);
            aZ0 = MFMA(a, b2, aZ0, 0, 0, 0);
            aZ1 = MFMA(a, b3, aZ1, 0, 0, 0);
            aN0 = MFMA(a, b4, aN0, 0, 0, 0);
            aN1 = MFMA(a, b5, aN1, 0, 0, 0);
        }

        short* hAn = hA[(t + 1) & 1];
        #pragma unroll
        for (int p = 0; p < 4; ++p) {
            int row = q * 4 + p;
            float r0 = sigmoid_f(giR0[p] + aR0[p]);
            float z0 = sigmoid_f(giZ0[p] + aZ0[p]);
            float n0 = tanh_fast(giN0[p] + r0 * aN0[p]);
            float h0 = n0 + z0 * (hreg0[p] - n0);
            hreg0[p] = h0;
            hAn[row * PADA + u0] = f2bf(h0);
            float r1 = sigmoid_f(giR1[p] + aR1[p]);
            float z1 = sigmoid_f(giZ1[p] + aZ1[p]);
            float n1 = tanh_fast(giN1[p] + r1 * aN1[p]);
            float h1 = n1 + z1 * (hreg1[p] - n1);
            hreg1[p] = h1;
            hAn[row * PADA + u1] = f2bf(h1);
        }
        __syncthreads();
    }

    #pragma unroll
    for (int p = 0; p < 4; ++p) {
        int s = sblock + q * 4 + p;
        hlast[s * 256 + u0] = hreg0[p];
        hlast[s * 256 + u1] = hreg1[p];
    }
}

// ---------------------------------------------------------------------------
// tail_fc: g_lds = [g(b) | hlast(b)], fc1+relu, fc2
// ---------------------------------------------------------------------------
__global__ __launch_bounds__(256) void tail_fc(
        const float* __restrict__ g, const float* __restrict__ hlast,
        const float* __restrict__ fc1Wt, const float* __restrict__ fc1b,
        const float* __restrict__ fc2W, const float* __restrict__ fc2b,
        float* __restrict__ out) {
    __shared__ float g_lds[FCIN_];
    __shared__ float red[4];
    const int tid = threadIdx.x;
    const int b = blockIdx.x;
    for (int i = tid; i < GRED_; i += 256) g_lds[i] = g[b * GRED_ + i];
    g_lds[GRED_ + tid] = hlast[b * 256 + tid];
    __syncthreads();

    float a0 = 0.f, a1 = 0.f, a2 = 0.f, a3 = 0.f;
    for (int i = 0; i < FCIN_; i += 4) {
        a0 = fmaf(g_lds[i],     fc1Wt[(i) * 256 + tid],     a0);
        a1 = fmaf(g_lds[i + 1], fc1Wt[(i + 1) * 256 + tid], a1);
        a2 = fmaf(g_lds[i + 2], fc1Wt[(i + 2) * 256 + tid], a2);
        a3 = fmaf(g_lds[i + 3], fc1Wt[(i + 3) * 256 + tid], a3);
    }
    float acc = ((a0 + a1) + (a2 + a3)) + fc1b[tid];
    float hv = fmaxf(acc, 0.f);
    float part = hv * fc2W[tid];
    #pragma unroll
    for (int off = 32; off >= 1; off >>= 1)
        part += __shfl_down(part, off, 64);
    if ((tid & 63) == 0) red[tid >> 6] = part;
    __syncthreads();
    if (tid == 0)
        out[b] = fc2b[0] + red[0] + red[1] + red[2] + red[3];
}

// ---------------------------------------------------------------------------
extern "C" void kernel_launch(void* const* d_in, const int* in_sizes, int n_in,
                              void* d_out, int out_size, void* d_ws, size_t ws_size,
                              hipStream_t stream) {
    const float* x1     = (const float*)d_in[0];
    const float* states = (const float*)d_in[1];
    const int*   perm1  = (const int*)d_in[2];
    const int*   perm2  = (const int*)d_in[3];
    const float* Wih2   = (const float*)d_in[4];
    const float* Whh2   = (const float*)d_in[5];
    const float* bih2   = (const float*)d_in[6];
    const float* bhh2   = (const float*)d_in[7];
    const float* Wih1   = (const float*)d_in[8];
    const float* Whh1   = (const float*)d_in[9];
    const float* bih1   = (const float*)d_in[10];
    const float* bhh1   = (const float*)d_in[11];
    const float* fc1W   = (const float*)d_in[12];
    const float* fc1b   = (const float*)d_in[13];
    const float* fc2W   = (const float*)d_in[14];
    const float* fc2b   = (const float*)d_in[15];
    float* out = (float*)d_out;

    float* ws = (float*)d_ws;
    short* Bfrag   = (short*)ws;                          // 245760 bf16
    short* Bfrag1  = (short*)(ws + 122880);               // 196608 bf16
    short* Bfrag1W = (short*)(ws + 122880 + 98304);       // 712704 bf16
    float* fc1Wt   = ws + 577536;                         // 765952 f
    float* f       = fc1Wt + FCIN_ * 256;                 // 1343488
    short* fbf     = (short*)(f + 2048 * INTER_);         // 1900544 bf16
    float* xw1     = f + 2048 * INTER_ + 950272;          // 4161536
    float* hlast   = xw1 + 2048 * G3_;                    // 5734400
    float* g       = hlast + 8192;                        // 5742592 (+87552)

    prep_kernel<<<dim3(2992), 256, 0, stream>>>(Whh2, Wih2, Whh1, Wih1, fc1W,
                                                Bfrag, Bfrag1, Bfrag1W, fc1Wt);
    reduce_states_kernel<<<dim3(512), 256, 0, stream>>>(states, x1, f);
    gru2d_mfma<<<dim3(128), 512, 0, stream>>>(states, perm1, perm2, Bfrag,
                                              bih2, bhh2, f);
    convert_f_kernel<<<dim3(1856), 256, 0, stream>>>(f, fbf);
    gemm_xw1_mfma<<<dim3(12, 32), 256, 0, stream>>>(fbf, Bfrag1W, bih1, xw1);
    gru1d_freduce<<<dim3(34), 512, 0, stream>>>(xw1, Bfrag1, bhh1, hlast, f, g);
    tail_fc<<<dim3(32), 256, 0, stream>>>(g, hlast, fc1Wt, fc1b, fc2W, fc2b, out);
}

// Round 6
// 841.253 us; speedup vs baseline: 1.3191x; 1.3191x over previous
//
#include <hip/hip_runtime.h>
#include <cmath>

#define B_ 32
#define N_ 64
#define H_ 256
#define G3_ 768           // 3*H
#define INTER_ 912        // 2H + 6C + C1
#define KP_ 928           // INTER_ padded to 29*32 for bf16 MFMA GEMM
#define FCIN_ 2992        // 3*INTER + H
#define GRED_ 2736        // 3*INTER (f reductions part of g)

#define PADA 264          // hA row stride (bf16 elems)
#define PADX 72           // xA row stride (bf16 elems)

typedef __attribute__((ext_vector_type(8))) short short8;
typedef __attribute__((ext_vector_type(4))) short sshort4;
typedef __attribute__((ext_vector_type(4))) float float4v;

#define MFMA __builtin_amdgcn_mfma_f32_16x16x32_bf16

// single-instruction transcendentals: v_exp_f32 is exp2, v_rcp_f32
__device__ __forceinline__ float sigmoid_f(float x) {
    return __builtin_amdgcn_rcpf(1.0f + __builtin_amdgcn_exp2f(-1.44269504f * x));
}
__device__ __forceinline__ float tanh_fast(float x) {
    return 1.0f - 2.0f * __builtin_amdgcn_rcpf(1.0f + __builtin_amdgcn_exp2f(2.88539008f * x));
}
__device__ __forceinline__ unsigned f2bf_bits(float x) {
    unsigned u = __float_as_uint(x);
    return (u + 0x7fffu + ((u >> 16) & 1u)) >> 16;
}
__device__ __forceinline__ short f2bf(float x) { return (short)f2bf_bits(x); }

// ---------------------------------------------------------------------------
// prep: (a) Bfrag   = gru2d weights, fragment-major bf16 (layout verified R2)
//       (b) Bfrag1  = gru1d Whh, same pack (8 kt)
//       (c) Bfrag1W = gru1d Wih (768 x 912), same pack, K zero-padded to 928
//       (d) fc1Wt transpose
// Fragment layout: [kt][ntile(48)][lane(64)][j(8)] bf16; value = W[n][k] with
// n = ntile*16 + (lane&15), k = kt*32 + (lane>>4)*8 + j.
// ---------------------------------------------------------------------------
__global__ __launch_bounds__(256) void prep_kernel(
        const float* __restrict__ Whh2, const float* __restrict__ Wih2,
        const float* __restrict__ Whh1, const float* __restrict__ Wih1,
        const float* __restrict__ fc1W,
        short* __restrict__ Bfrag, short* __restrict__ Bfrag1,
        short* __restrict__ Bfrag1W, float* __restrict__ fc1Wt) {
    int idx = blockIdx.x * 256 + threadIdx.x;
    if (idx < 10 * 48 * 64 * 8) {
        int j = idx & 7, lane = (idx >> 3) & 63, tile = idx >> 9;
        int nt = tile % 48, kt = tile / 48;
        int n = nt * 16 + (lane & 15);
        int kb = (lane >> 4) * 8 + j;
        float v = (kt < 8) ? Whh2[n * 256 + kt * 32 + kb]
                           : Wih2[n * 64 + (kt - 8) * 32 + kb];
        Bfrag[idx] = f2bf(v);
    }
    if (idx < 8 * 48 * 64 * 8) {
        int j = idx & 7, lane = (idx >> 3) & 63, tile = idx >> 9;
        int nt = tile % 48, kt = tile / 48;
        int n = nt * 16 + (lane & 15);
        int k = kt * 32 + (lane >> 4) * 8 + j;
        Bfrag1[idx] = f2bf(Whh1[n * 256 + k]);
    }
    if (idx < 29 * 48 * 64 * 8) {
        int j = idx & 7, lane = (idx >> 3) & 63, tile = idx >> 9;
        int nt = tile % 48, kt = tile / 48;
        int n = nt * 16 + (lane & 15);
        int k = kt * 32 + (lane >> 4) * 8 + j;
        Bfrag1W[idx] = (k < INTER_) ? f2bf(Wih1[n * INTER_ + k]) : (short)0;
    }
    if (idx < FCIN_ * 256) {
        int o = idx & 255, i = idx >> 8;
        fc1Wt[idx] = fc1W[o * FCIN_ + i];
    }
}

// ---------------------------------------------------------------------------
// reduce_states: d[] reductions + x1 copy -> f[:, 0:400]. NT loads.
// ---------------------------------------------------------------------------
__global__ __launch_bounds__(256) void reduce_states_kernel(
        const float* __restrict__ states, const float* __restrict__ x1,
        float* __restrict__ f) {
    const int c = threadIdx.x & 63;
    const int bj = blockIdx.x * 4 + (threadIdx.x >> 6);
    const int b = bj >> 6, j = bj & 63;
    const float* p1 = states + b * 262144 + j * 64 + c;
    const float* p2 = states + b * 262144 + j * 4096 + c;
    float mx1 = -1e30f, mn1 = 1e30f, sm1 = 0.f;
    float mx2 = -1e30f, mn2 = 1e30f, sm2 = 0.f;
    #pragma unroll 8
    for (int n = 0; n < 64; ++n) {
        float v = __builtin_nontemporal_load(p1 + n * 4096);
        mx1 = fmaxf(mx1, v); mn1 = fminf(mn1, v); sm1 += v;
    }
    #pragma unroll 8
    for (int m = 0; m < 64; ++m) {
        float v = __builtin_nontemporal_load(p2 + m * 64);
        mx2 = fmaxf(mx2, v); mn2 = fminf(mn2, v); sm2 += v;
    }
    float* fr = f + bj * INTER_;
    fr[16 + c]  = mx1;  fr[80 + c]  = sm1 * (1.f / 64.f);  fr[144 + c] = mn1;
    fr[208 + c] = mx2;  fr[272 + c] = sm2 * (1.f / 64.f);  fr[336 + c] = mn2;
    if (c < 16) fr[c] = x1[bj * 16 + c];
}

// ---------------------------------------------------------------------------
// gru2d R6: 16-wave (1024-thread) blocks, R4 dataflow. Each wave owns ONE
// 16-col output chunk (u = w*16+m): tiles {R: nt=w, Z: nt=16+w, N: nt=32+w}.
// 4 waves/SIMD (vs 2) -> latency hiding across staggered waves; per-wave
// live set shrinks (Bres 18 short8, 4 acc chains) to fit 128 VGPR.
// B residency: kt0-5 regs, kt6-7 LDS, kt8-9 (x-part) per-step inline reload
// (L2-hot, R2-proven free). hA double-buffer, single barrier/step,
// bias-folded acc init, exp2/rcp transcendentals.
// ---------------------------------------------------------------------------
__global__ __launch_bounds__(1024, 1) void gru2d_mfma(
        const float* __restrict__ states,
        const int* __restrict__ perm1, const int* __restrict__ perm2,
        const short* __restrict__ Bfrag,
        const float* __restrict__ bih, const float* __restrict__ bhh,
        float* __restrict__ f) {
    __shared__ short hA[2][16 * PADA];
    __shared__ short xA[2][16 * PADX];
    __shared__ short8 Blds[2 * 48 * 64];
    __shared__ int perms[1024];

    const int tid = threadIdx.x;
    const int lane = tid & 63;
    const int w = tid >> 6;          // wave 0..15
    const int m = lane & 15;
    const int q = lane >> 4;
    const bool sd2 = blockIdx.x >= 128;
    const int sblock = (blockIdx.x & 127) * 16;

    {   // perms: one entry per thread; same-wave write->read pattern (safe)
        int r = tid >> 6, t = tid & 63;
        int qq = (sblock + r) & 63;
        perms[tid] = sd2 ? perm2[qq * 64 + t] : perm1[qq * 64 + t];
    }
    for (int i = tid; i < 16 * PADA; i += 1024) hA[0][i] = 0;
    {
        const uint4* src = (const uint4*)(Bfrag + 6 * 48 * 64 * 8);
        uint4* dst = (uint4*)Blds;
        #pragma unroll
        for (int rep = 0; rep < 6; ++rep)
            dst[tid + rep * 1024] = src[tid + rep * 1024];
    }

    const short8* Bf8 = (const short8*)Bfrag;
    short8 Bres[18];   // kt0-5 x {R,Z,N}
    #pragma unroll
    for (int kt = 0; kt < 6; ++kt) {
        Bres[kt * 3 + 0] = Bf8[(kt * 48 + w) * 64 + lane];
        Bres[kt * 3 + 1] = Bf8[(kt * 48 + 16 + w) * 64 + lane];
        Bres[kt * 3 + 2] = Bf8[(kt * 48 + 32 + w) * 64 + lane];
    }

    const int u = 16 * w + m;
    const float br = bih[u] + bhh[u];
    const float bz = bih[256 + u] + bhh[256 + u];
    const float bnx = bih[512 + u];
    const float bnh = bhh[512 + u];

    // per-thread x-gather geometry (thread -> (row r = w, col c = lane))
    const int sg = sblock + w;
    const int bb = sg >> 6, qq = sg & 63;
    const float* xbase = sd2 ? states + (size_t)bb * 262144 + qq * 64 + lane
                             : states + (size_t)(bb * 64 + qq) * 4096 + lane;
    const int pstride = sd2 ? 4096 : 64;
    const int xwofs = w * PADX + lane;

    float4v hreg = {0.f, 0.f, 0.f, 0.f};

    // x^0 staging (perms[w*64] written by lane 0 of this wave -> safe)
    xA[0][xwofs] = f2bf(xbase[perms[w * 64] * pstride]);
    __syncthreads();

    for (int t = 0; t < 64; ++t) {
        const short* hAc = hA[t & 1];
        const short* xAc = xA[t & 1];

        float xg = 0.f;
        if (t + 1 < 64)
            xg = xbase[perms[w * 64 + t + 1] * pstride];

        float4v aR  = {br, br, br, br};
        float4v aZ  = {bz, bz, bz, bz};
        float4v aNh = {bnh, bnh, bnh, bnh};
        float4v aNx = {bnx, bnx, bnx, bnx};

        #pragma unroll
        for (int kt = 0; kt < 6; ++kt) {
            short8 a = *(const short8*)(hAc + m * PADA + kt * 32 + q * 8);
            aR  = MFMA(a, Bres[kt * 3 + 0], aR, 0, 0, 0);
            aZ  = MFMA(a, Bres[kt * 3 + 1], aZ, 0, 0, 0);
            aNh = MFMA(a, Bres[kt * 3 + 2], aNh, 0, 0, 0);
        }
        #pragma unroll
        for (int kt = 0; kt < 2; ++kt) {
            short8 a = *(const short8*)(hAc + m * PADA + (6 + kt) * 32 + q * 8);
            short8 b0 = Blds[(kt * 48 + w) * 64 + lane];
            short8 b1 = Blds[(kt * 48 + 16 + w) * 64 + lane];
            short8 b2 = Blds[(kt * 48 + 32 + w) * 64 + lane];
            aR  = MFMA(a, b0, aR, 0, 0, 0);
            aZ  = MFMA(a, b1, aZ, 0, 0, 0);
            aNh = MFMA(a, b2, aNh, 0, 0, 0);
        }
        #pragma unroll
        for (int kt = 0; kt < 2; ++kt) {
            short8 a = *(const short8*)(xAc + m * PADX + kt * 32 + q * 8);
            short8 b0 = Bf8[((8 + kt) * 48 + w) * 64 + lane];
            short8 b1 = Bf8[((8 + kt) * 48 + 16 + w) * 64 + lane];
            short8 b2 = Bf8[((8 + kt) * 48 + 32 + w) * 64 + lane];
            aR  = MFMA(a, b0, aR, 0, 0, 0);
            aZ  = MFMA(a, b1, aZ, 0, 0, 0);
            aNx = MFMA(a, b2, aNx, 0, 0, 0);
        }

        short* hAn = hA[(t + 1) & 1];
        #pragma unroll
        for (int p = 0; p < 4; ++p) {
            int row = q * 4 + p;
            float r = sigmoid_f(aR[p]);
            float z = sigmoid_f(aZ[p]);
            float n = tanh_fast(aNx[p] + r * aNh[p]);
            float h = n + z * (hreg[p] - n);
            hreg[p] = h;
            hAn[row * PADA + u] = f2bf(h);
        }
        if (t + 1 < 64)
            xA[(t + 1) & 1][xwofs] = f2bf(xg);
        __syncthreads();
    }

    const int off = sd2 ? 656 : 400;
    #pragma unroll
    for (int p = 0; p < 4; ++p) {
        int s = sblock + q * 4 + p;
        f[s * INTER_ + off + u] = hreg[p];
    }
}

// ---------------------------------------------------------------------------
// convert f (fp32 [2048][912]) -> fbf (bf16 [2048][928], zero-padded K)
// ---------------------------------------------------------------------------
__global__ __launch_bounds__(256) void convert_f_kernel(
        const float* __restrict__ f, short* __restrict__ fbf) {
    int idx = blockIdx.x * 256 + threadIdx.x;
    int row = idx / 232;
    int c4 = (idx - row * 232) * 4;
    if (row >= 2048) return;
    sshort4 o;
    if (c4 < INTER_) {
        float4v v = *(const float4v*)(f + row * INTER_ + c4);
        o[0] = f2bf(v[0]); o[1] = f2bf(v[1]); o[2] = f2bf(v[2]); o[3] = f2bf(v[3]);
    } else {
        o[0] = 0; o[1] = 0; o[2] = 0; o[3] = 0;
    }
    *(sshort4*)(fbf + row * KP_ + c4) = o;
}

// ---------------------------------------------------------------------------
// xw1 = fbf[2048][928] @ Wih1^T (+bih1), bf16 MFMA. Output TRANSPOSED to
// [t][seq][768] so gru1d's per-step reads are step-contiguous.
// ---------------------------------------------------------------------------
__global__ __launch_bounds__(256) void gemm_xw1_mfma(
        const short* __restrict__ fbf, const short* __restrict__ BfragW,
        const float* __restrict__ bih, float* __restrict__ xw) {
    const int tid = threadIdx.x;
    const int lane = tid & 63;
    const int w = tid >> 6;
    const int m = lane & 15;
    const int q = lane >> 4;
    const int tn = blockIdx.x;
    const int tm = blockIdx.y;
    const int rowb = tm * 64 + w * 16;
    const short8* Bf8 = (const short8*)BfragW;

    float4v acc[4];
    #pragma unroll
    for (int nn = 0; nn < 4; ++nn) {
        float b = bih[tn * 64 + nn * 16 + m];
        acc[nn][0] = b; acc[nn][1] = b; acc[nn][2] = b; acc[nn][3] = b;
    }

    const short* arow = fbf + (rowb + m) * KP_;
    short8 a_cur = *(const short8*)(arow + q * 8);
    short8 b_cur[4];
    #pragma unroll
    for (int nn = 0; nn < 4; ++nn)
        b_cur[nn] = Bf8[(tn * 4 + nn) * 64 + lane];

    for (int kt = 0; kt < 29; ++kt) {
        short8 a_nxt = a_cur;
        short8 b_nxt[4];
        if (kt + 1 < 29) {
            a_nxt = *(const short8*)(arow + (kt + 1) * 32 + q * 8);
            #pragma unroll
            for (int nn = 0; nn < 4; ++nn)
                b_nxt[nn] = Bf8[((kt + 1) * 48 + tn * 4 + nn) * 64 + lane];
        }
        #pragma unroll
        for (int nn = 0; nn < 4; ++nn)
            acc[nn] = MFMA(a_cur, b_cur[nn], acc[nn], 0, 0, 0);
        a_cur = a_nxt;
        #pragma unroll
        for (int nn = 0; nn < 4; ++nn) b_cur[nn] = b_nxt[nn];
    }

    #pragma unroll
    for (int p = 0; p < 4; ++p) {
        int row = rowb + q * 4 + p;
        int seq = row >> 6, t = row & 63;
        #pragma unroll
        for (int nn = 0; nn < 4; ++nn)
            xw[(t * 32 + seq) * G3_ + tn * 64 + nn * 16 + m] = acc[nn][p];
    }
}

// ---------------------------------------------------------------------------
// fused: blocks 0-1 = gru1d (2 CUs, 16-wave version); blocks 2-33 =
// f-reductions for tail. gru1d: wave w owns chunk u=w*16+m, tiles
// {R:w, Z:16+w, N:32+w}; kt0-5 regs, kt6-7 LDS.
// ---------------------------------------------------------------------------
__global__ __launch_bounds__(1024, 1) void gru1d_freduce(
        const float* __restrict__ xw, const short* __restrict__ Bfrag1,
        const float* __restrict__ bhh, float* __restrict__ hlast,
        const float* __restrict__ f, float* __restrict__ g) {
    __shared__ short hA[2][16 * PADA];
    __shared__ short8 Blds[2 * 48 * 64];   // kt 6,7

    const int tid = threadIdx.x;

    if (blockIdx.x >= 2) {
        const int b = blockIdx.x - 2;
        for (int i = tid; i < INTER_; i += 1024) {
            const float* fp = f + (size_t)(b * 64) * INTER_ + i;
            float mx = -1e30f, mn = 1e30f, sm = 0.f;
            #pragma unroll 8
            for (int t = 0; t < 64; ++t) {
                float v = __builtin_nontemporal_load(fp + t * INTER_);
                mx = fmaxf(mx, v); mn = fminf(mn, v); sm += v;
            }
            g[b * GRED_ + i] = mx;
            g[b * GRED_ + INTER_ + i] = sm * (1.f / 64.f);
            g[b * GRED_ + 2 * INTER_ + i] = mn;
        }
        return;
    }

    const int lane = tid & 63;
    const int w = tid >> 6;          // wave 0..15
    const int m = lane & 15;
    const int q = lane >> 4;
    const int sblock = blockIdx.x * 16;

    for (int i = tid; i < 16 * PADA; i += 1024) hA[0][i] = 0;
    {
        const uint4* src = (const uint4*)(Bfrag1 + 6 * 48 * 64 * 8);
        uint4* dst = (uint4*)Blds;
        #pragma unroll
        for (int rep = 0; rep < 6; ++rep)
            dst[tid + rep * 1024] = src[tid + rep * 1024];
    }
    const short8* Bf8 = (const short8*)Bfrag1;
    short8 Bres[18];   // kt0-5 x {R,Z,N}
    #pragma unroll
    for (int kt = 0; kt < 6; ++kt) {
        Bres[kt * 3 + 0] = Bf8[(kt * 48 + w) * 64 + lane];
        Bres[kt * 3 + 1] = Bf8[(kt * 48 + 16 + w) * 64 + lane];
        Bres[kt * 3 + 2] = Bf8[(kt * 48 + 32 + w) * 64 + lane];
    }

    const int u = 16 * w + m;
    const float br = bhh[u];
    const float bz = bhh[256 + u];
    const float bn = bhh[512 + u];

    float4v hreg = {0.f, 0.f, 0.f, 0.f};
    __syncthreads();

    for (int t = 0; t < 64; ++t) {
        const short* hAc = hA[t & 1];

        // gi for this step (xw transposed: step-contiguous, L2-hot)
        float giR[4], giZ[4], giN[4];
        #pragma unroll
        for (int p = 0; p < 4; ++p) {
            const float* gr = xw + (size_t)(t * 32 + sblock + q * 4 + p) * G3_;
            giR[p] = gr[u];
            giZ[p] = gr[256 + u];
            giN[p] = gr[512 + u];
        }

        float4v aR = {br, br, br, br};
        float4v aZ = {bz, bz, bz, bz};
        float4v aN = {bn, bn, bn, bn};

        #pragma unroll
        for (int kt = 0; kt < 6; ++kt) {
            short8 a = *(const short8*)(hAc + m * PADA + kt * 32 + q * 8);
            aR = MFMA(a, Bres[kt * 3 + 0], aR, 0, 0, 0);
            aZ = MFMA(a, Bres[kt * 3 + 1], aZ, 0, 0, 0);
            aN = MFMA(a, Bres[kt * 3 + 2], aN, 0, 0, 0);
        }
        #pragma unroll
        for (int kt = 0; kt < 2; ++kt) {
            short8 a = *(const short8*)(hAc + m * PADA + (6 + kt) * 32 + q * 8);
            short8 b0 = Blds[(kt * 48 + w) * 64 + lane];
            short8 b1 = Blds[(kt * 48 + 16 + w) * 64 + lane];
            short8 b2 = Blds[(kt * 48 + 32 + w) * 64 + lane];
            aR = MFMA(a, b0, aR, 0, 0, 0);
            aZ = MFMA(a, b1, aZ, 0, 0, 0);
            aN = MFMA(a, b2, aN, 0, 0, 0);
        }

        short* hAn = hA[(t + 1) & 1];
        #pragma unroll
        for (int p = 0; p < 4; ++p) {
            int row = q * 4 + p;
            float r = sigmoid_f(giR[p] + aR[p]);
            float z = sigmoid_f(giZ[p] + aZ[p]);
            float n = tanh_fast(giN[p] + r * aN[p]);
            float h = n + z * (hreg[p] - n);
            hreg[p] = h;
            hAn[row * PADA + u] = f2bf(h);
        }
        __syncthreads();
    }

    #pragma unroll
    for (int p = 0; p < 4; ++p) {
        int s = sblock + q * 4 + p;
        hlast[s * 256 + u] = hreg[p];
    }
}

// ---------------------------------------------------------------------------
// tail_fc: g_lds = [g(b) | hlast(b)], fc1+relu, fc2
// ---------------------------------------------------------------------------
__global__ __launch_bounds__(256) void tail_fc(
        const float* __restrict__ g, const float* __restrict__ hlast,
        const float* __restrict__ fc1Wt, const float* __restrict__ fc1b,
        const float* __restrict__ fc2W, const float* __restrict__ fc2b,
        float* __restrict__ out) {
    __shared__ float g_lds[FCIN_];
    __shared__ float red[4];
    const int tid = threadIdx.x;
    const int b = blockIdx.x;
    for (int i = tid; i < GRED_; i += 256) g_lds[i] = g[b * GRED_ + i];
    g_lds[GRED_ + tid] = hlast[b * 256 + tid];
    __syncthreads();

    float a0 = 0.f, a1 = 0.f, a2 = 0.f, a3 = 0.f;
    for (int i = 0; i < FCIN_; i += 4) {
        a0 = fmaf(g_lds[i],     fc1Wt[(i) * 256 + tid],     a0);
        a1 = fmaf(g_lds[i + 1], fc1Wt[(i + 1) * 256 + tid], a1);
        a2 = fmaf(g_lds[i + 2], fc1Wt[(i + 2) * 256 + tid], a2);
        a3 = fmaf(g_lds[i + 3], fc1Wt[(i + 3) * 256 + tid], a3);
    }
    float acc = ((a0 + a1) + (a2 + a3)) + fc1b[tid];
    float hv = fmaxf(acc, 0.f);
    float part = hv * fc2W[tid];
    #pragma unroll
    for (int off = 32; off >= 1; off >>= 1)
        part += __shfl_down(part, off, 64);
    if ((tid & 63) == 0) red[tid >> 6] = part;
    __syncthreads();
    if (tid == 0)
        out[b] = fc2b[0] + red[0] + red[1] + red[2] + red[3];
}

// ---------------------------------------------------------------------------
extern "C" void kernel_launch(void* const* d_in, const int* in_sizes, int n_in,
                              void* d_out, int out_size, void* d_ws, size_t ws_size,
                              hipStream_t stream) {
    const float* x1     = (const float*)d_in[0];
    const float* states = (const float*)d_in[1];
    const int*   perm1  = (const int*)d_in[2];
    const int*   perm2  = (const int*)d_in[3];
    const float* Wih2   = (const float*)d_in[4];
    const float* Whh2   = (const float*)d_in[5];
    const float* bih2   = (const float*)d_in[6];
    const float* bhh2   = (const float*)d_in[7];
    const float* Wih1   = (const float*)d_in[8];
    const float* Whh1   = (const float*)d_in[9];
    const float* bih1   = (const float*)d_in[10];
    const float* bhh1   = (const float*)d_in[11];
    const float* fc1W   = (const float*)d_in[12];
    const float* fc1b   = (const float*)d_in[13];
    const float* fc2W   = (const float*)d_in[14];
    const float* fc2b   = (const float*)d_in[15];
    float* out = (float*)d_out;

    float* ws = (float*)d_ws;
    short* Bfrag   = (short*)ws;                          // 245760 bf16
    short* Bfrag1  = (short*)(ws + 122880);               // 196608 bf16
    short* Bfrag1W = (short*)(ws + 122880 + 98304);       // 712704 bf16
    float* fc1Wt   = ws + 577536;                         // 765952 f
    float* f       = fc1Wt + FCIN_ * 256;                 // 1343488
    short* fbf     = (short*)(f + 2048 * INTER_);         // 1900544 bf16
    float* xw1     = f + 2048 * INTER_ + 950272;          // 4161536
    float* hlast   = xw1 + 2048 * G3_;                    // 5734400
    float* g       = hlast + 8192;                        // 5742592 (+87552)

    prep_kernel<<<dim3(2992), 256, 0, stream>>>(Whh2, Wih2, Whh1, Wih1, fc1W,
                                                Bfrag, Bfrag1, Bfrag1W, fc1Wt);
    reduce_states_kernel<<<dim3(512), 256, 0, stream>>>(states, x1, f);
    gru2d_mfma<<<dim3(256), 1024, 0, stream>>>(states, perm1, perm2, Bfrag,
                                               bih2, bhh2, f);
    convert_f_kernel<<<dim3(1856), 256, 0, stream>>>(f, fbf);
    gemm_xw1_mfma<<<dim3(12, 32), 256, 0, stream>>>(fbf, Bfrag1W, bih1, xw1);
    gru1d_freduce<<<dim3(34), 1024, 0, stream>>>(xw1, Bfrag1, bhh1, hlast, f, g);
    tail_fc<<<dim3(32), 256, 0, stream>>>(g, hlast, fc1Wt, fc1b, fc2W, fc2b, out);
}

// Round 7
// 838.155 us; speedup vs baseline: 1.3240x; 1.0037x over previous
//
#include <hip/hip_runtime.h>
#include <cmath>

#define B_ 32
#define N_ 64
#define H_ 256
#define G3_ 768           // 3*H
#define INTER_ 912        // 2H + 6C + C1
#define KP_ 928           // INTER_ padded to 29*32 for bf16 MFMA GEMM
#define FCIN_ 2992        // 3*INTER + H
#define GRED_ 2736        // 3*INTER (f reductions part of g)

#define PADA 264          // hA row stride (bf16 elems)
#define PADX 72           // xA row stride (bf16 elems)

typedef __attribute__((ext_vector_type(8))) short short8;
typedef __attribute__((ext_vector_type(4))) short sshort4;
typedef __attribute__((ext_vector_type(4))) float float4v;

#define MFMA __builtin_amdgcn_mfma_f32_16x16x32_bf16

// single-instruction transcendentals: v_exp_f32 is exp2, v_rcp_f32
__device__ __forceinline__ float sigmoid_f(float x) {
    return __builtin_amdgcn_rcpf(1.0f + __builtin_amdgcn_exp2f(-1.44269504f * x));
}
__device__ __forceinline__ float tanh_fast(float x) {
    return 1.0f - 2.0f * __builtin_amdgcn_rcpf(1.0f + __builtin_amdgcn_exp2f(2.88539008f * x));
}
__device__ __forceinline__ unsigned f2bf_bits(float x) {
    unsigned u = __float_as_uint(x);
    return (u + 0x7fffu + ((u >> 16) & 1u)) >> 16;
}
__device__ __forceinline__ short f2bf(float x) { return (short)f2bf_bits(x); }

// ---------------------------------------------------------------------------
// prep: (a) Bfrag   = gru2d weights, fragment-major bf16 (layout verified R2)
//       (b) Bfrag1  = gru1d Whh, same pack (8 kt)
//       (c) Bfrag1W = gru1d Wih (768 x 912), same pack, K zero-padded to 928
//       (d) fc1Wt transpose
// Fragment layout: [kt][ntile(48)][lane(64)][j(8)] bf16; value = W[n][k] with
// n = ntile*16 + (lane&15), k = kt*32 + (lane>>4)*8 + j.
// ---------------------------------------------------------------------------
__global__ __launch_bounds__(256) void prep_kernel(
        const float* __restrict__ Whh2, const float* __restrict__ Wih2,
        const float* __restrict__ Whh1, const float* __restrict__ Wih1,
        const float* __restrict__ fc1W,
        short* __restrict__ Bfrag, short* __restrict__ Bfrag1,
        short* __restrict__ Bfrag1W, float* __restrict__ fc1Wt) {
    int idx = blockIdx.x * 256 + threadIdx.x;
    if (idx < 10 * 48 * 64 * 8) {
        int j = idx & 7, lane = (idx >> 3) & 63, tile = idx >> 9;
        int nt = tile % 48, kt = tile / 48;
        int n = nt * 16 + (lane & 15);
        int kb = (lane >> 4) * 8 + j;
        float v = (kt < 8) ? Whh2[n * 256 + kt * 32 + kb]
                           : Wih2[n * 64 + (kt - 8) * 32 + kb];
        Bfrag[idx] = f2bf(v);
    }
    if (idx < 8 * 48 * 64 * 8) {
        int j = idx & 7, lane = (idx >> 3) & 63, tile = idx >> 9;
        int nt = tile % 48, kt = tile / 48;
        int n = nt * 16 + (lane & 15);
        int k = kt * 32 + (lane >> 4) * 8 + j;
        Bfrag1[idx] = f2bf(Whh1[n * 256 + k]);
    }
    if (idx < 29 * 48 * 64 * 8) {
        int j = idx & 7, lane = (idx >> 3) & 63, tile = idx >> 9;
        int nt = tile % 48, kt = tile / 48;
        int n = nt * 16 + (lane & 15);
        int k = kt * 32 + (lane >> 4) * 8 + j;
        Bfrag1W[idx] = (k < INTER_) ? f2bf(Wih1[n * INTER_ + k]) : (short)0;
    }
    if (idx < FCIN_ * 256) {
        int o = idx & 255, i = idx >> 8;
        fc1Wt[idx] = fc1W[o * FCIN_ + i];
    }
}

// ---------------------------------------------------------------------------
// reduce_states: d[] reductions + x1 copy -> f[:, 0:400]. NT loads.
// ---------------------------------------------------------------------------
__global__ __launch_bounds__(256) void reduce_states_kernel(
        const float* __restrict__ states, const float* __restrict__ x1,
        float* __restrict__ f) {
    const int c = threadIdx.x & 63;
    const int bj = blockIdx.x * 4 + (threadIdx.x >> 6);
    const int b = bj >> 6, j = bj & 63;
    const float* p1 = states + b * 262144 + j * 64 + c;
    const float* p2 = states + b * 262144 + j * 4096 + c;
    float mx1 = -1e30f, mn1 = 1e30f, sm1 = 0.f;
    float mx2 = -1e30f, mn2 = 1e30f, sm2 = 0.f;
    #pragma unroll 8
    for (int n = 0; n < 64; ++n) {
        float v = __builtin_nontemporal_load(p1 + n * 4096);
        mx1 = fmaxf(mx1, v); mn1 = fminf(mn1, v); sm1 += v;
    }
    #pragma unroll 8
    for (int m = 0; m < 64; ++m) {
        float v = __builtin_nontemporal_load(p2 + m * 64);
        mx2 = fmaxf(mx2, v); mn2 = fminf(mn2, v); sm2 += v;
    }
    float* fr = f + bj * INTER_;
    fr[16 + c]  = mx1;  fr[80 + c]  = sm1 * (1.f / 64.f);  fr[144 + c] = mn1;
    fr[208 + c] = mx2;  fr[272 + c] = sm2 * (1.f / 64.f);  fr[336 + c] = mn2;
    if (c < 16) fr[c] = x1[bj * 16 + c];
}

// ---------------------------------------------------------------------------
// gru2d R7 = R6 16-wave structure + amdgpu_waves_per_eu(4,4).
// R6 failed because the backend chose a 64-VGPR budget for the 1024-thread
// kernel (live set ~110) -> massive scratch spills (FETCH 818 MB). Pinning
// waves/EU to 4 caps VGPR at 128 and removes the incentive to shrink below.
// Each wave owns ONE 16-col chunk (u = w*16+m): tiles {R:w, Z:16+w, N:32+w}.
// B residency: kt0-5 regs (18 short8), kt6-7 LDS, kt8-9 per-step inline
// reload (L2-hot). hA double-buffer, single barrier/step, bias-folded init.
// ---------------------------------------------------------------------------
__global__ __launch_bounds__(1024)
__attribute__((amdgpu_waves_per_eu(4, 4)))
void gru2d_mfma(
        const float* __restrict__ states,
        const int* __restrict__ perm1, const int* __restrict__ perm2,
        const short* __restrict__ Bfrag,
        const float* __restrict__ bih, const float* __restrict__ bhh,
        float* __restrict__ f) {
    __shared__ short hA[2][16 * PADA];
    __shared__ short xA[2][16 * PADX];
    __shared__ short8 Blds[2 * 48 * 64];
    __shared__ int perms[1024];

    const int tid = threadIdx.x;
    const int lane = tid & 63;
    const int w = tid >> 6;          // wave 0..15
    const int m = lane & 15;
    const int q = lane >> 4;
    const bool sd2 = blockIdx.x >= 128;
    const int sblock = (blockIdx.x & 127) * 16;

    {   // perms: one entry per thread; same-wave write->read pattern (safe)
        int r = tid >> 6, t = tid & 63;
        int qq = (sblock + r) & 63;
        perms[tid] = sd2 ? perm2[qq * 64 + t] : perm1[qq * 64 + t];
    }
    for (int i = tid; i < 16 * PADA; i += 1024) hA[0][i] = 0;
    {
        const uint4* src = (const uint4*)(Bfrag + 6 * 48 * 64 * 8);
        uint4* dst = (uint4*)Blds;
        #pragma unroll
        for (int rep = 0; rep < 6; ++rep)
            dst[tid + rep * 1024] = src[tid + rep * 1024];
    }

    const short8* Bf8 = (const short8*)Bfrag;
    short8 Bres[18];   // kt0-5 x {R,Z,N}
    #pragma unroll
    for (int kt = 0; kt < 6; ++kt) {
        Bres[kt * 3 + 0] = Bf8[(kt * 48 + w) * 64 + lane];
        Bres[kt * 3 + 1] = Bf8[(kt * 48 + 16 + w) * 64 + lane];
        Bres[kt * 3 + 2] = Bf8[(kt * 48 + 32 + w) * 64 + lane];
    }

    const int u = 16 * w + m;
    const float br = bih[u] + bhh[u];
    const float bz = bih[256 + u] + bhh[256 + u];
    const float bnx = bih[512 + u];
    const float bnh = bhh[512 + u];

    // per-thread x-gather geometry (thread -> (row r = w, col c = lane))
    const int sg = sblock + w;
    const int bb = sg >> 6, qq = sg & 63;
    const float* xbase = sd2 ? states + (size_t)bb * 262144 + qq * 64 + lane
                             : states + (size_t)(bb * 64 + qq) * 4096 + lane;
    const int pstride = sd2 ? 4096 : 64;
    const int xwofs = w * PADX + lane;

    float4v hreg = {0.f, 0.f, 0.f, 0.f};

    // x^0 staging (perms[w*64] written by lane 0 of this wave -> safe)
    xA[0][xwofs] = f2bf(xbase[perms[w * 64] * pstride]);
    __syncthreads();

    for (int t = 0; t < 64; ++t) {
        const short* hAc = hA[t & 1];
        const short* xAc = xA[t & 1];

        float xg = 0.f;
        if (t + 1 < 64)
            xg = xbase[perms[w * 64 + t + 1] * pstride];

        float4v aR  = {br, br, br, br};
        float4v aZ  = {bz, bz, bz, bz};
        float4v aNh = {bnh, bnh, bnh, bnh};
        float4v aNx = {bnx, bnx, bnx, bnx};

        #pragma unroll
        for (int kt = 0; kt < 6; ++kt) {
            short8 a = *(const short8*)(hAc + m * PADA + kt * 32 + q * 8);
            aR  = MFMA(a, Bres[kt * 3 + 0], aR, 0, 0, 0);
            aZ  = MFMA(a, Bres[kt * 3 + 1], aZ, 0, 0, 0);
            aNh = MFMA(a, Bres[kt * 3 + 2], aNh, 0, 0, 0);
        }
        #pragma unroll
        for (int kt = 0; kt < 2; ++kt) {
            short8 a = *(const short8*)(hAc + m * PADA + (6 + kt) * 32 + q * 8);
            short8 b0 = Blds[(kt * 48 + w) * 64 + lane];
            short8 b1 = Blds[(kt * 48 + 16 + w) * 64 + lane];
            short8 b2 = Blds[(kt * 48 + 32 + w) * 64 + lane];
            aR  = MFMA(a, b0, aR, 0, 0, 0);
            aZ  = MFMA(a, b1, aZ, 0, 0, 0);
            aNh = MFMA(a, b2, aNh, 0, 0, 0);
        }
        #pragma unroll
        for (int kt = 0; kt < 2; ++kt) {
            short8 a = *(const short8*)(xAc + m * PADX + kt * 32 + q * 8);
            short8 b0 = Bf8[((8 + kt) * 48 + w) * 64 + lane];
            short8 b1 = Bf8[((8 + kt) * 48 + 16 + w) * 64 + lane];
            short8 b2 = Bf8[((8 + kt) * 48 + 32 + w) * 64 + lane];
            aR  = MFMA(a, b0, aR, 0, 0, 0);
            aZ  = MFMA(a, b1, aZ, 0, 0, 0);
            aNx = MFMA(a, b2, aNx, 0, 0, 0);
        }

        short* hAn = hA[(t + 1) & 1];
        #pragma unroll
        for (int p = 0; p < 4; ++p) {
            int row = q * 4 + p;
            float r = sigmoid_f(aR[p]);
            float z = sigmoid_f(aZ[p]);
            float n = tanh_fast(aNx[p] + r * aNh[p]);
            float h = n + z * (hreg[p] - n);
            hreg[p] = h;
            hAn[row * PADA + u] = f2bf(h);
        }
        if (t + 1 < 64)
            xA[(t + 1) & 1][xwofs] = f2bf(xg);
        __syncthreads();
    }

    const int off = sd2 ? 656 : 400;
    #pragma unroll
    for (int p = 0; p < 4; ++p) {
        int s = sblock + q * 4 + p;
        f[s * INTER_ + off + u] = hreg[p];
    }
}

// ---------------------------------------------------------------------------
// convert f (fp32 [2048][912]) -> fbf (bf16 [2048][928], zero-padded K)
// ---------------------------------------------------------------------------
__global__ __launch_bounds__(256) void convert_f_kernel(
        const float* __restrict__ f, short* __restrict__ fbf) {
    int idx = blockIdx.x * 256 + threadIdx.x;
    int row = idx / 232;
    int c4 = (idx - row * 232) * 4;
    if (row >= 2048) return;
    sshort4 o;
    if (c4 < INTER_) {
        float4v v = *(const float4v*)(f + row * INTER_ + c4);
        o[0] = f2bf(v[0]); o[1] = f2bf(v[1]); o[2] = f2bf(v[2]); o[3] = f2bf(v[3]);
    } else {
        o[0] = 0; o[1] = 0; o[2] = 0; o[3] = 0;
    }
    *(sshort4*)(fbf + row * KP_ + c4) = o;
}

// ---------------------------------------------------------------------------
// xw1 = fbf[2048][928] @ Wih1^T (+bih1), bf16 MFMA. Output TRANSPOSED to
// [t][seq][768] so gru1d's per-step reads are step-contiguous.
// ---------------------------------------------------------------------------
__global__ __launch_bounds__(256) void gemm_xw1_mfma(
        const short* __restrict__ fbf, const short* __restrict__ BfragW,
        const float* __restrict__ bih, float* __restrict__ xw) {
    const int tid = threadIdx.x;
    const int lane = tid & 63;
    const int w = tid >> 6;
    const int m = lane & 15;
    const int q = lane >> 4;
    const int tn = blockIdx.x;
    const int tm = blockIdx.y;
    const int rowb = tm * 64 + w * 16;
    const short8* Bf8 = (const short8*)BfragW;

    float4v acc[4];
    #pragma unroll
    for (int nn = 0; nn < 4; ++nn) {
        float b = bih[tn * 64 + nn * 16 + m];
        acc[nn][0] = b; acc[nn][1] = b; acc[nn][2] = b; acc[nn][3] = b;
    }

    const short* arow = fbf + (rowb + m) * KP_;
    short8 a_cur = *(const short8*)(arow + q * 8);
    short8 b_cur[4];
    #pragma unroll
    for (int nn = 0; nn < 4; ++nn)
        b_cur[nn] = Bf8[(tn * 4 + nn) * 64 + lane];

    for (int kt = 0; kt < 29; ++kt) {
        short8 a_nxt = a_cur;
        short8 b_nxt[4];
        if (kt + 1 < 29) {
            a_nxt = *(const short8*)(arow + (kt + 1) * 32 + q * 8);
            #pragma unroll
            for (int nn = 0; nn < 4; ++nn)
                b_nxt[nn] = Bf8[((kt + 1) * 48 + tn * 4 + nn) * 64 + lane];
        }
        #pragma unroll
        for (int nn = 0; nn < 4; ++nn)
            acc[nn] = MFMA(a_cur, b_cur[nn], acc[nn], 0, 0, 0);
        a_cur = a_nxt;
        #pragma unroll
        for (int nn = 0; nn < 4; ++nn) b_cur[nn] = b_nxt[nn];
    }

    #pragma unroll
    for (int p = 0; p < 4; ++p) {
        int row = rowb + q * 4 + p;
        int seq = row >> 6, t = row & 63;
        #pragma unroll
        for (int nn = 0; nn < 4; ++nn)
            xw[(t * 32 + seq) * G3_ + tn * 64 + nn * 16 + m] = acc[nn][p];
    }
}

// ---------------------------------------------------------------------------
// fused: blocks 0-1 = gru1d (2 CUs, 16-wave version); blocks 2-33 =
// f-reductions for tail. gru1d: wave w owns chunk u=w*16+m, tiles
// {R:w, Z:16+w, N:32+w}; kt0-5 regs, kt6-7 LDS. waves_per_eu(4,4) pins
// the 128-VGPR budget (see gru2d comment).
// ---------------------------------------------------------------------------
__global__ __launch_bounds__(1024)
__attribute__((amdgpu_waves_per_eu(4, 4)))
void gru1d_freduce(
        const float* __restrict__ xw, const short* __restrict__ Bfrag1,
        const float* __restrict__ bhh, float* __restrict__ hlast,
        const float* __restrict__ f, float* __restrict__ g) {
    __shared__ short hA[2][16 * PADA];
    __shared__ short8 Blds[2 * 48 * 64];   // kt 6,7

    const int tid = threadIdx.x;

    if (blockIdx.x >= 2) {
        const int b = blockIdx.x - 2;
        for (int i = tid; i < INTER_; i += 1024) {
            const float* fp = f + (size_t)(b * 64) * INTER_ + i;
            float mx = -1e30f, mn = 1e30f, sm = 0.f;
            #pragma unroll 8
            for (int t = 0; t < 64; ++t) {
                float v = __builtin_nontemporal_load(fp + t * INTER_);
                mx = fmaxf(mx, v); mn = fminf(mn, v); sm += v;
            }
            g[b * GRED_ + i] = mx;
            g[b * GRED_ + INTER_ + i] = sm * (1.f / 64.f);
            g[b * GRED_ + 2 * INTER_ + i] = mn;
        }
        return;
    }

    const int lane = tid & 63;
    const int w = tid >> 6;          // wave 0..15
    const int m = lane & 15;
    const int q = lane >> 4;
    const int sblock = blockIdx.x * 16;

    for (int i = tid; i < 16 * PADA; i += 1024) hA[0][i] = 0;
    {
        const uint4* src = (const uint4*)(Bfrag1 + 6 * 48 * 64 * 8);
        uint4* dst = (uint4*)Blds;
        #pragma unroll
        for (int rep = 0; rep < 6; ++rep)
            dst[tid + rep * 1024] = src[tid + rep * 1024];
    }
    const short8* Bf8 = (const short8*)Bfrag1;
    short8 Bres[18];   // kt0-5 x {R,Z,N}
    #pragma unroll
    for (int kt = 0; kt < 6; ++kt) {
        Bres[kt * 3 + 0] = Bf8[(kt * 48 + w) * 64 + lane];
        Bres[kt * 3 + 1] = Bf8[(kt * 48 + 16 + w) * 64 + lane];
        Bres[kt * 3 + 2] = Bf8[(kt * 48 + 32 + w) * 64 + lane];
    }

    const int u = 16 * w + m;
    const float br = bhh[u];
    const float bz = bhh[256 + u];
    const float bn = bhh[512 + u];

    float4v hreg = {0.f, 0.f, 0.f, 0.f};
    __syncthreads();

    for (int t = 0; t < 64; ++t) {
        const short* hAc = hA[t & 1];

        // gi for this step (xw transposed: step-contiguous, L2-hot)
        float giR[4], giZ[4], giN[4];
        #pragma unroll
        for (int p = 0; p < 4; ++p) {
            const float* gr = xw + (size_t)(t * 32 + sblock + q * 4 + p) * G3_;
            giR[p] = gr[u];
            giZ[p] = gr[256 + u];
            giN[p] = gr[512 + u];
        }

        float4v aR = {br, br, br, br};
        float4v aZ = {bz, bz, bz, bz};
        float4v aN = {bn, bn, bn, bn};

        #pragma unroll
        for (int kt = 0; kt < 6; ++kt) {
            short8 a = *(const short8*)(hAc + m * PADA + kt * 32 + q * 8);
            aR = MFMA(a, Bres[kt * 3 + 0], aR, 0, 0, 0);
            aZ = MFMA(a, Bres[kt * 3 + 1], aZ, 0, 0, 0);
            aN = MFMA(a, Bres[kt * 3 + 2], aN, 0, 0, 0);
        }
        #pragma unroll
        for (int kt = 0; kt < 2; ++kt) {
            short8 a = *(const short8*)(hAc + m * PADA + (6 + kt) * 32 + q * 8);
            short8 b0 = Blds[(kt * 48 + w) * 64 + lane];
            short8 b1 = Blds[(kt * 48 + 16 + w) * 64 + lane];
            short8 b2 = Blds[(kt * 48 + 32 + w) * 64 + lane];
            aR = MFMA(a, b0, aR, 0, 0, 0);
            aZ = MFMA(a, b1, aZ, 0, 0, 0);
            aN = MFMA(a, b2, aN, 0, 0, 0);
        }

        short* hAn = hA[(t + 1) & 1];
        #pragma unroll
        for (int p = 0; p < 4; ++p) {
            int row = q * 4 + p;
            float r = sigmoid_f(giR[p] + aR[p]);
            float z = sigmoid_f(giZ[p] + aZ[p]);
            float n = tanh_fast(giN[p] + r * aN[p]);
            float h = n + z * (hreg[p] - n);
            hreg[p] = h;
            hAn[row * PADA + u] = f2bf(h);
        }
        __syncthreads();
    }

    #pragma unroll
    for (int p = 0; p < 4; ++p) {
        int s = sblock + q * 4 + p;
        hlast[s * 256 + u] = hreg[p];
    }
}

// ---------------------------------------------------------------------------
// tail_fc: g_lds = [g(b) | hlast(b)], fc1+relu, fc2
// ---------------------------------------------------------------------------
__global__ __launch_bounds__(256) void tail_fc(
        const float* __restrict__ g, const float* __restrict__ hlast,
        const float* __restrict__ fc1Wt, const float* __restrict__ fc1b,
        const float* __restrict__ fc2W, const float* __restrict__ fc2b,
        float* __restrict__ out) {
    __shared__ float g_lds[FCIN_];
    __shared__ float red[4];
    const int tid = threadIdx.x;
    const int b = blockIdx.x;
    for (int i = tid; i < GRED_; i += 256) g_lds[i] = g[b * GRED_ + i];
    g_lds[GRED_ + tid] = hlast[b * 256 + tid];
    __syncthreads();

    float a0 = 0.f, a1 = 0.f, a2 = 0.f, a3 = 0.f;
    for (int i = 0; i < FCIN_; i += 4) {
        a0 = fmaf(g_lds[i],     fc1Wt[(i) * 256 + tid],     a0);
        a1 = fmaf(g_lds[i + 1], fc1Wt[(i + 1) * 256 + tid], a1);
        a2 = fmaf(g_lds[i + 2], fc1Wt[(i + 2) * 256 + tid], a2);
        a3 = fmaf(g_lds[i + 3], fc1Wt[(i + 3) * 256 + tid], a3);
    }
    float acc = ((a0 + a1) + (a2 + a3)) + fc1b[tid];
    float hv = fmaxf(acc, 0.f);
    float part = hv * fc2W[tid];
    #pragma unroll
    for (int off = 32; off >= 1; off >>= 1)
        part += __shfl_down(part, off, 64);
    if ((tid & 63) == 0) red[tid >> 6] = part;
    __syncthreads();
    if (tid == 0)
        out[b] = fc2b[0] + red[0] + red[1] + red[2] + red[3];
}

// ---------------------------------------------------------------------------
extern "C" void kernel_launch(void* const* d_in, const int* in_sizes, int n_in,
                              void* d_out, int out_size, void* d_ws, size_t ws_size,
                              hipStream_t stream) {
    const float* x1     = (const float*)d_in[0];
    const float* states = (const float*)d_in[1];
    const int*   perm1  = (const int*)d_in[2];
    const int*   perm2  = (const int*)d_in[3];
    const float* Wih2   = (const float*)d_in[4];
    const float* Whh2   = (const float*)d_in[5];
    const float* bih2   = (const float*)d_in[6];
    const float* bhh2   = (const float*)d_in[7];
    const float* Wih1   = (const float*)d_in[8];
    const float* Whh1   = (const float*)d_in[9];
    const float* bih1   = (const float*)d_in[10];
    const float* bhh1   = (const float*)d_in[11];
    const float* fc1W   = (const float*)d_in[12];
    const float* fc1b   = (const float*)d_in[13];
    const float* fc2W   = (const float*)d_in[14];
    const float* fc2b   = (const float*)d_in[15];
    float* out = (float*)d_out;

    float* ws = (float*)d_ws;
    short* Bfrag   = (short*)ws;                          // 245760 bf16
    short* Bfrag1  = (short*)(ws + 122880);               // 196608 bf16
    short* Bfrag1W = (short*)(ws + 122880 + 98304);       // 712704 bf16
    float* fc1Wt   = ws + 577536;                         // 765952 f
    float* f       = fc1Wt + FCIN_ * 256;                 // 1343488
    short* fbf     = (short*)(f + 2048 * INTER_);         // 1900544 bf16
    float* xw1     = f + 2048 * INTER_ + 950272;          // 4161536
    float* hlast   = xw1 + 2048 * G3_;                    // 5734400
    float* g       = hlast + 8192;                        // 5742592 (+87552)

    prep_kernel<<<dim3(2992), 256, 0, stream>>>(Whh2, Wih2, Whh1, Wih1, fc1W,
                                                Bfrag, Bfrag1, Bfrag1W, fc1Wt);
    reduce_states_kernel<<<dim3(512), 256, 0, stream>>>(states, x1, f);
    gru2d_mfma<<<dim3(256), 1024, 0, stream>>>(states, perm1, perm2, Bfrag,
                                               bih2, bhh2, f);
    convert_f_kernel<<<dim3(1856), 256, 0, stream>>>(f, fbf);
    gemm_xw1_mfma<<<dim3(12, 32), 256, 0, stream>>>(fbf, Bfrag1W, bih1, xw1);
    gru1d_freduce<<<dim3(34), 1024, 0, stream>>>(xw1, Bfrag1, bhh1, hlast, f, g);
    tail_fc<<<dim3(32), 256, 0, stream>>>(g, hlast, fc1Wt, fc1b, fc2W, fc2b, out);
}

// Round 8
// 660.455 us; speedup vs baseline: 1.6802x; 1.2691x over previous
//
#include <hip/hip_runtime.h>
#include <cmath>

#define B_ 32
#define N_ 64
#define H_ 256
#define G3_ 768           // 3*H
#define INTER_ 912        // 2H + 6C + C1
#define KP_ 928           // INTER_ padded to 29*32 for bf16 MFMA GEMM
#define FCIN_ 2992        // 3*INTER + H
#define GRED_ 2736        // 3*INTER (f reductions part of g)

#define PADA 264          // hA row stride (bf16 elems)
#define PADX 72           // xA row stride (bf16 elems)

typedef __attribute__((ext_vector_type(8))) short short8;
typedef __attribute__((ext_vector_type(4))) short sshort4;
typedef __attribute__((ext_vector_type(4))) float float4v;

#define MFMA __builtin_amdgcn_mfma_f32_16x16x32_bf16

// single-instruction transcendentals: v_exp_f32 is exp2, v_rcp_f32
__device__ __forceinline__ float sigmoid_f(float x) {
    return __builtin_amdgcn_rcpf(1.0f + __builtin_amdgcn_exp2f(-1.44269504f * x));
}
__device__ __forceinline__ float tanh_fast(float x) {
    return 1.0f - 2.0f * __builtin_amdgcn_rcpf(1.0f + __builtin_amdgcn_exp2f(2.88539008f * x));
}
__device__ __forceinline__ unsigned f2bf_bits(float x) {
    unsigned u = __float_as_uint(x);
    return (u + 0x7fffu + ((u >> 16) & 1u)) >> 16;
}
__device__ __forceinline__ short f2bf(float x) { return (short)f2bf_bits(x); }

// ---------------------------------------------------------------------------
// prep: (a) Bfrag   = gru2d weights, fragment-major bf16 (layout verified R2)
//       (b) Bfrag1  = gru1d Whh, same pack (8 kt)
//       (c) Bfrag1W = gru1d Wih (768 x 912), same pack, K zero-padded to 928
//       (d) fc1Wt transpose
// Fragment layout: [kt][ntile(48)][lane(64)][j(8)] bf16; value = W[n][k] with
// n = ntile*16 + (lane&15), k = kt*32 + (lane>>4)*8 + j.
// ---------------------------------------------------------------------------
__global__ __launch_bounds__(256) void prep_kernel(
        const float* __restrict__ Whh2, const float* __restrict__ Wih2,
        const float* __restrict__ Whh1, const float* __restrict__ Wih1,
        const float* __restrict__ fc1W,
        short* __restrict__ Bfrag, short* __restrict__ Bfrag1,
        short* __restrict__ Bfrag1W, float* __restrict__ fc1Wt) {
    int idx = blockIdx.x * 256 + threadIdx.x;
    if (idx < 10 * 48 * 64 * 8) {
        int j = idx & 7, lane = (idx >> 3) & 63, tile = idx >> 9;
        int nt = tile % 48, kt = tile / 48;
        int n = nt * 16 + (lane & 15);
        int kb = (lane >> 4) * 8 + j;
        float v = (kt < 8) ? Whh2[n * 256 + kt * 32 + kb]
                           : Wih2[n * 64 + (kt - 8) * 32 + kb];
        Bfrag[idx] = f2bf(v);
    }
    if (idx < 8 * 48 * 64 * 8) {
        int j = idx & 7, lane = (idx >> 3) & 63, tile = idx >> 9;
        int nt = tile % 48, kt = tile / 48;
        int n = nt * 16 + (lane & 15);
        int k = kt * 32 + (lane >> 4) * 8 + j;
        Bfrag1[idx] = f2bf(Whh1[n * 256 + k]);
    }
    if (idx < 29 * 48 * 64 * 8) {
        int j = idx & 7, lane = (idx >> 3) & 63, tile = idx >> 9;
        int nt = tile % 48, kt = tile / 48;
        int n = nt * 16 + (lane & 15);
        int k = kt * 32 + (lane >> 4) * 8 + j;
        Bfrag1W[idx] = (k < INTER_) ? f2bf(Wih1[n * INTER_ + k]) : (short)0;
    }
    if (idx < FCIN_ * 256) {
        int o = idx & 255, i = idx >> 8;
        fc1Wt[idx] = fc1W[o * FCIN_ + i];
    }
}

// ---------------------------------------------------------------------------
// reduce_states: d[] reductions + x1 copy -> f[:, 0:400]. NT loads.
// ---------------------------------------------------------------------------
__global__ __launch_bounds__(256) void reduce_states_kernel(
        const float* __restrict__ states, const float* __restrict__ x1,
        float* __restrict__ f) {
    const int c = threadIdx.x & 63;
    const int bj = blockIdx.x * 4 + (threadIdx.x >> 6);
    const int b = bj >> 6, j = bj & 63;
    const float* p1 = states + b * 262144 + j * 64 + c;
    const float* p2 = states + b * 262144 + j * 4096 + c;
    float mx1 = -1e30f, mn1 = 1e30f, sm1 = 0.f;
    float mx2 = -1e30f, mn2 = 1e30f, sm2 = 0.f;
    #pragma unroll 8
    for (int n = 0; n < 64; ++n) {
        float v = __builtin_nontemporal_load(p1 + n * 4096);
        mx1 = fmaxf(mx1, v); mn1 = fminf(mn1, v); sm1 += v;
    }
    #pragma unroll 8
    for (int m = 0; m < 64; ++m) {
        float v = __builtin_nontemporal_load(p2 + m * 64);
        mx2 = fmaxf(mx2, v); mn2 = fminf(mn2, v); sm2 += v;
    }
    float* fr = f + bj * INTER_;
    fr[16 + c]  = mx1;  fr[80 + c]  = sm1 * (1.f / 64.f);  fr[144 + c] = mn1;
    fr[208 + c] = mx2;  fr[272 + c] = sm2 * (1.f / 64.f);  fr[336 + c] = mn2;
    if (c < 16) fr[c] = x1[bj * 16 + c];
}

// ---------------------------------------------------------------------------
// gru2d R8: 16-wave blocks with register-lean B residency.
//  - __launch_bounds__(1024, 4): documented HIP knob; min 4 waves/EU ->
//    VGPR cap 512/4 = 128 (R7's amdgpu_waves_per_eu attribute was ignored;
//    VGPR stayed 64 -> spills -> 818 MB FETCH).
//  - per-wave residency cut to fit 128: Bres kt0-3 only (12 frags = 48),
//    Blds kt4-5 (98 KB LDS), kt6-7 + kt8-9(x) STREAMED from L2 per step
//    (R2-proven pattern; two 24-reg windows, issue-early/consume-late).
//  - wave w owns one 16-col chunk u = w*16+m: tiles {R:w, Z:16+w, N:32+w}.
//  - hA double-buffer, single barrier/step, bias-folded init.
// ---------------------------------------------------------------------------
__global__ __launch_bounds__(1024, 4)
void gru2d_mfma(
        const float* __restrict__ states,
        const int* __restrict__ perm1, const int* __restrict__ perm2,
        const short* __restrict__ Bfrag,
        const float* __restrict__ bih, const float* __restrict__ bhh,
        float* __restrict__ f) {
    __shared__ short hA[2][16 * PADA];
    __shared__ short xA[2][16 * PADX];
    __shared__ short8 Blds[2 * 48 * 64];   // kt 4,5
    __shared__ int perms[1024];

    const int tid = threadIdx.x;
    const int lane = tid & 63;
    const int w = tid >> 6;          // wave 0..15
    const int m = lane & 15;
    const int q = lane >> 4;
    const bool sd2 = blockIdx.x >= 128;
    const int sblock = (blockIdx.x & 127) * 16;

    {   // perms: one entry per thread; same-wave write->read pattern (safe)
        int r = tid >> 6, t = tid & 63;
        int qq = (sblock + r) & 63;
        perms[tid] = sd2 ? perm2[qq * 64 + t] : perm1[qq * 64 + t];
    }
    for (int i = tid; i < 16 * PADA; i += 1024) hA[0][i] = 0;
    {
        const uint4* src = (const uint4*)(Bfrag + 4 * 48 * 64 * 8);  // kt4-5
        uint4* dst = (uint4*)Blds;
        #pragma unroll
        for (int rep = 0; rep < 6; ++rep)
            dst[tid + rep * 1024] = src[tid + rep * 1024];
    }

    const short8* Bf8 = (const short8*)Bfrag;
    short8 Bres[12];   // kt0-3 x {R,Z,N}
    #pragma unroll
    for (int kt = 0; kt < 4; ++kt) {
        Bres[kt * 3 + 0] = Bf8[(kt * 48 + w) * 64 + lane];
        Bres[kt * 3 + 1] = Bf8[(kt * 48 + 16 + w) * 64 + lane];
        Bres[kt * 3 + 2] = Bf8[(kt * 48 + 32 + w) * 64 + lane];
    }

    const int u = 16 * w + m;
    const float br = bih[u] + bhh[u];
    const float bz = bih[256 + u] + bhh[256 + u];
    const float bnx = bih[512 + u];
    const float bnh = bhh[512 + u];

    // per-thread x-gather geometry (thread -> (row r = w, col c = lane))
    const int sg = sblock + w;
    const int bb = sg >> 6, qq = sg & 63;
    const float* xbase = sd2 ? states + (size_t)bb * 262144 + qq * 64 + lane
                             : states + (size_t)(bb * 64 + qq) * 4096 + lane;
    const int pstride = sd2 ? 4096 : 64;
    const int xwofs = w * PADX + lane;

    float4v hreg = {0.f, 0.f, 0.f, 0.f};

    // x^0 staging (perms[w*64] written by lane 0 of this wave -> safe)
    xA[0][xwofs] = f2bf(xbase[perms[w * 64] * pstride]);
    __syncthreads();

    for (int t = 0; t < 64; ++t) {
        const short* hAc = hA[t & 1];
        const short* xAc = xA[t & 1];

        // stream kt6-7 (h-part) early: latency hides under kt0-5 MFMAs
        short8 s6a = Bf8[(6 * 48 + w) * 64 + lane];
        short8 s6b = Bf8[(6 * 48 + 16 + w) * 64 + lane];
        short8 s6c = Bf8[(6 * 48 + 32 + w) * 64 + lane];
        short8 s7a = Bf8[(7 * 48 + w) * 64 + lane];
        short8 s7b = Bf8[(7 * 48 + 16 + w) * 64 + lane];
        short8 s7c = Bf8[(7 * 48 + 32 + w) * 64 + lane];

        float xg = 0.f;
        if (t + 1 < 64)
            xg = xbase[perms[w * 64 + t + 1] * pstride];

        float4v aR  = {br, br, br, br};
        float4v aZ  = {bz, bz, bz, bz};
        float4v aNh = {bnh, bnh, bnh, bnh};
        float4v aNx = {bnx, bnx, bnx, bnx};

        #pragma unroll
        for (int kt = 0; kt < 4; ++kt) {
            short8 a = *(const short8*)(hAc + m * PADA + kt * 32 + q * 8);
            aR  = MFMA(a, Bres[kt * 3 + 0], aR, 0, 0, 0);
            aZ  = MFMA(a, Bres[kt * 3 + 1], aZ, 0, 0, 0);
            aNh = MFMA(a, Bres[kt * 3 + 2], aNh, 0, 0, 0);
        }
        #pragma unroll
        for (int kt = 0; kt < 2; ++kt) {
            short8 a = *(const short8*)(hAc + m * PADA + (4 + kt) * 32 + q * 8);
            short8 b0 = Blds[(kt * 48 + w) * 64 + lane];
            short8 b1 = Blds[(kt * 48 + 16 + w) * 64 + lane];
            short8 b2 = Blds[(kt * 48 + 32 + w) * 64 + lane];
            aR  = MFMA(a, b0, aR, 0, 0, 0);
            aZ  = MFMA(a, b1, aZ, 0, 0, 0);
            aNh = MFMA(a, b2, aNh, 0, 0, 0);
        }
        // kt6 consume (frees s6*)
        {
            short8 a = *(const short8*)(hAc + m * PADA + 6 * 32 + q * 8);
            aR  = MFMA(a, s6a, aR, 0, 0, 0);
            aZ  = MFMA(a, s6b, aZ, 0, 0, 0);
            aNh = MFMA(a, s6c, aNh, 0, 0, 0);
        }
        // stream kt8-9 (x-part) now; covered by kt7 MFMAs + epilogue latency
        short8 s8a = Bf8[(8 * 48 + w) * 64 + lane];
        short8 s8b = Bf8[(8 * 48 + 16 + w) * 64 + lane];
        short8 s8c = Bf8[(8 * 48 + 32 + w) * 64 + lane];
        short8 s9a = Bf8[(9 * 48 + w) * 64 + lane];
        short8 s9b = Bf8[(9 * 48 + 16 + w) * 64 + lane];
        short8 s9c = Bf8[(9 * 48 + 32 + w) * 64 + lane];
        // kt7 consume
        {
            short8 a = *(const short8*)(hAc + m * PADA + 7 * 32 + q * 8);
            aR  = MFMA(a, s7a, aR, 0, 0, 0);
            aZ  = MFMA(a, s7b, aZ, 0, 0, 0);
            aNh = MFMA(a, s7c, aNh, 0, 0, 0);
        }
        // x-part
        {
            short8 a = *(const short8*)(xAc + m * PADX + 0 * 32 + q * 8);
            aR  = MFMA(a, s8a, aR, 0, 0, 0);
            aZ  = MFMA(a, s8b, aZ, 0, 0, 0);
            aNx = MFMA(a, s8c, aNx, 0, 0, 0);
        }
        {
            short8 a = *(const short8*)(xAc + m * PADX + 1 * 32 + q * 8);
            aR  = MFMA(a, s9a, aR, 0, 0, 0);
            aZ  = MFMA(a, s9b, aZ, 0, 0, 0);
            aNx = MFMA(a, s9c, aNx, 0, 0, 0);
        }

        short* hAn = hA[(t + 1) & 1];
        #pragma unroll
        for (int p = 0; p < 4; ++p) {
            int row = q * 4 + p;
            float r = sigmoid_f(aR[p]);
            float z = sigmoid_f(aZ[p]);
            float n = tanh_fast(aNx[p] + r * aNh[p]);
            float h = n + z * (hreg[p] - n);
            hreg[p] = h;
            hAn[row * PADA + u] = f2bf(h);
        }
        if (t + 1 < 64)
            xA[(t + 1) & 1][xwofs] = f2bf(xg);
        __syncthreads();
    }

    const int off = sd2 ? 656 : 400;
    #pragma unroll
    for (int p = 0; p < 4; ++p) {
        int s = sblock + q * 4 + p;
        f[s * INTER_ + off + u] = hreg[p];
    }
}

// ---------------------------------------------------------------------------
// convert f (fp32 [2048][912]) -> fbf (bf16 [2048][928], zero-padded K)
// ---------------------------------------------------------------------------
__global__ __launch_bounds__(256) void convert_f_kernel(
        const float* __restrict__ f, short* __restrict__ fbf) {
    int idx = blockIdx.x * 256 + threadIdx.x;
    int row = idx / 232;
    int c4 = (idx - row * 232) * 4;
    if (row >= 2048) return;
    sshort4 o;
    if (c4 < INTER_) {
        float4v v = *(const float4v*)(f + row * INTER_ + c4);
        o[0] = f2bf(v[0]); o[1] = f2bf(v[1]); o[2] = f2bf(v[2]); o[3] = f2bf(v[3]);
    } else {
        o[0] = 0; o[1] = 0; o[2] = 0; o[3] = 0;
    }
    *(sshort4*)(fbf + row * KP_ + c4) = o;
}

// ---------------------------------------------------------------------------
// xw1 = fbf[2048][928] @ Wih1^T (+bih1), bf16 MFMA. Output TRANSPOSED to
// [t][seq][768] so gru1d's per-step reads are step-contiguous.
// ---------------------------------------------------------------------------
__global__ __launch_bounds__(256) void gemm_xw1_mfma(
        const short* __restrict__ fbf, const short* __restrict__ BfragW,
        const float* __restrict__ bih, float* __restrict__ xw) {
    const int tid = threadIdx.x;
    const int lane = tid & 63;
    const int w = tid >> 6;
    const int m = lane & 15;
    const int q = lane >> 4;
    const int tn = blockIdx.x;
    const int tm = blockIdx.y;
    const int rowb = tm * 64 + w * 16;
    const short8* Bf8 = (const short8*)BfragW;

    float4v acc[4];
    #pragma unroll
    for (int nn = 0; nn < 4; ++nn) {
        float b = bih[tn * 64 + nn * 16 + m];
        acc[nn][0] = b; acc[nn][1] = b; acc[nn][2] = b; acc[nn][3] = b;
    }

    const short* arow = fbf + (rowb + m) * KP_;
    short8 a_cur = *(const short8*)(arow + q * 8);
    short8 b_cur[4];
    #pragma unroll
    for (int nn = 0; nn < 4; ++nn)
        b_cur[nn] = Bf8[(tn * 4 + nn) * 64 + lane];

    for (int kt = 0; kt < 29; ++kt) {
        short8 a_nxt = a_cur;
        short8 b_nxt[4];
        if (kt + 1 < 29) {
            a_nxt = *(const short8*)(arow + (kt + 1) * 32 + q * 8);
            #pragma unroll
            for (int nn = 0; nn < 4; ++nn)
                b_nxt[nn] = Bf8[((kt + 1) * 48 + tn * 4 + nn) * 64 + lane];
        }
        #pragma unroll
        for (int nn = 0; nn < 4; ++nn)
            acc[nn] = MFMA(a_cur, b_cur[nn], acc[nn], 0, 0, 0);
        a_cur = a_nxt;
        #pragma unroll
        for (int nn = 0; nn < 4; ++nn) b_cur[nn] = b_nxt[nn];
    }

    #pragma unroll
    for (int p = 0; p < 4; ++p) {
        int row = rowb + q * 4 + p;
        int seq = row >> 6, t = row & 63;
        #pragma unroll
        for (int nn = 0; nn < 4; ++nn)
            xw[(t * 32 + seq) * G3_ + tn * 64 + nn * 16 + m] = acc[nn][p];
    }
}

// ---------------------------------------------------------------------------
// fused: blocks 0-1 = gru1d (2 CUs); blocks 2-33 = f-reductions for tail.
// R4-proven 512-thread form (8 waves, wave owns 2 chunks u0/u1).
// ---------------------------------------------------------------------------
__global__ __launch_bounds__(512, 1) void gru1d_freduce(
        const float* __restrict__ xw, const short* __restrict__ Bfrag1,
        const float* __restrict__ bhh, float* __restrict__ hlast,
        const float* __restrict__ f, float* __restrict__ g) {
    __shared__ short hA[2][16 * PADA];
    __shared__ short8 Blds[2 * 48 * 64];   // kt 6,7

    const int tid = threadIdx.x;

    if (blockIdx.x >= 2) {
        const int b = blockIdx.x - 2;
        for (int i = tid; i < INTER_; i += 512) {
            const float* fp = f + (size_t)(b * 64) * INTER_ + i;
            float mx = -1e30f, mn = 1e30f, sm = 0.f;
            #pragma unroll 8
            for (int t = 0; t < 64; ++t) {
                float v = __builtin_nontemporal_load(fp + t * INTER_);
                mx = fmaxf(mx, v); mn = fminf(mn, v); sm += v;
            }
            g[b * GRED_ + i] = mx;
            g[b * GRED_ + INTER_ + i] = sm * (1.f / 64.f);
            g[b * GRED_ + 2 * INTER_ + i] = mn;
        }
        return;
    }

    const int lane = tid & 63;
    const int w = tid >> 6;
    const int m = lane & 15;
    const int q = lane >> 4;
    const int sblock = blockIdx.x * 16;

    for (int i = tid; i < 16 * PADA; i += 512) hA[0][i] = 0;
    {
        const uint4* src = (const uint4*)(Bfrag1 + 6 * 48 * 64 * 8);
        uint4* dst = (uint4*)Blds;
        #pragma unroll
        for (int rep = 0; rep < 12; ++rep)
            dst[tid + rep * 512] = src[tid + rep * 512];
    }
    const short8* Bf8 = (const short8*)Bfrag1;
    short8 Bres[36];
    #pragma unroll
    for (int kt = 0; kt < 6; ++kt)
        #pragma unroll
        for (int j = 0; j < 6; ++j)
            Bres[kt * 6 + j] = Bf8[(kt * 48 + 8 * j + w) * 64 + lane];

    const int u0 = 16 * w + m;
    const int u1 = 128 + u0;
    const float br0 = bhh[u0],       br1 = bhh[u1];
    const float bz0 = bhh[256 + u0], bz1 = bhh[256 + u1];
    const float bn0 = bhh[512 + u0], bn1 = bhh[512 + u1];

    float4v hreg0 = {0.f, 0.f, 0.f, 0.f}, hreg1 = {0.f, 0.f, 0.f, 0.f};
    __syncthreads();

    for (int t = 0; t < 64; ++t) {
        const short* hAc = hA[t & 1];

        float giR0[4], giR1[4], giZ0[4], giZ1[4], giN0[4], giN1[4];
        #pragma unroll
        for (int p = 0; p < 4; ++p) {
            const float* gr = xw + (size_t)(t * 32 + sblock + q * 4 + p) * G3_;
            giR0[p] = gr[u0];        giR1[p] = gr[u1];
            giZ0[p] = gr[256 + u0];  giZ1[p] = gr[256 + u1];
            giN0[p] = gr[512 + u0];  giN1[p] = gr[512 + u1];
        }

        float4v aR0 = {br0, br0, br0, br0}, aR1 = {br1, br1, br1, br1};
        float4v aZ0 = {bz0, bz0, bz0, bz0}, aZ1 = {bz1, bz1, bz1, bz1};
        float4v aN0 = {bn0, bn0, bn0, bn0}, aN1 = {bn1, bn1, bn1, bn1};

        #pragma unroll
        for (int kt = 0; kt < 6; ++kt) {
            short8 a = *(const short8*)(hAc + m * PADA + kt * 32 + q * 8);
            aR0 = MFMA(a, Bres[kt * 6 + 0], aR0, 0, 0, 0);
            aR1 = MFMA(a, Bres[kt * 6 + 1], aR1, 0, 0, 0);
            aZ0 = MFMA(a, Bres[kt * 6 + 2], aZ0, 0, 0, 0);
            aZ1 = MFMA(a, Bres[kt * 6 + 3], aZ1, 0, 0, 0);
            aN0 = MFMA(a, Bres[kt * 6 + 4], aN0, 0, 0, 0);
            aN1 = MFMA(a, Bres[kt * 6 + 5], aN1, 0, 0, 0);
        }
        #pragma unroll
        for (int kt = 0; kt < 2; ++kt) {
            short8 a = *(const short8*)(hAc + m * PADA + (6 + kt) * 32 + q * 8);
            short8 b0 = Blds[(kt * 48 + 8 * 0 + w) * 64 + lane];
            short8 b1 = Blds[(kt * 48 + 8 * 1 + w) * 64 + lane];
            short8 b2 = Blds[(kt * 48 + 8 * 2 + w) * 64 + lane];
            short8 b3 = Blds[(kt * 48 + 8 * 3 + w) * 64 + lane];
            short8 b4 = Blds[(kt * 48 + 8 * 4 + w) * 64 + lane];
            short8 b5 = Blds[(kt * 48 + 8 * 5 + w) * 64 + lane];
            aR0 = MFMA(a, b0, aR0, 0, 0, 0);
            aR1 = MFMA(a, b1, aR1, 0, 0, 0);
            aZ0 = MFMA(a, b2, aZ0, 0, 0, 0);
            aZ1 = MFMA(a, b3, aZ1, 0, 0, 0);
            aN0 = MFMA(a, b4, aN0, 0, 0, 0);
            aN1 = MFMA(a, b5, aN1, 0, 0, 0);
        }

        short* hAn = hA[(t + 1) & 1];
        #pragma unroll
        for (int p = 0; p < 4; ++p) {
            int row = q * 4 + p;
            float r0 = sigmoid_f(giR0[p] + aR0[p]);
            float z0 = sigmoid_f(giZ0[p] + aZ0[p]);
            float n0 = tanh_fast(giN0[p] + r0 * aN0[p]);
            float h0 = n0 + z0 * (hreg0[p] - n0);
            hreg0[p] = h0;
            hAn[row * PADA + u0] = f2bf(h0);
            float r1 = sigmoid_f(giR1[p] + aR1[p]);
            float z1 = sigmoid_f(giZ1[p] + aZ1[p]);
            float n1 = tanh_fast(giN1[p] + r1 * aN1[p]);
            float h1 = n1 + z1 * (hreg1[p] - n1);
            hreg1[p] = h1;
            hAn[row * PADA + u1] = f2bf(h1);
        }
        __syncthreads();
    }

    #pragma unroll
    for (int p = 0; p < 4; ++p) {
        int s = sblock + q * 4 + p;
        hlast[s * 256 + u0] = hreg0[p];
        hlast[s * 256 + u1] = hreg1[p];
    }
}

// ---------------------------------------------------------------------------
// tail_fc: g_lds = [g(b) | hlast(b)], fc1+relu, fc2
// ---------------------------------------------------------------------------
__global__ __launch_bounds__(256) void tail_fc(
        const float* __restrict__ g, const float* __restrict__ hlast,
        const float* __restrict__ fc1Wt, const float* __restrict__ fc1b,
        const float* __restrict__ fc2W, const float* __restrict__ fc2b,
        float* __restrict__ out) {
    __shared__ float g_lds[FCIN_];
    __shared__ float red[4];
    const int tid = threadIdx.x;
    const int b = blockIdx.x;
    for (int i = tid; i < GRED_; i += 256) g_lds[i] = g[b * GRED_ + i];
    g_lds[GRED_ + tid] = hlast[b * 256 + tid];
    __syncthreads();

    float a0 = 0.f, a1 = 0.f, a2 = 0.f, a3 = 0.f;
    for (int i = 0; i < FCIN_; i += 4) {
        a0 = fmaf(g_lds[i],     fc1Wt[(i) * 256 + tid],     a0);
        a1 = fmaf(g_lds[i + 1], fc1Wt[(i + 1) * 256 + tid], a1);
        a2 = fmaf(g_lds[i + 2], fc1Wt[(i + 2) * 256 + tid], a2);
        a3 = fmaf(g_lds[i + 3], fc1Wt[(i + 3) * 256 + tid], a3);
    }
    float acc = ((a0 + a1) + (a2 + a3)) + fc1b[tid];
    float hv = fmaxf(acc, 0.f);
    float part = hv * fc2W[tid];
    #pragma unroll
    for (int off = 32; off >= 1; off >>= 1)
        part += __shfl_down(part, off, 64);
    if ((tid & 63) == 0) red[tid >> 6] = part;
    __syncthreads();
    if (tid == 0)
        out[b] = fc2b[0] + red[0] + red[1] + red[2] + red[3];
}

// ---------------------------------------------------------------------------
extern "C" void kernel_launch(void* const* d_in, const int* in_sizes, int n_in,
                              void* d_out, int out_size, void* d_ws, size_t ws_size,
                              hipStream_t stream) {
    const float* x1     = (const float*)d_in[0];
    const float* states = (const float*)d_in[1];
    const int*   perm1  = (const int*)d_in[2];
    const int*   perm2  = (const int*)d_in[3];
    const float* Wih2   = (const float*)d_in[4];
    const float* Whh2   = (const float*)d_in[5];
    const float* bih2   = (const float*)d_in[6];
    const float* bhh2   = (const float*)d_in[7];
    const float* Wih1   = (const float*)d_in[8];
    const float* Whh1   = (const float*)d_in[9];
    const float* bih1   = (const float*)d_in[10];
    const float* bhh1   = (const float*)d_in[11];
    const float* fc1W   = (const float*)d_in[12];
    const float* fc1b   = (const float*)d_in[13];
    const float* fc2W   = (const float*)d_in[14];
    const float* fc2b   = (const float*)d_in[15];
    float* out = (float*)d_out;

    float* ws = (float*)d_ws;
    short* Bfrag   = (short*)ws;                          // 245760 bf16
    short* Bfrag1  = (short*)(ws + 122880);               // 196608 bf16
    short* Bfrag1W = (short*)(ws + 122880 + 98304);       // 712704 bf16
    float* fc1Wt   = ws + 577536;                         // 765952 f
    float* f       = fc1Wt + FCIN_ * 256;                 // 1343488
    short* fbf     = (short*)(f + 2048 * INTER_);         // 1900544 bf16
    float* xw1     = f + 2048 * INTER_ + 950272;          // 4161536
    float* hlast   = xw1 + 2048 * G3_;                    // 5734400
    float* g       = hlast + 8192;                        // 5742592 (+87552)

    prep_kernel<<<dim3(2992), 256, 0, stream>>>(Whh2, Wih2, Whh1, Wih1, fc1W,
                                                Bfrag, Bfrag1, Bfrag1W, fc1Wt);
    reduce_states_kernel<<<dim3(512), 256, 0, stream>>>(states, x1, f);
    gru2d_mfma<<<dim3(256), 1024, 0, stream>>>(states, perm1, perm2, Bfrag,
                                               bih2, bhh2, f);
    convert_f_kernel<<<dim3(1856), 256, 0, stream>>>(f, fbf);
    gemm_xw1_mfma<<<dim3(12, 32), 256, 0, stream>>>(fbf, Bfrag1W, bih1, xw1);
    gru1d_freduce<<<dim3(34), 512, 0, stream>>>(xw1, Bfrag1, bhh1, hlast, f, g);
    tail_fc<<<dim3(32), 256, 0, stream>>>(g, hlast, fc1Wt, fc1b, fc2W, fc2b, out);
}

// Round 9
// 630.824 us; speedup vs baseline: 1.7592x; 1.0470x over previous
//
#include <hip/hip_runtime.h>
#include <cmath>

#define B_ 32
#define N_ 64
#define H_ 256
#define G3_ 768           // 3*H
#define INTER_ 912        // 2H + 6C + C1
#define KP_ 928           // INTER_ padded to 29*32 for bf16 MFMA GEMM
#define FCIN_ 2992        // 3*INTER + H
#define GRED_ 2736        // 3*INTER (f reductions part of g)

#define PADA 264          // hA row stride (bf16 elems)
#define PADX 72           // xA row stride (bf16 elems)

typedef __attribute__((ext_vector_type(8))) short short8;
typedef __attribute__((ext_vector_type(4))) short sshort4;
typedef __attribute__((ext_vector_type(4))) float float4v;

#define MFMA __builtin_amdgcn_mfma_f32_16x16x32_bf16

// single-instruction transcendentals: v_exp_f32 is exp2, v_rcp_f32
__device__ __forceinline__ float sigmoid_f(float x) {
    return __builtin_amdgcn_rcpf(1.0f + __builtin_amdgcn_exp2f(-1.44269504f * x));
}
__device__ __forceinline__ float tanh_fast(float x) {
    return 1.0f - 2.0f * __builtin_amdgcn_rcpf(1.0f + __builtin_amdgcn_exp2f(2.88539008f * x));
}
__device__ __forceinline__ unsigned f2bf_bits(float x) {
    unsigned u = __float_as_uint(x);
    return (u + 0x7fffu + ((u >> 16) & 1u)) >> 16;
}
__device__ __forceinline__ short f2bf(float x) { return (short)f2bf_bits(x); }

// ---------------------------------------------------------------------------
// prep: (a) Bfrag   = gru2d weights, fragment-major bf16 (layout verified R2)
//       (b) Bfrag1  = gru1d Whh, same pack (8 kt)
//       (c) Bfrag1W = gru1d Wih (768 x 912), same pack, K zero-padded to 928
//       (d) fc1Wt transpose
//       (e) x1 copy -> f[:, 0:16]  (was in reduce_states; that kernel is
//           now fused into gru2d)
// Fragment layout: [kt][ntile(48)][lane(64)][j(8)] bf16; value = W[n][k] with
// n = ntile*16 + (lane&15), k = kt*32 + (lane>>4)*8 + j.
// ---------------------------------------------------------------------------
__global__ __launch_bounds__(256) void prep_kernel(
        const float* __restrict__ Whh2, const float* __restrict__ Wih2,
        const float* __restrict__ Whh1, const float* __restrict__ Wih1,
        const float* __restrict__ fc1W, const float* __restrict__ x1,
        short* __restrict__ Bfrag, short* __restrict__ Bfrag1,
        short* __restrict__ Bfrag1W, float* __restrict__ fc1Wt,
        float* __restrict__ f) {
    int idx = blockIdx.x * 256 + threadIdx.x;
    if (idx < 10 * 48 * 64 * 8) {
        int j = idx & 7, lane = (idx >> 3) & 63, tile = idx >> 9;
        int nt = tile % 48, kt = tile / 48;
        int n = nt * 16 + (lane & 15);
        int kb = (lane >> 4) * 8 + j;
        float v = (kt < 8) ? Whh2[n * 256 + kt * 32 + kb]
                           : Wih2[n * 64 + (kt - 8) * 32 + kb];
        Bfrag[idx] = f2bf(v);
    }
    if (idx < 8 * 48 * 64 * 8) {
        int j = idx & 7, lane = (idx >> 3) & 63, tile = idx >> 9;
        int nt = tile % 48, kt = tile / 48;
        int n = nt * 16 + (lane & 15);
        int k = kt * 32 + (lane >> 4) * 8 + j;
        Bfrag1[idx] = f2bf(Whh1[n * 256 + k]);
    }
    if (idx < 29 * 48 * 64 * 8) {
        int j = idx & 7, lane = (idx >> 3) & 63, tile = idx >> 9;
        int nt = tile % 48, kt = tile / 48;
        int n = nt * 16 + (lane & 15);
        int k = kt * 32 + (lane >> 4) * 8 + j;
        Bfrag1W[idx] = (k < INTER_) ? f2bf(Wih1[n * INTER_ + k]) : (short)0;
    }
    if (idx < FCIN_ * 256) {
        int o = idx & 255, i = idx >> 8;
        fc1Wt[idx] = fc1W[o * FCIN_ + i];
    }
    if (idx < 2048 * 16) {
        int bj = idx >> 4, c = idx & 15;
        f[bj * INTER_ + c] = x1[idx];
    }
}

// ---------------------------------------------------------------------------
// gru2d R9: R2-proven structure (512 thr, xA staging, per-step Bx reload,
// hA double-buffer, single barrier/step, bias-folded init) + FUSED d[]
// reductions: this kernel already streams every states element exactly once
// (sd1 block: states[b][qq][p][c] over all p = axis-2 reduction; sd2 block:
// states[b][p][qq][c] over all p = axis-1). 6 running max/min/sum registers
// per thread (2 (r,c) pairs x 3), 6 VALU ops/step, 6 stores at end.
// reduce_states kernel deleted (~50 us saved). Mean accumulates in perm
// order (FP reassociation only).
// ---------------------------------------------------------------------------
__global__ __launch_bounds__(512, 1) void gru2d_mfma(
        const float* __restrict__ states,
        const int* __restrict__ perm1, const int* __restrict__ perm2,
        const short* __restrict__ Bfrag,
        const float* __restrict__ bih, const float* __restrict__ bhh,
        float* __restrict__ f) {
    __shared__ short hA[2][16 * PADA];
    __shared__ short xA[2][16 * PADX];
    __shared__ short8 Blds[2 * 48 * 64];
    __shared__ int perms[1024];

    const int tid = threadIdx.x;
    const int lane = tid & 63;
    const int w = tid >> 6;
    const int m = lane & 15;
    const int q = lane >> 4;
    const bool sd2 = blockIdx.x >= 128;
    const int sblock = (blockIdx.x & 127) * 16;

    for (int i = tid; i < 1024; i += 512) {
        int r = i >> 6, t = i & 63;
        int qq = (sblock + r) & 63;
        perms[i] = sd2 ? perm2[qq * 64 + t] : perm1[qq * 64 + t];
    }
    for (int i = tid; i < 16 * PADA; i += 512) hA[0][i] = 0;
    {
        const uint4* src = (const uint4*)(Bfrag + 6 * 48 * 64 * 8);
        uint4* dst = (uint4*)Blds;
        #pragma unroll
        for (int rep = 0; rep < 12; ++rep)
            dst[tid + rep * 512] = src[tid + rep * 512];
    }

    const short8* Bf8 = (const short8*)Bfrag;
    short8 Bres[36];
    #pragma unroll
    for (int kt = 0; kt < 6; ++kt)
        #pragma unroll
        for (int j = 0; j < 6; ++j)
            Bres[kt * 6 + j] = Bf8[(kt * 48 + 8 * j + w) * 64 + lane];

    const int u0 = 16 * w + m;
    const int u1 = 128 + u0;
    const float br0 = bih[u0] + bhh[u0],             br1 = bih[u1] + bhh[u1];
    const float bz0 = bih[256 + u0] + bhh[256 + u0], bz1 = bih[256 + u1] + bhh[256 + u1];
    const float bnx0 = bih[512 + u0], bnx1 = bih[512 + u1];
    const float bnh0 = bhh[512 + u0], bnh1 = bhh[512 + u1];

    float4v hreg0 = {0.f, 0.f, 0.f, 0.f}, hreg1 = {0.f, 0.f, 0.f, 0.f};

    // fused-reduction accumulators: half0 -> (r = tid>>6, c), half1 -> (r+8, c)
    float mxA = -1e30f, mnA = 1e30f, smA = 0.f;
    float mxB = -1e30f, mnB = 1e30f, smB = 0.f;

    {
        #pragma unroll
        for (int half = 0; half < 2; ++half) {
            int i = tid + half * 512;
            int r = i >> 6, c = i & 63;
            int s = sblock + r, b = s >> 6, qq = s & 63;
            int p = perms[r * 64 + 0];
            int src = sd2 ? ((b * 64 + p) * 64 + qq) * 64 + c
                          : ((b * 64 + qq) * 64 + p) * 64 + c;
            float v = states[src];
            if (half == 0) { mxA = fmaxf(mxA, v); mnA = fminf(mnA, v); smA += v; }
            else           { mxB = fmaxf(mxB, v); mnB = fminf(mnB, v); smB += v; }
            xA[0][r * PADX + c] = f2bf(v);
        }
    }
    __syncthreads();

    for (int t = 0; t < 64; ++t) {
        const short* hAc = hA[t & 1];
        const short* xAc = xA[t & 1];

        // x-part B fragments: per-step reload from L2-hot Bfrag (R2-proven;
        // keeps resident regs low enough for the fused accumulators)
        short8 Bx[12];
        #pragma unroll
        for (int kt = 0; kt < 2; ++kt)
            #pragma unroll
            for (int j = 0; j < 6; ++j)
                Bx[kt * 6 + j] = Bf8[((8 + kt) * 48 + 8 * j + w) * 64 + lane];

        float xg0 = 0.f, xg1 = 0.f;
        int w0 = -1, w1 = -1;
        if (t + 1 < 64) {
            #pragma unroll
            for (int half = 0; half < 2; ++half) {
                int i = tid + half * 512;
                int r = i >> 6, c = i & 63;
                int s = sblock + r, b = s >> 6, qq = s & 63;
                int p = perms[r * 64 + t + 1];
                int src = sd2 ? ((b * 64 + p) * 64 + qq) * 64 + c
                              : ((b * 64 + qq) * 64 + p) * 64 + c;
                float v = states[src];
                if (half == 0) {
                    xg0 = v; w0 = r * PADX + c;
                    mxA = fmaxf(mxA, v); mnA = fminf(mnA, v); smA += v;
                } else {
                    xg1 = v; w1 = r * PADX + c;
                    mxB = fmaxf(mxB, v); mnB = fminf(mnB, v); smB += v;
                }
            }
        }

        // ---- interleaved 6-chain MFMA, biases pre-folded ----
        float4v aR0 = {br0, br0, br0, br0},     aR1 = {br1, br1, br1, br1};
        float4v aZ0 = {bz0, bz0, bz0, bz0},     aZ1 = {bz1, bz1, bz1, bz1};
        float4v aNh0 = {bnh0, bnh0, bnh0, bnh0}, aNh1 = {bnh1, bnh1, bnh1, bnh1};
        float4v aNx0 = {bnx0, bnx0, bnx0, bnx0}, aNx1 = {bnx1, bnx1, bnx1, bnx1};

        #pragma unroll
        for (int kt = 0; kt < 6; ++kt) {
            short8 a = *(const short8*)(hAc + m * PADA + kt * 32 + q * 8);
            aR0  = MFMA(a, Bres[kt * 6 + 0], aR0, 0, 0, 0);
            aR1  = MFMA(a, Bres[kt * 6 + 1], aR1, 0, 0, 0);
            aZ0  = MFMA(a, Bres[kt * 6 + 2], aZ0, 0, 0, 0);
            aZ1  = MFMA(a, Bres[kt * 6 + 3], aZ1, 0, 0, 0);
            aNh0 = MFMA(a, Bres[kt * 6 + 4], aNh0, 0, 0, 0);
            aNh1 = MFMA(a, Bres[kt * 6 + 5], aNh1, 0, 0, 0);
        }
        #pragma unroll
        for (int kt = 0; kt < 2; ++kt) {
            short8 a = *(const short8*)(hAc + m * PADA + (6 + kt) * 32 + q * 8);
            short8 b0 = Blds[(kt * 48 + 8 * 0 + w) * 64 + lane];
            short8 b1 = Blds[(kt * 48 + 8 * 1 + w) * 64 + lane];
            short8 b2 = Blds[(kt * 48 + 8 * 2 + w) * 64 + lane];
            short8 b3 = Blds[(kt * 48 + 8 * 3 + w) * 64 + lane];
            short8 b4 = Blds[(kt * 48 + 8 * 4 + w) * 64 + lane];
            short8 b5 = Blds[(kt * 48 + 8 * 5 + w) * 64 + lane];
            aR0  = MFMA(a, b0, aR0, 0, 0, 0);
            aR1  = MFMA(a, b1, aR1, 0, 0, 0);
            aZ0  = MFMA(a, b2, aZ0, 0, 0, 0);
            aZ1  = MFMA(a, b3, aZ1, 0, 0, 0);
            aNh0 = MFMA(a, b4, aNh0, 0, 0, 0);
            aNh1 = MFMA(a, b5, aNh1, 0, 0, 0);
        }
        #pragma unroll
        for (int kt = 0; kt < 2; ++kt) {
            short8 a = *(const short8*)(xAc + m * PADX + kt * 32 + q * 8);
            aR0  = MFMA(a, Bx[kt * 6 + 0], aR0, 0, 0, 0);
            aR1  = MFMA(a, Bx[kt * 6 + 1], aR1, 0, 0, 0);
            aZ0  = MFMA(a, Bx[kt * 6 + 2], aZ0, 0, 0, 0);
            aZ1  = MFMA(a, Bx[kt * 6 + 3], aZ1, 0, 0, 0);
            aNx0 = MFMA(a, Bx[kt * 6 + 4], aNx0, 0, 0, 0);
            aNx1 = MFMA(a, Bx[kt * 6 + 5], aNx1, 0, 0, 0);
        }

        short* hAn = hA[(t + 1) & 1];
        #pragma unroll
        for (int p = 0; p < 4; ++p) {
            int row = q * 4 + p;
            float r0 = sigmoid_f(aR0[p]);
            float z0 = sigmoid_f(aZ0[p]);
            float n0 = tanh_fast(aNx0[p] + r0 * aNh0[p]);
            float h0 = n0 + z0 * (hreg0[p] - n0);
            hreg0[p] = h0;
            hAn[row * PADA + u0] = f2bf(h0);
            float r1 = sigmoid_f(aR1[p]);
            float z1 = sigmoid_f(aZ1[p]);
            float n1 = tanh_fast(aNx1[p] + r1 * aNh1[p]);
            float h1 = n1 + z1 * (hreg1[p] - n1);
            hreg1[p] = h1;
            hAn[row * PADA + u1] = f2bf(h1);
        }
        if (t + 1 < 64) {
            xA[(t + 1) & 1][w0] = f2bf(xg0);
            xA[(t + 1) & 1][w1] = f2bf(xg1);
        }
        __syncthreads();
    }

    // fused-reduction writes: sd1 -> axis-2 (208/272/336), sd2 -> axis-1
    // (16/80/144); same f rows this block owns, disjoint columns vs h.
    {
        const int off2 = sd2 ? 16 : 208;
        int r0 = tid >> 6, c0 = tid & 63;
        float* fr0 = f + (size_t)(sblock + r0) * INTER_ + off2 + c0;
        fr0[0]   = mxA;
        fr0[64]  = smA * (1.f / 64.f);
        fr0[128] = mnA;
        float* fr1 = f + (size_t)(sblock + r0 + 8) * INTER_ + off2 + c0;
        fr1[0]   = mxB;
        fr1[64]  = smB * (1.f / 64.f);
        fr1[128] = mnB;
    }

    const int off = sd2 ? 656 : 400;
    #pragma unroll
    for (int p = 0; p < 4; ++p) {
        int s = sblock + q * 4 + p;
        f[s * INTER_ + off + u0] = hreg0[p];
        f[s * INTER_ + off + u1] = hreg1[p];
    }
}

// ---------------------------------------------------------------------------
// convert f (fp32 [2048][912]) -> fbf (bf16 [2048][928], zero-padded K)
// ---------------------------------------------------------------------------
__global__ __launch_bounds__(256) void convert_f_kernel(
        const float* __restrict__ f, short* __restrict__ fbf) {
    int idx = blockIdx.x * 256 + threadIdx.x;
    int row = idx / 232;
    int c4 = (idx - row * 232) * 4;
    if (row >= 2048) return;
    sshort4 o;
    if (c4 < INTER_) {
        float4v v = *(const float4v*)(f + row * INTER_ + c4);
        o[0] = f2bf(v[0]); o[1] = f2bf(v[1]); o[2] = f2bf(v[2]); o[3] = f2bf(v[3]);
    } else {
        o[0] = 0; o[1] = 0; o[2] = 0; o[3] = 0;
    }
    *(sshort4*)(fbf + row * KP_ + c4) = o;
}

// ---------------------------------------------------------------------------
// xw1 = fbf[2048][928] @ Wih1^T (+bih1), bf16 MFMA. Output TRANSPOSED to
// [t][seq][768] so gru1d's per-step reads are step-contiguous.
// ---------------------------------------------------------------------------
__global__ __launch_bounds__(256) void gemm_xw1_mfma(
        const short* __restrict__ fbf, const short* __restrict__ BfragW,
        const float* __restrict__ bih, float* __restrict__ xw) {
    const int tid = threadIdx.x;
    const int lane = tid & 63;
    const int w = tid >> 6;
    const int m = lane & 15;
    const int q = lane >> 4;
    const int tn = blockIdx.x;
    const int tm = blockIdx.y;
    const int rowb = tm * 64 + w * 16;
    const short8* Bf8 = (const short8*)BfragW;

    float4v acc[4];
    #pragma unroll
    for (int nn = 0; nn < 4; ++nn) {
        float b = bih[tn * 64 + nn * 16 + m];
        acc[nn][0] = b; acc[nn][1] = b; acc[nn][2] = b; acc[nn][3] = b;
    }

    const short* arow = fbf + (rowb + m) * KP_;
    short8 a_cur = *(const short8*)(arow + q * 8);
    short8 b_cur[4];
    #pragma unroll
    for (int nn = 0; nn < 4; ++nn)
        b_cur[nn] = Bf8[(tn * 4 + nn) * 64 + lane];

    for (int kt = 0; kt < 29; ++kt) {
        short8 a_nxt = a_cur;
        short8 b_nxt[4];
        if (kt + 1 < 29) {
            a_nxt = *(const short8*)(arow + (kt + 1) * 32 + q * 8);
            #pragma unroll
            for (int nn = 0; nn < 4; ++nn)
                b_nxt[nn] = Bf8[((kt + 1) * 48 + tn * 4 + nn) * 64 + lane];
        }
        #pragma unroll
        for (int nn = 0; nn < 4; ++nn)
            acc[nn] = MFMA(a_cur, b_cur[nn], acc[nn], 0, 0, 0);
        a_cur = a_nxt;
        #pragma unroll
        for (int nn = 0; nn < 4; ++nn) b_cur[nn] = b_nxt[nn];
    }

    #pragma unroll
    for (int p = 0; p < 4; ++p) {
        int row = rowb + q * 4 + p;
        int seq = row >> 6, t = row & 63;
        #pragma unroll
        for (int nn = 0; nn < 4; ++nn)
            xw[(t * 32 + seq) * G3_ + tn * 64 + nn * 16 + m] = acc[nn][p];
    }
}

// ---------------------------------------------------------------------------
// fused: blocks 0-1 = gru1d (2 CUs); blocks 2-33 = f-reductions for tail.
// R4-proven 512-thread form (8 waves, wave owns 2 chunks u0/u1).
// ---------------------------------------------------------------------------
__global__ __launch_bounds__(512, 1) void gru1d_freduce(
        const float* __restrict__ xw, const short* __restrict__ Bfrag1,
        const float* __restrict__ bhh, float* __restrict__ hlast,
        const float* __restrict__ f, float* __restrict__ g) {
    __shared__ short hA[2][16 * PADA];
    __shared__ short8 Blds[2 * 48 * 64];   // kt 6,7

    const int tid = threadIdx.x;

    if (blockIdx.x >= 2) {
        const int b = blockIdx.x - 2;
        for (int i = tid; i < INTER_; i += 512) {
            const float* fp = f + (size_t)(b * 64) * INTER_ + i;
            float mx = -1e30f, mn = 1e30f, sm = 0.f;
            #pragma unroll 8
            for (int t = 0; t < 64; ++t) {
                float v = __builtin_nontemporal_load(fp + t * INTER_);
                mx = fmaxf(mx, v); mn = fminf(mn, v); sm += v;
            }
            g[b * GRED_ + i] = mx;
            g[b * GRED_ + INTER_ + i] = sm * (1.f / 64.f);
            g[b * GRED_ + 2 * INTER_ + i] = mn;
        }
        return;
    }

    const int lane = tid & 63;
    const int w = tid >> 6;
    const int m = lane & 15;
    const int q = lane >> 4;
    const int sblock = blockIdx.x * 16;

    for (int i = tid; i < 16 * PADA; i += 512) hA[0][i] = 0;
    {
        const uint4* src = (const uint4*)(Bfrag1 + 6 * 48 * 64 * 8);
        uint4* dst = (uint4*)Blds;
        #pragma unroll
        for (int rep = 0; rep < 12; ++rep)
            dst[tid + rep * 512] = src[tid + rep * 512];
    }
    const short8* Bf8 = (const short8*)Bfrag1;
    short8 Bres[36];
    #pragma unroll
    for (int kt = 0; kt < 6; ++kt)
        #pragma unroll
        for (int j = 0; j < 6; ++j)
            Bres[kt * 6 + j] = Bf8[(kt * 48 + 8 * j + w) * 64 + lane];

    const int u0 = 16 * w + m;
    const int u1 = 128 + u0;
    const float br0 = bhh[u0],       br1 = bhh[u1];
    const float bz0 = bhh[256 + u0], bz1 = bhh[256 + u1];
    const float bn0 = bhh[512 + u0], bn1 = bhh[512 + u1];

    float4v hreg0 = {0.f, 0.f, 0.f, 0.f}, hreg1 = {0.f, 0.f, 0.f, 0.f};
    __syncthreads();

    for (int t = 0; t < 64; ++t) {
        const short* hAc = hA[t & 1];

        float giR0[4], giR1[4], giZ0[4], giZ1[4], giN0[4], giN1[4];
        #pragma unroll
        for (int p = 0; p < 4; ++p) {
            const float* gr = xw + (size_t)(t * 32 + sblock + q * 4 + p) * G3_;
            giR0[p] = gr[u0];        giR1[p] = gr[u1];
            giZ0[p] = gr[256 + u0];  giZ1[p] = gr[256 + u1];
            giN0[p] = gr[512 + u0];  giN1[p] = gr[512 + u1];
        }

        float4v aR0 = {br0, br0, br0, br0}, aR1 = {br1, br1, br1, br1};
        float4v aZ0 = {bz0, bz0, bz0, bz0}, aZ1 = {bz1, bz1, bz1, bz1};
        float4v aN0 = {bn0, bn0, bn0, bn0}, aN1 = {bn1, bn1, bn1, bn1};

        #pragma unroll
        for (int kt = 0; kt < 6; ++kt) {
            short8 a = *(const short8*)(hAc + m * PADA + kt * 32 + q * 8);
            aR0 = MFMA(a, Bres[kt * 6 + 0], aR0, 0, 0, 0);
            aR1 = MFMA(a, Bres[kt * 6 + 1], aR1, 0, 0, 0);
            aZ0 = MFMA(a, Bres[kt * 6 + 2], aZ0, 0, 0, 0);
            aZ1 = MFMA(a, Bres[kt * 6 + 3], aZ1, 0, 0, 0);
            aN0 = MFMA(a, Bres[kt * 6 + 4], aN0, 0, 0, 0);
            aN1 = MFMA(a, Bres[kt * 6 + 5], aN1, 0, 0, 0);
        }
        #pragma unroll
        for (int kt = 0; kt < 2; ++kt) {
            short8 a = *(const short8*)(hAc + m * PADA + (6 + kt) * 32 + q * 8);
            short8 b0 = Blds[(kt * 48 + 8 * 0 + w) * 64 + lane];
            short8 b1 = Blds[(kt * 48 + 8 * 1 + w) * 64 + lane];
            short8 b2 = Blds[(kt * 48 + 8 * 2 + w) * 64 + lane];
            short8 b3 = Blds[(kt * 48 + 8 * 3 + w) * 64 + lane];
            short8 b4 = Blds[(kt * 48 + 8 * 4 + w) * 64 + lane];
            short8 b5 = Blds[(kt * 48 + 8 * 5 + w) * 64 + lane];
            aR0 = MFMA(a, b0, aR0, 0, 0, 0);
            aR1 = MFMA(a, b1, aR1, 0, 0, 0);
            aZ0 = MFMA(a, b2, aZ0, 0, 0, 0);
            aZ1 = MFMA(a, b3, aZ1, 0, 0, 0);
            aN0 = MFMA(a, b4, aN0, 0, 0, 0);
            aN1 = MFMA(a, b5, aN1, 0, 0, 0);
        }

        short* hAn = hA[(t + 1) & 1];
        #pragma unroll
        for (int p = 0; p < 4; ++p) {
            int row = q * 4 + p;
            float r0 = sigmoid_f(giR0[p] + aR0[p]);
            float z0 = sigmoid_f(giZ0[p] + aZ0[p]);
            float n0 = tanh_fast(giN0[p] + r0 * aN0[p]);
            float h0 = n0 + z0 * (hreg0[p] - n0);
            hreg0[p] = h0;
            hAn[row * PADA + u0] = f2bf(h0);
            float r1 = sigmoid_f(giR1[p] + aR1[p]);
            float z1 = sigmoid_f(giZ1[p] + aZ1[p]);
            float n1 = tanh_fast(giN1[p] + r1 * aN1[p]);
            float h1 = n1 + z1 * (hreg1[p] - n1);
            hreg1[p] = h1;
            hAn[row * PADA + u1] = f2bf(h1);
        }
        __syncthreads();
    }

    #pragma unroll
    for (int p = 0; p < 4; ++p) {
        int s = sblock + q * 4 + p;
        hlast[s * 256 + u0] = hreg0[p];
        hlast[s * 256 + u1] = hreg1[p];
    }
}

// ---------------------------------------------------------------------------
// tail_fc: g_lds = [g(b) | hlast(b)], fc1+relu, fc2
// ---------------------------------------------------------------------------
__global__ __launch_bounds__(256) void tail_fc(
        const float* __restrict__ g, const float* __restrict__ hlast,
        const float* __restrict__ fc1Wt, const float* __restrict__ fc1b,
        const float* __restrict__ fc2W, const float* __restrict__ fc2b,
        float* __restrict__ out) {
    __shared__ float g_lds[FCIN_];
    __shared__ float red[4];
    const int tid = threadIdx.x;
    const int b = blockIdx.x;
    for (int i = tid; i < GRED_; i += 256) g_lds[i] = g[b * GRED_ + i];
    g_lds[GRED_ + tid] = hlast[b * 256 + tid];
    __syncthreads();

    float a0 = 0.f, a1 = 0.f, a2 = 0.f, a3 = 0.f;
    for (int i = 0; i < FCIN_; i += 4) {
        a0 = fmaf(g_lds[i],     fc1Wt[(i) * 256 + tid],     a0);
        a1 = fmaf(g_lds[i + 1], fc1Wt[(i + 1) * 256 + tid], a1);
        a2 = fmaf(g_lds[i + 2], fc1Wt[(i + 2) * 256 + tid], a2);
        a3 = fmaf(g_lds[i + 3], fc1Wt[(i + 3) * 256 + tid], a3);
    }
    float acc = ((a0 + a1) + (a2 + a3)) + fc1b[tid];
    float hv = fmaxf(acc, 0.f);
    float part = hv * fc2W[tid];
    #pragma unroll
    for (int off = 32; off >= 1; off >>= 1)
        part += __shfl_down(part, off, 64);
    if ((tid & 63) == 0) red[tid >> 6] = part;
    __syncthreads();
    if (tid == 0)
        out[b] = fc2b[0] + red[0] + red[1] + red[2] + red[3];
}

// ---------------------------------------------------------------------------
extern "C" void kernel_launch(void* const* d_in, const int* in_sizes, int n_in,
                              void* d_out, int out_size, void* d_ws, size_t ws_size,
                              hipStream_t stream) {
    const float* x1     = (const float*)d_in[0];
    const float* states = (const float*)d_in[1];
    const int*   perm1  = (const int*)d_in[2];
    const int*   perm2  = (const int*)d_in[3];
    const float* Wih2   = (const float*)d_in[4];
    const float* Whh2   = (const float*)d_in[5];
    const float* bih2   = (const float*)d_in[6];
    const float* bhh2   = (const float*)d_in[7];
    const float* Wih1   = (const float*)d_in[8];
    const float* Whh1   = (const float*)d_in[9];
    const float* bih1   = (const float*)d_in[10];
    const float* bhh1   = (const float*)d_in[11];
    const float* fc1W   = (const float*)d_in[12];
    const float* fc1b   = (const float*)d_in[13];
    const float* fc2W   = (const float*)d_in[14];
    const float* fc2b   = (const float*)d_in[15];
    float* out = (float*)d_out;

    float* ws = (float*)d_ws;
    short* Bfrag   = (short*)ws;                          // 245760 bf16
    short* Bfrag1  = (short*)(ws + 122880);               // 196608 bf16
    short* Bfrag1W = (short*)(ws + 122880 + 98304);       // 712704 bf16
    float* fc1Wt   = ws + 577536;                         // 765952 f
    float* f       = fc1Wt + FCIN_ * 256;                 // 1343488
    short* fbf     = (short*)(f + 2048 * INTER_);         // 1900544 bf16
    float* xw1     = f + 2048 * INTER_ + 950272;          // 4161536
    float* hlast   = xw1 + 2048 * G3_;                    // 5734400
    float* g       = hlast + 8192;                        // 5742592 (+87552)

    prep_kernel<<<dim3(2992), 256, 0, stream>>>(Whh2, Wih2, Whh1, Wih1, fc1W,
                                                x1, Bfrag, Bfrag1, Bfrag1W,
                                                fc1Wt, f);
    gru2d_mfma<<<dim3(256), 512, 0, stream>>>(states, perm1, perm2, Bfrag,
                                              bih2, bhh2, f);
    convert_f_kernel<<<dim3(1856), 256, 0, stream>>>(f, fbf);
    gemm_xw1_mfma<<<dim3(12, 32), 256, 0, stream>>>(fbf, Bfrag1W, bih1, xw1);
    gru1d_freduce<<<dim3(34), 512, 0, stream>>>(xw1, Bfrag1, bhh1, hlast, f, g);
    tail_fc<<<dim3(32), 256, 0, stream>>>(g, hlast, fc1Wt, fc1b, fc2W, fc2b, out);
}

// Round 10
// 622.912 us; speedup vs baseline: 1.7815x; 1.0127x over previous
//
#include <hip/hip_runtime.h>
#include <cmath>

#define B_ 32
#define N_ 64
#define H_ 256
#define G3_ 768           // 3*H
#define INTER_ 912        // 2H + 6C + C1
#define KP_ 928           // INTER_ padded to 29*32 for bf16 MFMA GEMM
#define FCIN_ 2992        // 3*INTER + H
#define GRED_ 2736        // 3*INTER (f reductions part of g)

#define PADA 264          // hA row stride (bf16 elems)
#define PADX 72           // xA row stride (bf16 elems)

typedef __attribute__((ext_vector_type(8))) short short8;
typedef __attribute__((ext_vector_type(4))) short sshort4;
typedef __attribute__((ext_vector_type(4))) float float4v;

#define MFMA __builtin_amdgcn_mfma_f32_16x16x32_bf16

// single-instruction transcendentals: v_exp_f32 is exp2, v_rcp_f32
__device__ __forceinline__ float sigmoid_f(float x) {
    return __builtin_amdgcn_rcpf(1.0f + __builtin_amdgcn_exp2f(-1.44269504f * x));
}
__device__ __forceinline__ float tanh_fast(float x) {
    return 1.0f - 2.0f * __builtin_amdgcn_rcpf(1.0f + __builtin_amdgcn_exp2f(2.88539008f * x));
}
__device__ __forceinline__ unsigned f2bf_bits(float x) {
    unsigned u = __float_as_uint(x);
    return (u + 0x7fffu + ((u >> 16) & 1u)) >> 16;
}
__device__ __forceinline__ short f2bf(float x) { return (short)f2bf_bits(x); }

// ---------------------------------------------------------------------------
// prep: (a) Bfrag   = gru2d weights, fragment-major bf16 (layout verified R2)
//       (b) Bfrag1  = gru1d Whh, same pack (8 kt)
//       (c) Bfrag1W = gru1d Wih (768 x 912), same pack, K zero-padded to 928
//       (d) fc1Wt transpose
//       (e) x1 copy -> f[:, 0:16] AND fbf[:, 0:16] (bf16), + fbf K-pad
//           cols 912-928 (convert_f kernel deleted; gru2d writes the rest
//           of fbf directly)
// Fragment layout: [kt][ntile(48)][lane(64)][j(8)] bf16; value = W[n][k] with
// n = ntile*16 + (lane&15), k = kt*32 + (lane>>4)*8 + j.
// ---------------------------------------------------------------------------
__global__ __launch_bounds__(256) void prep_kernel(
        const float* __restrict__ Whh2, const float* __restrict__ Wih2,
        const float* __restrict__ Whh1, const float* __restrict__ Wih1,
        const float* __restrict__ fc1W, const float* __restrict__ x1,
        short* __restrict__ Bfrag, short* __restrict__ Bfrag1,
        short* __restrict__ Bfrag1W, float* __restrict__ fc1Wt,
        float* __restrict__ f, short* __restrict__ fbf) {
    int idx = blockIdx.x * 256 + threadIdx.x;
    if (idx < 10 * 48 * 64 * 8) {
        int j = idx & 7, lane = (idx >> 3) & 63, tile = idx >> 9;
        int nt = tile % 48, kt = tile / 48;
        int n = nt * 16 + (lane & 15);
        int kb = (lane >> 4) * 8 + j;
        float v = (kt < 8) ? Whh2[n * 256 + kt * 32 + kb]
                           : Wih2[n * 64 + (kt - 8) * 32 + kb];
        Bfrag[idx] = f2bf(v);
    }
    if (idx < 8 * 48 * 64 * 8) {
        int j = idx & 7, lane = (idx >> 3) & 63, tile = idx >> 9;
        int nt = tile % 48, kt = tile / 48;
        int n = nt * 16 + (lane & 15);
        int k = kt * 32 + (lane >> 4) * 8 + j;
        Bfrag1[idx] = f2bf(Whh1[n * 256 + k]);
    }
    if (idx < 29 * 48 * 64 * 8) {
        int j = idx & 7, lane = (idx >> 3) & 63, tile = idx >> 9;
        int nt = tile % 48, kt = tile / 48;
        int n = nt * 16 + (lane & 15);
        int k = kt * 32 + (lane >> 4) * 8 + j;
        Bfrag1W[idx] = (k < INTER_) ? f2bf(Wih1[n * INTER_ + k]) : (short)0;
    }
    if (idx < FCIN_ * 256) {
        int o = idx & 255, i = idx >> 8;
        fc1Wt[idx] = fc1W[o * FCIN_ + i];
    }
    if (idx < 2048 * 16) {
        int bj = idx >> 4, c = idx & 15;
        float v = x1[idx];
        f[bj * INTER_ + c] = v;
        fbf[bj * KP_ + c] = f2bf(v);
        fbf[bj * KP_ + 912 + c] = 0;   // zero-pad K 912..927
    }
}

// ---------------------------------------------------------------------------
// gru2d R10: R9 structure (512 thr, xA staging, per-step Bx reload, hA
// double-buffer, single barrier/step, bias-folded init, FUSED d[]
// reductions) + direct fbf (bf16) writes in the epilogue: h-columns and
// reduction-columns are written both fp32 (f, for tail reductions) and
// bf16 (fbf, for the gemm). convert_f kernel deleted.
// ---------------------------------------------------------------------------
__global__ __launch_bounds__(512, 1) void gru2d_mfma(
        const float* __restrict__ states,
        const int* __restrict__ perm1, const int* __restrict__ perm2,
        const short* __restrict__ Bfrag,
        const float* __restrict__ bih, const float* __restrict__ bhh,
        float* __restrict__ f, short* __restrict__ fbf) {
    __shared__ short hA[2][16 * PADA];
    __shared__ short xA[2][16 * PADX];
    __shared__ short8 Blds[2 * 48 * 64];
    __shared__ int perms[1024];

    const int tid = threadIdx.x;
    const int lane = tid & 63;
    const int w = tid >> 6;
    const int m = lane & 15;
    const int q = lane >> 4;
    const bool sd2 = blockIdx.x >= 128;
    const int sblock = (blockIdx.x & 127) * 16;

    for (int i = tid; i < 1024; i += 512) {
        int r = i >> 6, t = i & 63;
        int qq = (sblock + r) & 63;
        perms[i] = sd2 ? perm2[qq * 64 + t] : perm1[qq * 64 + t];
    }
    for (int i = tid; i < 16 * PADA; i += 512) hA[0][i] = 0;
    {
        const uint4* src = (const uint4*)(Bfrag + 6 * 48 * 64 * 8);
        uint4* dst = (uint4*)Blds;
        #pragma unroll
        for (int rep = 0; rep < 12; ++rep)
            dst[tid + rep * 512] = src[tid + rep * 512];
    }

    const short8* Bf8 = (const short8*)Bfrag;
    short8 Bres[36];
    #pragma unroll
    for (int kt = 0; kt < 6; ++kt)
        #pragma unroll
        for (int j = 0; j < 6; ++j)
            Bres[kt * 6 + j] = Bf8[(kt * 48 + 8 * j + w) * 64 + lane];

    const int u0 = 16 * w + m;
    const int u1 = 128 + u0;
    const float br0 = bih[u0] + bhh[u0],             br1 = bih[u1] + bhh[u1];
    const float bz0 = bih[256 + u0] + bhh[256 + u0], bz1 = bih[256 + u1] + bhh[256 + u1];
    const float bnx0 = bih[512 + u0], bnx1 = bih[512 + u1];
    const float bnh0 = bhh[512 + u0], bnh1 = bhh[512 + u1];

    float4v hreg0 = {0.f, 0.f, 0.f, 0.f}, hreg1 = {0.f, 0.f, 0.f, 0.f};

    // fused-reduction accumulators: half0 -> (r = tid>>6, c), half1 -> (r+8, c)
    float mxA = -1e30f, mnA = 1e30f, smA = 0.f;
    float mxB = -1e30f, mnB = 1e30f, smB = 0.f;

    {
        #pragma unroll
        for (int half = 0; half < 2; ++half) {
            int i = tid + half * 512;
            int r = i >> 6, c = i & 63;
            int s = sblock + r, b = s >> 6, qq = s & 63;
            int p = perms[r * 64 + 0];
            int src = sd2 ? ((b * 64 + p) * 64 + qq) * 64 + c
                          : ((b * 64 + qq) * 64 + p) * 64 + c;
            float v = states[src];
            if (half == 0) { mxA = fmaxf(mxA, v); mnA = fminf(mnA, v); smA += v; }
            else           { mxB = fmaxf(mxB, v); mnB = fminf(mnB, v); smB += v; }
            xA[0][r * PADX + c] = f2bf(v);
        }
    }
    __syncthreads();

    for (int t = 0; t < 64; ++t) {
        const short* hAc = hA[t & 1];
        const short* xAc = xA[t & 1];

        // x-part B fragments: per-step reload from L2-hot Bfrag (R2-proven;
        // keeps resident regs low enough for the fused accumulators)
        short8 Bx[12];
        #pragma unroll
        for (int kt = 0; kt < 2; ++kt)
            #pragma unroll
            for (int j = 0; j < 6; ++j)
                Bx[kt * 6 + j] = Bf8[((8 + kt) * 48 + 8 * j + w) * 64 + lane];

        float xg0 = 0.f, xg1 = 0.f;
        int w0 = -1, w1 = -1;
        if (t + 1 < 64) {
            #pragma unroll
            for (int half = 0; half < 2; ++half) {
                int i = tid + half * 512;
                int r = i >> 6, c = i & 63;
                int s = sblock + r, b = s >> 6, qq = s & 63;
                int p = perms[r * 64 + t + 1];
                int src = sd2 ? ((b * 64 + p) * 64 + qq) * 64 + c
                              : ((b * 64 + qq) * 64 + p) * 64 + c;
                float v = states[src];
                if (half == 0) {
                    xg0 = v; w0 = r * PADX + c;
                    mxA = fmaxf(mxA, v); mnA = fminf(mnA, v); smA += v;
                } else {
                    xg1 = v; w1 = r * PADX + c;
                    mxB = fmaxf(mxB, v); mnB = fminf(mnB, v); smB += v;
                }
            }
        }

        // ---- interleaved 6-chain MFMA, biases pre-folded ----
        float4v aR0 = {br0, br0, br0, br0},     aR1 = {br1, br1, br1, br1};
        float4v aZ0 = {bz0, bz0, bz0, bz0},     aZ1 = {bz1, bz1, bz1, bz1};
        float4v aNh0 = {bnh0, bnh0, bnh0, bnh0}, aNh1 = {bnh1, bnh1, bnh1, bnh1};
        float4v aNx0 = {bnx0, bnx0, bnx0, bnx0}, aNx1 = {bnx1, bnx1, bnx1, bnx1};

        #pragma unroll
        for (int kt = 0; kt < 6; ++kt) {
            short8 a = *(const short8*)(hAc + m * PADA + kt * 32 + q * 8);
            aR0  = MFMA(a, Bres[kt * 6 + 0], aR0, 0, 0, 0);
            aR1  = MFMA(a, Bres[kt * 6 + 1], aR1, 0, 0, 0);
            aZ0  = MFMA(a, Bres[kt * 6 + 2], aZ0, 0, 0, 0);
            aZ1  = MFMA(a, Bres[kt * 6 + 3], aZ1, 0, 0, 0);
            aNh0 = MFMA(a, Bres[kt * 6 + 4], aNh0, 0, 0, 0);
            aNh1 = MFMA(a, Bres[kt * 6 + 5], aNh1, 0, 0, 0);
        }
        #pragma unroll
        for (int kt = 0; kt < 2; ++kt) {
            short8 a = *(const short8*)(hAc + m * PADA + (6 + kt) * 32 + q * 8);
            short8 b0 = Blds[(kt * 48 + 8 * 0 + w) * 64 + lane];
            short8 b1 = Blds[(kt * 48 + 8 * 1 + w) * 64 + lane];
            short8 b2 = Blds[(kt * 48 + 8 * 2 + w) * 64 + lane];
            short8 b3 = Blds[(kt * 48 + 8 * 3 + w) * 64 + lane];
            short8 b4 = Blds[(kt * 48 + 8 * 4 + w) * 64 + lane];
            short8 b5 = Blds[(kt * 48 + 8 * 5 + w) * 64 + lane];
            aR0  = MFMA(a, b0, aR0, 0, 0, 0);
            aR1  = MFMA(a, b1, aR1, 0, 0, 0);
            aZ0  = MFMA(a, b2, aZ0, 0, 0, 0);
            aZ1  = MFMA(a, b3, aZ1, 0, 0, 0);
            aNh0 = MFMA(a, b4, aNh0, 0, 0, 0);
            aNh1 = MFMA(a, b5, aNh1, 0, 0, 0);
        }
        #pragma unroll
        for (int kt = 0; kt < 2; ++kt) {
            short8 a = *(const short8*)(xAc + m * PADX + kt * 32 + q * 8);
            aR0  = MFMA(a, Bx[kt * 6 + 0], aR0, 0, 0, 0);
            aR1  = MFMA(a, Bx[kt * 6 + 1], aR1, 0, 0, 0);
            aZ0  = MFMA(a, Bx[kt * 6 + 2], aZ0, 0, 0, 0);
            aZ1  = MFMA(a, Bx[kt * 6 + 3], aZ1, 0, 0, 0);
            aNx0 = MFMA(a, Bx[kt * 6 + 4], aNx0, 0, 0, 0);
            aNx1 = MFMA(a, Bx[kt * 6 + 5], aNx1, 0, 0, 0);
        }

        short* hAn = hA[(t + 1) & 1];
        #pragma unroll
        for (int p = 0; p < 4; ++p) {
            int row = q * 4 + p;
            float r0 = sigmoid_f(aR0[p]);
            float z0 = sigmoid_f(aZ0[p]);
            float n0 = tanh_fast(aNx0[p] + r0 * aNh0[p]);
            float h0 = n0 + z0 * (hreg0[p] - n0);
            hreg0[p] = h0;
            hAn[row * PADA + u0] = f2bf(h0);
            float r1 = sigmoid_f(aR1[p]);
            float z1 = sigmoid_f(aZ1[p]);
            float n1 = tanh_fast(aNx1[p] + r1 * aNh1[p]);
            float h1 = n1 + z1 * (hreg1[p] - n1);
            hreg1[p] = h1;
            hAn[row * PADA + u1] = f2bf(h1);
        }
        if (t + 1 < 64) {
            xA[(t + 1) & 1][w0] = f2bf(xg0);
            xA[(t + 1) & 1][w1] = f2bf(xg1);
        }
        __syncthreads();
    }

    // fused-reduction writes (fp32 f + bf16 fbf): sd1 -> axis-2 (208/272/
    // 336), sd2 -> axis-1 (16/80/144).
    {
        const int off2 = sd2 ? 16 : 208;
        int r0 = tid >> 6, c0 = tid & 63;
        float smAm = smA * (1.f / 64.f);
        float smBm = smB * (1.f / 64.f);
        float* fr0 = f + (size_t)(sblock + r0) * INTER_ + off2 + c0;
        short* fb0 = fbf + (size_t)(sblock + r0) * KP_ + off2 + c0;
        fr0[0]   = mxA;   fb0[0]   = f2bf(mxA);
        fr0[64]  = smAm;  fb0[64]  = f2bf(smAm);
        fr0[128] = mnA;   fb0[128] = f2bf(mnA);
        float* fr1 = f + (size_t)(sblock + r0 + 8) * INTER_ + off2 + c0;
        short* fb1 = fbf + (size_t)(sblock + r0 + 8) * KP_ + off2 + c0;
        fr1[0]   = mxB;   fb1[0]   = f2bf(mxB);
        fr1[64]  = smBm;  fb1[64]  = f2bf(smBm);
        fr1[128] = mnB;   fb1[128] = f2bf(mnB);
    }

    const int off = sd2 ? 656 : 400;
    #pragma unroll
    for (int p = 0; p < 4; ++p) {
        int s = sblock + q * 4 + p;
        f[s * INTER_ + off + u0] = hreg0[p];
        f[s * INTER_ + off + u1] = hreg1[p];
        fbf[s * KP_ + off + u0] = f2bf(hreg0[p]);
        fbf[s * KP_ + off + u1] = f2bf(hreg1[p]);
    }
}

// ---------------------------------------------------------------------------
// xw1 = fbf[2048][928] @ Wih1^T (+bih1), bf16 MFMA. Output TRANSPOSED to
// [t][seq][768] so gru1d's per-step reads are step-contiguous.
// ---------------------------------------------------------------------------
__global__ __launch_bounds__(256) void gemm_xw1_mfma(
        const short* __restrict__ fbf, const short* __restrict__ BfragW,
        const float* __restrict__ bih, float* __restrict__ xw) {
    const int tid = threadIdx.x;
    const int lane = tid & 63;
    const int w = tid >> 6;
    const int m = lane & 15;
    const int q = lane >> 4;
    const int tn = blockIdx.x;
    const int tm = blockIdx.y;
    const int rowb = tm * 64 + w * 16;
    const short8* Bf8 = (const short8*)BfragW;

    float4v acc[4];
    #pragma unroll
    for (int nn = 0; nn < 4; ++nn) {
        float b = bih[tn * 64 + nn * 16 + m];
        acc[nn][0] = b; acc[nn][1] = b; acc[nn][2] = b; acc[nn][3] = b;
    }

    const short* arow = fbf + (rowb + m) * KP_;
    short8 a_cur = *(const short8*)(arow + q * 8);
    short8 b_cur[4];
    #pragma unroll
    for (int nn = 0; nn < 4; ++nn)
        b_cur[nn] = Bf8[(tn * 4 + nn) * 64 + lane];

    for (int kt = 0; kt < 29; ++kt) {
        short8 a_nxt = a_cur;
        short8 b_nxt[4];
        if (kt + 1 < 29) {
            a_nxt = *(const short8*)(arow + (kt + 1) * 32 + q * 8);
            #pragma unroll
            for (int nn = 0; nn < 4; ++nn)
                b_nxt[nn] = Bf8[((kt + 1) * 48 + tn * 4 + nn) * 64 + lane];
        }
        #pragma unroll
        for (int nn = 0; nn < 4; ++nn)
            acc[nn] = MFMA(a_cur, b_cur[nn], acc[nn], 0, 0, 0);
        a_cur = a_nxt;
        #pragma unroll
        for (int nn = 0; nn < 4; ++nn) b_cur[nn] = b_nxt[nn];
    }

    #pragma unroll
    for (int p = 0; p < 4; ++p) {
        int row = rowb + q * 4 + p;
        int seq = row >> 6, t = row & 63;
        #pragma unroll
        for (int nn = 0; nn < 4; ++nn)
            xw[(t * 32 + seq) * G3_ + tn * 64 + nn * 16 + m] = acc[nn][p];
    }
}

// ---------------------------------------------------------------------------
// fused: blocks 0-1 = gru1d (2 CUs); blocks 2-33 = f-reductions for tail.
// R4-proven 512-thread form (8 waves, wave owns 2 chunks u0/u1).
// ---------------------------------------------------------------------------
__global__ __launch_bounds__(512, 1) void gru1d_freduce(
        const float* __restrict__ xw, const short* __restrict__ Bfrag1,
        const float* __restrict__ bhh, float* __restrict__ hlast,
        const float* __restrict__ f, float* __restrict__ g) {
    __shared__ short hA[2][16 * PADA];
    __shared__ short8 Blds[2 * 48 * 64];   // kt 6,7

    const int tid = threadIdx.x;

    if (blockIdx.x >= 2) {
        const int b = blockIdx.x - 2;
        for (int i = tid; i < INTER_; i += 512) {
            const float* fp = f + (size_t)(b * 64) * INTER_ + i;
            float mx = -1e30f, mn = 1e30f, sm = 0.f;
            #pragma unroll 8
            for (int t = 0; t < 64; ++t) {
                float v = __builtin_nontemporal_load(fp + t * INTER_);
                mx = fmaxf(mx, v); mn = fminf(mn, v); sm += v;
            }
            g[b * GRED_ + i] = mx;
            g[b * GRED_ + INTER_ + i] = sm * (1.f / 64.f);
            g[b * GRED_ + 2 * INTER_ + i] = mn;
        }
        return;
    }

    const int lane = tid & 63;
    const int w = tid >> 6;
    const int m = lane & 15;
    const int q = lane >> 4;
    const int sblock = blockIdx.x * 16;

    for (int i = tid; i < 16 * PADA; i += 512) hA[0][i] = 0;
    {
        const uint4* src = (const uint4*)(Bfrag1 + 6 * 48 * 64 * 8);
        uint4* dst = (uint4*)Blds;
        #pragma unroll
        for (int rep = 0; rep < 12; ++rep)
            dst[tid + rep * 512] = src[tid + rep * 512];
    }
    const short8* Bf8 = (const short8*)Bfrag1;
    short8 Bres[36];
    #pragma unroll
    for (int kt = 0; kt < 6; ++kt)
        #pragma unroll
        for (int j = 0; j < 6; ++j)
            Bres[kt * 6 + j] = Bf8[(kt * 48 + 8 * j + w) * 64 + lane];

    const int u0 = 16 * w + m;
    const int u1 = 128 + u0;
    const float br0 = bhh[u0],       br1 = bhh[u1];
    const float bz0 = bhh[256 + u0], bz1 = bhh[256 + u1];
    const float bn0 = bhh[512 + u0], bn1 = bhh[512 + u1];

    float4v hreg0 = {0.f, 0.f, 0.f, 0.f}, hreg1 = {0.f, 0.f, 0.f, 0.f};
    __syncthreads();

    for (int t = 0; t < 64; ++t) {
        const short* hAc = hA[t & 1];

        float giR0[4], giR1[4], giZ0[4], giZ1[4], giN0[4], giN1[4];
        #pragma unroll
        for (int p = 0; p < 4; ++p) {
            const float* gr = xw + (size_t)(t * 32 + sblock + q * 4 + p) * G3_;
            giR0[p] = gr[u0];        giR1[p] = gr[u1];
            giZ0[p] = gr[256 + u0];  giZ1[p] = gr[256 + u1];
            giN0[p] = gr[512 + u0];  giN1[p] = gr[512 + u1];
        }

        float4v aR0 = {br0, br0, br0, br0}, aR1 = {br1, br1, br1, br1};
        float4v aZ0 = {bz0, bz0, bz0, bz0}, aZ1 = {bz1, bz1, bz1, bz1};
        float4v aN0 = {bn0, bn0, bn0, bn0}, aN1 = {bn1, bn1, bn1, bn1};

        #pragma unroll
        for (int kt = 0; kt < 6; ++kt) {
            short8 a = *(const short8*)(hAc + m * PADA + kt * 32 + q * 8);
            aR0 = MFMA(a, Bres[kt * 6 + 0], aR0, 0, 0, 0);
            aR1 = MFMA(a, Bres[kt * 6 + 1], aR1, 0, 0, 0);
            aZ0 = MFMA(a, Bres[kt * 6 + 2], aZ0, 0, 0, 0);
            aZ1 = MFMA(a, Bres[kt * 6 + 3], aZ1, 0, 0, 0);
            aN0 = MFMA(a, Bres[kt * 6 + 4], aN0, 0, 0, 0);
            aN1 = MFMA(a, Bres[kt * 6 + 5], aN1, 0, 0, 0);
        }
        #pragma unroll
        for (int kt = 0; kt < 2; ++kt) {
            short8 a = *(const short8*)(hAc + m * PADA + (6 + kt) * 32 + q * 8);
            short8 b0 = Blds[(kt * 48 + 8 * 0 + w) * 64 + lane];
            short8 b1 = Blds[(kt * 48 + 8 * 1 + w) * 64 + lane];
            short8 b2 = Blds[(kt * 48 + 8 * 2 + w) * 64 + lane];
            short8 b3 = Blds[(kt * 48 + 8 * 3 + w) * 64 + lane];
            short8 b4 = Blds[(kt * 48 + 8 * 4 + w) * 64 + lane];
            short8 b5 = Blds[(kt * 48 + 8 * 5 + w) * 64 + lane];
            aR0 = MFMA(a, b0, aR0, 0, 0, 0);
            aR1 = MFMA(a, b1, aR1, 0, 0, 0);
            aZ0 = MFMA(a, b2, aZ0, 0, 0, 0);
            aZ1 = MFMA(a, b3, aZ1, 0, 0, 0);
            aN0 = MFMA(a, b4, aN0, 0, 0, 0);
            aN1 = MFMA(a, b5, aN1, 0, 0, 0);
        }

        short* hAn = hA[(t + 1) & 1];
        #pragma unroll
        for (int p = 0; p < 4; ++p) {
            int row = q * 4 + p;
            float r0 = sigmoid_f(giR0[p] + aR0[p]);
            float z0 = sigmoid_f(giZ0[p] + aZ0[p]);
            float n0 = tanh_fast(giN0[p] + r0 * aN0[p]);
            float h0 = n0 + z0 * (hreg0[p] - n0);
            hreg0[p] = h0;
            hAn[row * PADA + u0] = f2bf(h0);
            float r1 = sigmoid_f(giR1[p] + aR1[p]);
            float z1 = sigmoid_f(giZ1[p] + aZ1[p]);
            float n1 = tanh_fast(giN1[p] + r1 * aN1[p]);
            float h1 = n1 + z1 * (hreg1[p] - n1);
            hreg1[p] = h1;
            hAn[row * PADA + u1] = f2bf(h1);
        }
        __syncthreads();
    }

    #pragma unroll
    for (int p = 0; p < 4; ++p) {
        int s = sblock + q * 4 + p;
        hlast[s * 256 + u0] = hreg0[p];
        hlast[s * 256 + u1] = hreg1[p];
    }
}

// ---------------------------------------------------------------------------
// tail_fc: g_lds = [g(b) | hlast(b)], fc1+relu, fc2
// ---------------------------------------------------------------------------
__global__ __launch_bounds__(256) void tail_fc(
        const float* __restrict__ g, const float* __restrict__ hlast,
        const float* __restrict__ fc1Wt, const float* __restrict__ fc1b,
        const float* __restrict__ fc2W, const float* __restrict__ fc2b,
        float* __restrict__ out) {
    __shared__ float g_lds[FCIN_];
    __shared__ float red[4];
    const int tid = threadIdx.x;
    const int b = blockIdx.x;
    for (int i = tid; i < GRED_; i += 256) g_lds[i] = g[b * GRED_ + i];
    g_lds[GRED_ + tid] = hlast[b * 256 + tid];
    __syncthreads();

    float a0 = 0.f, a1 = 0.f, a2 = 0.f, a3 = 0.f;
    for (int i = 0; i < FCIN_; i += 4) {
        a0 = fmaf(g_lds[i],     fc1Wt[(i) * 256 + tid],     a0);
        a1 = fmaf(g_lds[i + 1], fc1Wt[(i + 1) * 256 + tid], a1);
        a2 = fmaf(g_lds[i + 2], fc1Wt[(i + 2) * 256 + tid], a2);
        a3 = fmaf(g_lds[i + 3], fc1Wt[(i + 3) * 256 + tid], a3);
    }
    float acc = ((a0 + a1) + (a2 + a3)) + fc1b[tid];
    float hv = fmaxf(acc, 0.f);
    float part = hv * fc2W[tid];
    #pragma unroll
    for (int off = 32; off >= 1; off >>= 1)
        part += __shfl_down(part, off, 64);
    if ((tid & 63) == 0) red[tid >> 6] = part;
    __syncthreads();
    if (tid == 0)
        out[b] = fc2b[0] + red[0] + red[1] + red[2] + red[3];
}

// ---------------------------------------------------------------------------
extern "C" void kernel_launch(void* const* d_in, const int* in_sizes, int n_in,
                              void* d_out, int out_size, void* d_ws, size_t ws_size,
                              hipStream_t stream) {
    const float* x1     = (const float*)d_in[0];
    const float* states = (const float*)d_in[1];
    const int*   perm1  = (const int*)d_in[2];
    const int*   perm2  = (const int*)d_in[3];
    const float* Wih2   = (const float*)d_in[4];
    const float* Whh2   = (const float*)d_in[5];
    const float* bih2   = (const float*)d_in[6];
    const float* bhh2   = (const float*)d_in[7];
    const float* Wih1   = (const float*)d_in[8];
    const float* Whh1   = (const float*)d_in[9];
    const float* bih1   = (const float*)d_in[10];
    const float* bhh1   = (const float*)d_in[11];
    const float* fc1W   = (const float*)d_in[12];
    const float* fc1b   = (const float*)d_in[13];
    const float* fc2W   = (const float*)d_in[14];
    const float* fc2b   = (const float*)d_in[15];
    float* out = (float*)d_out;

    float* ws = (float*)d_ws;
    short* Bfrag   = (short*)ws;                          // 245760 bf16
    short* Bfrag1  = (short*)(ws + 122880);               // 196608 bf16
    short* Bfrag1W = (short*)(ws + 122880 + 98304);       // 712704 bf16
    float* fc1Wt   = ws + 577536;                         // 765952 f
    float* f       = fc1Wt + FCIN_ * 256;                 // 1343488
    short* fbf     = (short*)(f + 2048 * INTER_);         // 1900544 bf16
    float* xw1     = f + 2048 * INTER_ + 950272;          // 4161536
    float* hlast   = xw1 + 2048 * G3_;                    // 5734400
    float* g       = hlast + 8192;                        // 5742592 (+87552)

    prep_kernel<<<dim3(2992), 256, 0, stream>>>(Whh2, Wih2, Whh1, Wih1, fc1W,
                                                x1, Bfrag, Bfrag1, Bfrag1W,
                                                fc1Wt, f, fbf);
    gru2d_mfma<<<dim3(256), 512, 0, stream>>>(states, perm1, perm2, Bfrag,
                                              bih2, bhh2, f, fbf);
    gemm_xw1_mfma<<<dim3(12, 32), 256, 0, stream>>>(fbf, Bfrag1W, bih1, xw1);
    gru1d_freduce<<<dim3(34), 512, 0, stream>>>(xw1, Bfrag1, bhh1, hlast, f, g);
    tail_fc<<<dim3(32), 256, 0, stream>>>(g, hlast, fc1Wt, fc1b, fc2W, fc2b, out);
}

// Round 11
// 620.048 us; speedup vs baseline: 1.7897x; 1.0046x over previous
//
#include <hip/hip_runtime.h>
#include <cmath>

#define B_ 32
#define N_ 64
#define H_ 256
#define G3_ 768           // 3*H
#define INTER_ 912        // 2H + 6C + C1
#define KP_ 928           // INTER_ padded to 29*32 for bf16 MFMA GEMM
#define FCIN_ 2992        // 3*INTER + H
#define GRED_ 2736        // 3*INTER (f reductions part of g)

#define PADA 264          // hA row stride (bf16 elems)
#define PADX 72           // xA row stride (bf16 elems)

typedef __attribute__((ext_vector_type(8))) short short8;
typedef __attribute__((ext_vector_type(4))) short sshort4;
typedef __attribute__((ext_vector_type(4))) float float4v;

#define MFMA __builtin_amdgcn_mfma_f32_16x16x32_bf16

// single-instruction transcendentals: v_exp_f32 is exp2, v_rcp_f32
__device__ __forceinline__ float sigmoid_f(float x) {
    return __builtin_amdgcn_rcpf(1.0f + __builtin_amdgcn_exp2f(-1.44269504f * x));
}
__device__ __forceinline__ float tanh_fast(float x) {
    return 1.0f - 2.0f * __builtin_amdgcn_rcpf(1.0f + __builtin_amdgcn_exp2f(2.88539008f * x));
}
__device__ __forceinline__ unsigned f2bf_bits(float x) {
    unsigned u = __float_as_uint(x);
    return (u + 0x7fffu + ((u >> 16) & 1u)) >> 16;
}
__device__ __forceinline__ short f2bf(float x) { return (short)f2bf_bits(x); }

// ---------------------------------------------------------------------------
// prep: (a) Bfrag   = gru2d weights, fragment-major bf16 (layout verified R2)
//       (b) Bfrag1  = gru1d Whh, same pack (8 kt)
//       (c) Bfrag1W = gru1d Wih (768 x 912), same pack, K zero-padded to 928
//       (d) fc1Wt transpose
//       (e) x1 copy -> f[:, 0:16] AND fbf[:, 0:16] (bf16), + fbf K-pad
// Fragment layout: [kt][ntile(48)][lane(64)][j(8)] bf16; value = W[n][k] with
// n = ntile*16 + (lane&15), k = kt*32 + (lane>>4)*8 + j.
// ---------------------------------------------------------------------------
__global__ __launch_bounds__(256) void prep_kernel(
        const float* __restrict__ Whh2, const float* __restrict__ Wih2,
        const float* __restrict__ Whh1, const float* __restrict__ Wih1,
        const float* __restrict__ fc1W, const float* __restrict__ x1,
        short* __restrict__ Bfrag, short* __restrict__ Bfrag1,
        short* __restrict__ Bfrag1W, float* __restrict__ fc1Wt,
        float* __restrict__ f, short* __restrict__ fbf) {
    int idx = blockIdx.x * 256 + threadIdx.x;
    if (idx < 10 * 48 * 64 * 8) {
        int j = idx & 7, lane = (idx >> 3) & 63, tile = idx >> 9;
        int nt = tile % 48, kt = tile / 48;
        int n = nt * 16 + (lane & 15);
        int kb = (lane >> 4) * 8 + j;
        float v = (kt < 8) ? Whh2[n * 256 + kt * 32 + kb]
                           : Wih2[n * 64 + (kt - 8) * 32 + kb];
        Bfrag[idx] = f2bf(v);
    }
    if (idx < 8 * 48 * 64 * 8) {
        int j = idx & 7, lane = (idx >> 3) & 63, tile = idx >> 9;
        int nt = tile % 48, kt = tile / 48;
        int n = nt * 16 + (lane & 15);
        int k = kt * 32 + (lane >> 4) * 8 + j;
        Bfrag1[idx] = f2bf(Whh1[n * 256 + k]);
    }
    if (idx < 29 * 48 * 64 * 8) {
        int j = idx & 7, lane = (idx >> 3) & 63, tile = idx >> 9;
        int nt = tile % 48, kt = tile / 48;
        int n = nt * 16 + (lane & 15);
        int k = kt * 32 + (lane >> 4) * 8 + j;
        Bfrag1W[idx] = (k < INTER_) ? f2bf(Wih1[n * INTER_ + k]) : (short)0;
    }
    if (idx < FCIN_ * 256) {
        int o = idx & 255, i = idx >> 8;
        fc1Wt[idx] = fc1W[o * FCIN_ + i];
    }
    if (idx < 2048 * 16) {
        int bj = idx >> 4, c = idx & 15;
        float v = x1[idx];
        f[bj * INTER_ + c] = v;
        fbf[bj * KP_ + c] = f2bf(v);
        fbf[bj * KP_ + 912 + c] = 0;   // zero-pad K 912..927
    }
}

// ---------------------------------------------------------------------------
// gru2d R10 (unchanged): 512 thr, xA staging, per-step Bx reload, hA
// double-buffer, single barrier/step, bias-folded init, fused d[]
// reductions, direct fbf (bf16) epilogue writes.
// ---------------------------------------------------------------------------
__global__ __launch_bounds__(512, 1) void gru2d_mfma(
        const float* __restrict__ states,
        const int* __restrict__ perm1, const int* __restrict__ perm2,
        const short* __restrict__ Bfrag,
        const float* __restrict__ bih, const float* __restrict__ bhh,
        float* __restrict__ f, short* __restrict__ fbf) {
    __shared__ short hA[2][16 * PADA];
    __shared__ short xA[2][16 * PADX];
    __shared__ short8 Blds[2 * 48 * 64];
    __shared__ int perms[1024];

    const int tid = threadIdx.x;
    const int lane = tid & 63;
    const int w = tid >> 6;
    const int m = lane & 15;
    const int q = lane >> 4;
    const bool sd2 = blockIdx.x >= 128;
    const int sblock = (blockIdx.x & 127) * 16;

    for (int i = tid; i < 1024; i += 512) {
        int r = i >> 6, t = i & 63;
        int qq = (sblock + r) & 63;
        perms[i] = sd2 ? perm2[qq * 64 + t] : perm1[qq * 64 + t];
    }
    for (int i = tid; i < 16 * PADA; i += 512) hA[0][i] = 0;
    {
        const uint4* src = (const uint4*)(Bfrag + 6 * 48 * 64 * 8);
        uint4* dst = (uint4*)Blds;
        #pragma unroll
        for (int rep = 0; rep < 12; ++rep)
            dst[tid + rep * 512] = src[tid + rep * 512];
    }

    const short8* Bf8 = (const short8*)Bfrag;
    short8 Bres[36];
    #pragma unroll
    for (int kt = 0; kt < 6; ++kt)
        #pragma unroll
        for (int j = 0; j < 6; ++j)
            Bres[kt * 6 + j] = Bf8[(kt * 48 + 8 * j + w) * 64 + lane];

    const int u0 = 16 * w + m;
    const int u1 = 128 + u0;
    const float br0 = bih[u0] + bhh[u0],             br1 = bih[u1] + bhh[u1];
    const float bz0 = bih[256 + u0] + bhh[256 + u0], bz1 = bih[256 + u1] + bhh[256 + u1];
    const float bnx0 = bih[512 + u0], bnx1 = bih[512 + u1];
    const float bnh0 = bhh[512 + u0], bnh1 = bhh[512 + u1];

    float4v hreg0 = {0.f, 0.f, 0.f, 0.f}, hreg1 = {0.f, 0.f, 0.f, 0.f};

    // fused-reduction accumulators: half0 -> (r = tid>>6, c), half1 -> (r+8, c)
    float mxA = -1e30f, mnA = 1e30f, smA = 0.f;
    float mxB = -1e30f, mnB = 1e30f, smB = 0.f;

    {
        #pragma unroll
        for (int half = 0; half < 2; ++half) {
            int i = tid + half * 512;
            int r = i >> 6, c = i & 63;
            int s = sblock + r, b = s >> 6, qq = s & 63;
            int p = perms[r * 64 + 0];
            int src = sd2 ? ((b * 64 + p) * 64 + qq) * 64 + c
                          : ((b * 64 + qq) * 64 + p) * 64 + c;
            float v = states[src];
            if (half == 0) { mxA = fmaxf(mxA, v); mnA = fminf(mnA, v); smA += v; }
            else           { mxB = fmaxf(mxB, v); mnB = fminf(mnB, v); smB += v; }
            xA[0][r * PADX + c] = f2bf(v);
        }
    }
    __syncthreads();

    for (int t = 0; t < 64; ++t) {
        const short* hAc = hA[t & 1];
        const short* xAc = xA[t & 1];

        short8 Bx[12];
        #pragma unroll
        for (int kt = 0; kt < 2; ++kt)
            #pragma unroll
            for (int j = 0; j < 6; ++j)
                Bx[kt * 6 + j] = Bf8[((8 + kt) * 48 + 8 * j + w) * 64 + lane];

        float xg0 = 0.f, xg1 = 0.f;
        int w0 = -1, w1 = -1;
        if (t + 1 < 64) {
            #pragma unroll
            for (int half = 0; half < 2; ++half) {
                int i = tid + half * 512;
                int r = i >> 6, c = i & 63;
                int s = sblock + r, b = s >> 6, qq = s & 63;
                int p = perms[r * 64 + t + 1];
                int src = sd2 ? ((b * 64 + p) * 64 + qq) * 64 + c
                              : ((b * 64 + qq) * 64 + p) * 64 + c;
                float v = states[src];
                if (half == 0) {
                    xg0 = v; w0 = r * PADX + c;
                    mxA = fmaxf(mxA, v); mnA = fminf(mnA, v); smA += v;
                } else {
                    xg1 = v; w1 = r * PADX + c;
                    mxB = fmaxf(mxB, v); mnB = fminf(mnB, v); smB += v;
                }
            }
        }

        // ---- interleaved 6-chain MFMA, biases pre-folded ----
        float4v aR0 = {br0, br0, br0, br0},     aR1 = {br1, br1, br1, br1};
        float4v aZ0 = {bz0, bz0, bz0, bz0},     aZ1 = {bz1, bz1, bz1, bz1};
        float4v aNh0 = {bnh0, bnh0, bnh0, bnh0}, aNh1 = {bnh1, bnh1, bnh1, bnh1};
        float4v aNx0 = {bnx0, bnx0, bnx0, bnx0}, aNx1 = {bnx1, bnx1, bnx1, bnx1};

        #pragma unroll
        for (int kt = 0; kt < 6; ++kt) {
            short8 a = *(const short8*)(hAc + m * PADA + kt * 32 + q * 8);
            aR0  = MFMA(a, Bres[kt * 6 + 0], aR0, 0, 0, 0);
            aR1  = MFMA(a, Bres[kt * 6 + 1], aR1, 0, 0, 0);
            aZ0  = MFMA(a, Bres[kt * 6 + 2], aZ0, 0, 0, 0);
            aZ1  = MFMA(a, Bres[kt * 6 + 3], aZ1, 0, 0, 0);
            aNh0 = MFMA(a, Bres[kt * 6 + 4], aNh0, 0, 0, 0);
            aNh1 = MFMA(a, Bres[kt * 6 + 5], aNh1, 0, 0, 0);
        }
        #pragma unroll
        for (int kt = 0; kt < 2; ++kt) {
            short8 a = *(const short8*)(hAc + m * PADA + (6 + kt) * 32 + q * 8);
            short8 b0 = Blds[(kt * 48 + 8 * 0 + w) * 64 + lane];
            short8 b1 = Blds[(kt * 48 + 8 * 1 + w) * 64 + lane];
            short8 b2 = Blds[(kt * 48 + 8 * 2 + w) * 64 + lane];
            short8 b3 = Blds[(kt * 48 + 8 * 3 + w) * 64 + lane];
            short8 b4 = Blds[(kt * 48 + 8 * 4 + w) * 64 + lane];
            short8 b5 = Blds[(kt * 48 + 8 * 5 + w) * 64 + lane];
            aR0  = MFMA(a, b0, aR0, 0, 0, 0);
            aR1  = MFMA(a, b1, aR1, 0, 0, 0);
            aZ0  = MFMA(a, b2, aZ0, 0, 0, 0);
            aZ1  = MFMA(a, b3, aZ1, 0, 0, 0);
            aNh0 = MFMA(a, b4, aNh0, 0, 0, 0);
            aNh1 = MFMA(a, b5, aNh1, 0, 0, 0);
        }
        #pragma unroll
        for (int kt = 0; kt < 2; ++kt) {
            short8 a = *(const short8*)(xAc + m * PADX + kt * 32 + q * 8);
            aR0  = MFMA(a, Bx[kt * 6 + 0], aR0, 0, 0, 0);
            aR1  = MFMA(a, Bx[kt * 6 + 1], aR1, 0, 0, 0);
            aZ0  = MFMA(a, Bx[kt * 6 + 2], aZ0, 0, 0, 0);
            aZ1  = MFMA(a, Bx[kt * 6 + 3], aZ1, 0, 0, 0);
            aNx0 = MFMA(a, Bx[kt * 6 + 4], aNx0, 0, 0, 0);
            aNx1 = MFMA(a, Bx[kt * 6 + 5], aNx1, 0, 0, 0);
        }

        short* hAn = hA[(t + 1) & 1];
        #pragma unroll
        for (int p = 0; p < 4; ++p) {
            int row = q * 4 + p;
            float r0 = sigmoid_f(aR0[p]);
            float z0 = sigmoid_f(aZ0[p]);
            float n0 = tanh_fast(aNx0[p] + r0 * aNh0[p]);
            float h0 = n0 + z0 * (hreg0[p] - n0);
            hreg0[p] = h0;
            hAn[row * PADA + u0] = f2bf(h0);
            float r1 = sigmoid_f(aR1[p]);
            float z1 = sigmoid_f(aZ1[p]);
            float n1 = tanh_fast(aNx1[p] + r1 * aNh1[p]);
            float h1 = n1 + z1 * (hreg1[p] - n1);
            hreg1[p] = h1;
            hAn[row * PADA + u1] = f2bf(h1);
        }
        if (t + 1 < 64) {
            xA[(t + 1) & 1][w0] = f2bf(xg0);
            xA[(t + 1) & 1][w1] = f2bf(xg1);
        }
        __syncthreads();
    }

    // fused-reduction writes (fp32 f + bf16 fbf)
    {
        const int off2 = sd2 ? 16 : 208;
        int r0 = tid >> 6, c0 = tid & 63;
        float smAm = smA * (1.f / 64.f);
        float smBm = smB * (1.f / 64.f);
        float* fr0 = f + (size_t)(sblock + r0) * INTER_ + off2 + c0;
        short* fb0 = fbf + (size_t)(sblock + r0) * KP_ + off2 + c0;
        fr0[0]   = mxA;   fb0[0]   = f2bf(mxA);
        fr0[64]  = smAm;  fb0[64]  = f2bf(smAm);
        fr0[128] = mnA;   fb0[128] = f2bf(mnA);
        float* fr1 = f + (size_t)(sblock + r0 + 8) * INTER_ + off2 + c0;
        short* fb1 = fbf + (size_t)(sblock + r0 + 8) * KP_ + off2 + c0;
        fr1[0]   = mxB;   fb1[0]   = f2bf(mxB);
        fr1[64]  = smBm;  fb1[64]  = f2bf(smBm);
        fr1[128] = mnB;   fb1[128] = f2bf(mnB);
    }

    const int off = sd2 ? 656 : 400;
    #pragma unroll
    for (int p = 0; p < 4; ++p) {
        int s = sblock + q * 4 + p;
        f[s * INTER_ + off + u0] = hreg0[p];
        f[s * INTER_ + off + u1] = hreg1[p];
        fbf[s * KP_ + off + u0] = f2bf(hreg0[p]);
        fbf[s * KP_ + off + u1] = f2bf(hreg1[p]);
    }
}

// ---------------------------------------------------------------------------
// xw1 = fbf[2048][928] @ Wih1^T (+bih1), bf16 MFMA. Output TRANSPOSED to
// [t][seq][768] so gru1d's per-step reads are step-contiguous.
// ---------------------------------------------------------------------------
__global__ __launch_bounds__(256) void gemm_xw1_mfma(
        const short* __restrict__ fbf, const short* __restrict__ BfragW,
        const float* __restrict__ bih, float* __restrict__ xw) {
    const int tid = threadIdx.x;
    const int lane = tid & 63;
    const int w = tid >> 6;
    const int m = lane & 15;
    const int q = lane >> 4;
    const int tn = blockIdx.x;
    const int tm = blockIdx.y;
    const int rowb = tm * 64 + w * 16;
    const short8* Bf8 = (const short8*)BfragW;

    float4v acc[4];
    #pragma unroll
    for (int nn = 0; nn < 4; ++nn) {
        float b = bih[tn * 64 + nn * 16 + m];
        acc[nn][0] = b; acc[nn][1] = b; acc[nn][2] = b; acc[nn][3] = b;
    }

    const short* arow = fbf + (rowb + m) * KP_;
    short8 a_cur = *(const short8*)(arow + q * 8);
    short8 b_cur[4];
    #pragma unroll
    for (int nn = 0; nn < 4; ++nn)
        b_cur[nn] = Bf8[(tn * 4 + nn) * 64 + lane];

    for (int kt = 0; kt < 29; ++kt) {
        short8 a_nxt = a_cur;
        short8 b_nxt[4];
        if (kt + 1 < 29) {
            a_nxt = *(const short8*)(arow + (kt + 1) * 32 + q * 8);
            #pragma unroll
            for (int nn = 0; nn < 4; ++nn)
                b_nxt[nn] = Bf8[((kt + 1) * 48 + tn * 4 + nn) * 64 + lane];
        }
        #pragma unroll
        for (int nn = 0; nn < 4; ++nn)
            acc[nn] = MFMA(a_cur, b_cur[nn], acc[nn], 0, 0, 0);
        a_cur = a_nxt;
        #pragma unroll
        for (int nn = 0; nn < 4; ++nn) b_cur[nn] = b_nxt[nn];
    }

    #pragma unroll
    for (int p = 0; p < 4; ++p) {
        int row = rowb + q * 4 + p;
        int seq = row >> 6, t = row & 63;
        #pragma unroll
        for (int nn = 0; nn < 4; ++nn)
            xw[(t * 32 + seq) * G3_ + tn * 64 + nn * 16 + m] = acc[nn][p];
    }
}

// ---------------------------------------------------------------------------
// fused: blocks 0-1 = gru1d (2 CUs); blocks 2-33 = f-reductions for tail.
// R11: gru1d MFMA chains GATE-GROUPED (R -> Z -> N) so the r-sigmoids issue
// on the VALU pipe while the Z-group MFMAs occupy the matrix pipe, and the
// z-sigmoids overlap the N-group. Each accumulator chain's internal order
// is unchanged -> bit-identical results. gru1d has ~45 regs of slack at
// (512,1) (unlike gru2d), so the 16 extra live floats fit without spill.
// ---------------------------------------------------------------------------
__global__ __launch_bounds__(512, 1) void gru1d_freduce(
        const float* __restrict__ xw, const short* __restrict__ Bfrag1,
        const float* __restrict__ bhh, float* __restrict__ hlast,
        const float* __restrict__ f, float* __restrict__ g) {
    __shared__ short hA[2][16 * PADA];
    __shared__ short8 Blds[2 * 48 * 64];   // kt 6,7

    const int tid = threadIdx.x;

    if (blockIdx.x >= 2) {
        const int b = blockIdx.x - 2;
        for (int i = tid; i < INTER_; i += 512) {
            const float* fp = f + (size_t)(b * 64) * INTER_ + i;
            float mx = -1e30f, mn = 1e30f, sm = 0.f;
            #pragma unroll 8
            for (int t = 0; t < 64; ++t) {
                float v = __builtin_nontemporal_load(fp + t * INTER_);
                mx = fmaxf(mx, v); mn = fminf(mn, v); sm += v;
            }
            g[b * GRED_ + i] = mx;
            g[b * GRED_ + INTER_ + i] = sm * (1.f / 64.f);
            g[b * GRED_ + 2 * INTER_ + i] = mn;
        }
        return;
    }

    const int lane = tid & 63;
    const int w = tid >> 6;
    const int m = lane & 15;
    const int q = lane >> 4;
    const int sblock = blockIdx.x * 16;

    for (int i = tid; i < 16 * PADA; i += 512) hA[0][i] = 0;
    {
        const uint4* src = (const uint4*)(Bfrag1 + 6 * 48 * 64 * 8);
        uint4* dst = (uint4*)Blds;
        #pragma unroll
        for (int rep = 0; rep < 12; ++rep)
            dst[tid + rep * 512] = src[tid + rep * 512];
    }
    const short8* Bf8 = (const short8*)Bfrag1;
    short8 Bres[36];
    #pragma unroll
    for (int kt = 0; kt < 6; ++kt)
        #pragma unroll
        for (int j = 0; j < 6; ++j)
            Bres[kt * 6 + j] = Bf8[(kt * 48 + 8 * j + w) * 64 + lane];

    const int u0 = 16 * w + m;
    const int u1 = 128 + u0;
    const float br0 = bhh[u0],       br1 = bhh[u1];
    const float bz0 = bhh[256 + u0], bz1 = bhh[256 + u1];
    const float bn0 = bhh[512 + u0], bn1 = bhh[512 + u1];

    float4v hreg0 = {0.f, 0.f, 0.f, 0.f}, hreg1 = {0.f, 0.f, 0.f, 0.f};
    __syncthreads();

    for (int t = 0; t < 64; ++t) {
        const short* hAc = hA[t & 1];

        float giR0[4], giR1[4], giZ0[4], giZ1[4], giN0[4], giN1[4];
        #pragma unroll
        for (int p = 0; p < 4; ++p) {
            const float* gr = xw + (size_t)(t * 32 + sblock + q * 4 + p) * G3_;
            giR0[p] = gr[u0];        giR1[p] = gr[u1];
            giZ0[p] = gr[256 + u0];  giZ1[p] = gr[256 + u1];
            giN0[p] = gr[512 + u0];  giN1[p] = gr[512 + u1];
        }

        // ---- R group (16 MFMAs) ----
        float4v aR0 = {br0, br0, br0, br0}, aR1 = {br1, br1, br1, br1};
        #pragma unroll
        for (int kt = 0; kt < 6; ++kt) {
            short8 a = *(const short8*)(hAc + m * PADA + kt * 32 + q * 8);
            aR0 = MFMA(a, Bres[kt * 6 + 0], aR0, 0, 0, 0);
            aR1 = MFMA(a, Bres[kt * 6 + 1], aR1, 0, 0, 0);
        }
        #pragma unroll
        for (int kt = 0; kt < 2; ++kt) {
            short8 a = *(const short8*)(hAc + m * PADA + (6 + kt) * 32 + q * 8);
            aR0 = MFMA(a, Blds[(kt * 48 + 8 * 0 + w) * 64 + lane], aR0, 0, 0, 0);
            aR1 = MFMA(a, Blds[(kt * 48 + 8 * 1 + w) * 64 + lane], aR1, 0, 0, 0);
        }

        // ---- Z group (16 MFMAs) ----
        float4v aZ0 = {bz0, bz0, bz0, bz0}, aZ1 = {bz1, bz1, bz1, bz1};
        #pragma unroll
        for (int kt = 0; kt < 6; ++kt) {
            short8 a = *(const short8*)(hAc + m * PADA + kt * 32 + q * 8);
            aZ0 = MFMA(a, Bres[kt * 6 + 2], aZ0, 0, 0, 0);
            aZ1 = MFMA(a, Bres[kt * 6 + 3], aZ1, 0, 0, 0);
        }
        #pragma unroll
        for (int kt = 0; kt < 2; ++kt) {
            short8 a = *(const short8*)(hAc + m * PADA + (6 + kt) * 32 + q * 8);
            aZ0 = MFMA(a, Blds[(kt * 48 + 8 * 2 + w) * 64 + lane], aZ0, 0, 0, 0);
            aZ1 = MFMA(a, Blds[(kt * 48 + 8 * 3 + w) * 64 + lane], aZ1, 0, 0, 0);
        }

        // r-sigmoids: VALU runs while Z/N-group MFMAs occupy the matrix pipe
        float r0[4], r1[4];
        #pragma unroll
        for (int p = 0; p < 4; ++p) {
            r0[p] = sigmoid_f(giR0[p] + aR0[p]);
            r1[p] = sigmoid_f(giR1[p] + aR1[p]);
        }

        // ---- N group (16 MFMAs) ----
        float4v aN0 = {bn0, bn0, bn0, bn0}, aN1 = {bn1, bn1, bn1, bn1};
        #pragma unroll
        for (int kt = 0; kt < 6; ++kt) {
            short8 a = *(const short8*)(hAc + m * PADA + kt * 32 + q * 8);
            aN0 = MFMA(a, Bres[kt * 6 + 4], aN0, 0, 0, 0);
            aN1 = MFMA(a, Bres[kt * 6 + 5], aN1, 0, 0, 0);
        }
        #pragma unroll
        for (int kt = 0; kt < 2; ++kt) {
            short8 a = *(const short8*)(hAc + m * PADA + (6 + kt) * 32 + q * 8);
            aN0 = MFMA(a, Blds[(kt * 48 + 8 * 4 + w) * 64 + lane], aN0, 0, 0, 0);
            aN1 = MFMA(a, Blds[(kt * 48 + 8 * 5 + w) * 64 + lane], aN1, 0, 0, 0);
        }

        // z-sigmoids overlap the N-group MFMAs
        float z0[4], z1[4];
        #pragma unroll
        for (int p = 0; p < 4; ++p) {
            z0[p] = sigmoid_f(giZ0[p] + aZ0[p]);
            z1[p] = sigmoid_f(giZ1[p] + aZ1[p]);
        }

        short* hAn = hA[(t + 1) & 1];
        #pragma unroll
        for (int p = 0; p < 4; ++p) {
            int row = q * 4 + p;
            float n0 = tanh_fast(giN0[p] + r0[p] * aN0[p]);
            float h0 = n0 + z0[p] * (hreg0[p] - n0);
            hreg0[p] = h0;
            hAn[row * PADA + u0] = f2bf(h0);
            float n1 = tanh_fast(giN1[p] + r1[p] * aN1[p]);
            float h1 = n1 + z1[p] * (hreg1[p] - n1);
            hreg1[p] = h1;
            hAn[row * PADA + u1] = f2bf(h1);
        }
        __syncthreads();
    }

    #pragma unroll
    for (int p = 0; p < 4; ++p) {
        int s = sblock + q * 4 + p;
        hlast[s * 256 + u0] = hreg0[p];
        hlast[s * 256 + u1] = hreg1[p];
    }
}

// ---------------------------------------------------------------------------
// tail_fc: g_lds = [g(b) | hlast(b)], fc1+relu, fc2
// ---------------------------------------------------------------------------
__global__ __launch_bounds__(256) void tail_fc(
        const float* __restrict__ g, const float* __restrict__ hlast,
        const float* __restrict__ fc1Wt, const float* __restrict__ fc1b,
        const float* __restrict__ fc2W, const float* __restrict__ fc2b,
        float* __restrict__ out) {
    __shared__ float g_lds[FCIN_];
    __shared__ float red[4];
    const int tid = threadIdx.x;
    const int b = blockIdx.x;
    for (int i = tid; i < GRED_; i += 256) g_lds[i] = g[b * GRED_ + i];
    g_lds[GRED_ + tid] = hlast[b * 256 + tid];
    __syncthreads();

    float a0 = 0.f, a1 = 0.f, a2 = 0.f, a3 = 0.f;
    for (int i = 0; i < FCIN_; i += 4) {
        a0 = fmaf(g_lds[i],     fc1Wt[(i) * 256 + tid],     a0);
        a1 = fmaf(g_lds[i + 1], fc1Wt[(i + 1) * 256 + tid], a1);
        a2 = fmaf(g_lds[i + 2], fc1Wt[(i + 2) * 256 + tid], a2);
        a3 = fmaf(g_lds[i + 3], fc1Wt[(i + 3) * 256 + tid], a3);
    }
    float acc = ((a0 + a1) + (a2 + a3)) + fc1b[tid];
    float hv = fmaxf(acc, 0.f);
    float part = hv * fc2W[tid];
    #pragma unroll
    for (int off = 32; off >= 1; off >>= 1)
        part += __shfl_down(part, off, 64);
    if ((tid & 63) == 0) red[tid >> 6] = part;
    __syncthreads();
    if (tid == 0)
        out[b] = fc2b[0] + red[0] + red[1] + red[2] + red[3];
}

// ---------------------------------------------------------------------------
extern "C" void kernel_launch(void* const* d_in, const int* in_sizes, int n_in,
                              void* d_out, int out_size, void* d_ws, size_t ws_size,
                              hipStream_t stream) {
    const float* x1     = (const float*)d_in[0];
    const float* states = (const float*)d_in[1];
    const int*   perm1  = (const int*)d_in[2];
    const int*   perm2  = (const int*)d_in[3];
    const float* Wih2   = (const float*)d_in[4];
    const float* Whh2   = (const float*)d_in[5];
    const float* bih2   = (const float*)d_in[6];
    const float* bhh2   = (const float*)d_in[7];
    const float* Wih1   = (const float*)d_in[8];
    const float* Whh1   = (const float*)d_in[9];
    const float* bih1   = (const float*)d_in[10];
    const float* bhh1   = (const float*)d_in[11];
    const float* fc1W   = (const float*)d_in[12];
    const float* fc1b   = (const float*)d_in[13];
    const float* fc2W   = (const float*)d_in[14];
    const float* fc2b   = (const float*)d_in[15];
    float* out = (float*)d_out;

    float* ws = (float*)d_ws;
    short* Bfrag   = (short*)ws;                          // 245760 bf16
    short* Bfrag1  = (short*)(ws + 122880);               // 196608 bf16
    short* Bfrag1W = (short*)(ws + 122880 + 98304);       // 712704 bf16
    float* fc1Wt   = ws + 577536;                         // 765952 f
    float* f       = fc1Wt + FCIN_ * 256;                 // 1343488
    short* fbf     = (short*)(f + 2048 * INTER_);         // 1900544 bf16
    float* xw1     = f + 2048 * INTER_ + 950272;          // 4161536
    float* hlast   = xw1 + 2048 * G3_;                    // 5734400
    float* g       = hlast + 8192;                        // 5742592 (+87552)

    prep_kernel<<<dim3(2992), 256, 0, stream>>>(Whh2, Wih2, Whh1, Wih1, fc1W,
                                                x1, Bfrag, Bfrag1, Bfrag1W,
                                                fc1Wt, f, fbf);
    gru2d_mfma<<<dim3(256), 512, 0, stream>>>(states, perm1, perm2, Bfrag,
                                              bih2, bhh2, f, fbf);
    gemm_xw1_mfma<<<dim3(12, 32), 256, 0, stream>>>(fbf, Bfrag1W, bih1, xw1);
    gru1d_freduce<<<dim3(34), 512, 0, stream>>>(xw1, Bfrag1, bhh1, hlast, f, g);
    tail_fc<<<dim3(32), 256, 0, stream>>>(g, hlast, fc1Wt, fc1b, fc2W, fc2b, out);
}